// Round 8
// baseline (1436.879 us; speedup 1.0000x reference)
//
#include <hip/hip_runtime.h>
#include <stdint.h>

#define N_NODES 10000
#define N_EDGES 320000

using bf16x8 = __attribute__((ext_vector_type(8))) short;
using fp32x4 = __attribute__((ext_vector_type(4))) float;
using u16x8 = __attribute__((ext_vector_type(8))) unsigned short;
using i32x4 = __attribute__((ext_vector_type(4))) int;

__device__ __forceinline__ float bf2f(unsigned short u) {
  union { unsigned int i; float f; } v; v.i = ((unsigned int)u) << 16; return v.f;
}
__device__ __forceinline__ unsigned short f2bf(float f) {
  union { float f; unsigned int i; } v; v.f = f;
  unsigned int x = v.i;
  x += 0x7fffu + ((x >> 16) & 1u);
  return (unsigned short)(x >> 16);
}

// ---------------- internal bf16 arena (element offsets) ---------------------
#define A_POS 0
#define A_EA 20000
#define A_WP 340000
#define A_BP 340512
#define A_WA 340768
#define A_BA 341024
#define A_W1 341280
#define A_B1 537888
#define A_W2 538656
#define A_B2 735264
#define A_WE 736032
#define A_BE 998176
#define A_WS 999200
#define A_WT 1261344
#define A_WM1 1523488
#define A_BM1 1556384
#define A_AL 1556512
#define A_WM2 1556544
#define A_BM2 1556672
#define ARENA_USED 1556673
#define ARENA_TOT 1556736

__constant__ int g_off[19] = {A_POS, A_EA, A_WP, A_BP, A_WA, A_BA, A_W1, A_B1,
                              A_W2, A_B2, A_WE, A_BE, A_WS, A_WT, A_WM1,
                              A_BM1, A_AL, A_WM2, A_BM2};

struct Ptrs { const void* p[19]; };

// Dtype detector: fp32 read as bf16 halves yields ~47% |v|>100; bf16 never.
__global__ void k_detect(const unsigned short* wpraw, int* flag) {
  __shared__ int cnt;
  int tid = threadIdx.x;
  if (tid == 0) cnt = 0;
  __syncthreads();
  float v0 = bf2f(wpraw[tid]);
  float v1 = bf2f(wpraw[256 + tid]);
  int big = (fabsf(v0) > 100.f ? 1 : 0) + (fabsf(v1) > 100.f ? 1 : 0);
  atomicAdd(&cnt, big);
  __syncthreads();
  if (tid == 0) *flag = (cnt > 10) ? 1 : 0;  // 1 = fp32 inputs
}

// Normalize all float inputs into the bf16 arena (flattened grid).
__global__ void k_cast(Ptrs ptrs, const int* __restrict__ flag,
                       unsigned short* __restrict__ arena) {
  int a = blockIdx.x * 256 + threadIdx.x;
  if (a >= ARENA_USED) return;
  int z = 0;
#pragma unroll
  for (int j = 1; j < 19; ++j) if (a >= g_off[j]) z = j;
  int i = a - g_off[z];
  float v;
  if (*flag) v = ((const float*)ptrs.p[z])[i];
  else       v = bf2f(((const unsigned short*)ptrs.p[z])[i]);
  arena[a] = f2bf(v);
}

// ---------------------------------------------------------------------------
// Weight prep: transpose [K,N] -> n-major [N,K] (row = out-col, 512B rows).
// nodeBT per layer l<3: [W1T|W2T|WsT|WtT] (1024x256); l==3: [WsT|WtT].
// ---------------------------------------------------------------------------
__global__ void k_prep(const unsigned short* __restrict__ arena,
                       unsigned short* nodeBT, unsigned short* WeT,
                       unsigned short* Wm1T, unsigned short* biascat) {
  int z = blockIdx.z;
  int i = blockIdx.x * 256 + threadIdx.x;
  if (z == 19) {  // bias concat: 3 x [b1|b2|0|0] (1024) then 512 zeros
    if (i < 3072) {
      int l = i >> 10, j = i & 1023;
      unsigned short v = 0;
      if (j < 256) v = arena[A_B1 + l * 256 + j];
      else if (j < 512) v = arena[A_B2 + l * 256 + (j - 256)];
      biascat[i] = v;
    } else if (i < 3584) {
      biascat[i] = 0;
    }
    return;
  }
  const unsigned short* src; unsigned short* dst; int srcN = 256;
  if (z < 3)       {                 src = arena + A_W1 + z * 65536; dst = nodeBT + z * 262144; }
  else if (z < 6)  { int l = z - 3;  src = arena + A_W2 + l * 65536; dst = nodeBT + l * 262144 + 65536; }
  else if (z < 10) { int l = z - 6;  src = arena + A_WS + l * 65536;
                     dst = (l < 3) ? nodeBT + l * 262144 + 131072 : nodeBT + 786432; }
  else if (z < 14) { int l = z - 10; src = arena + A_WT + l * 65536;
                     dst = (l < 3) ? nodeBT + l * 262144 + 196608 : nodeBT + 786432 + 65536; }
  else if (z < 18) { int l = z - 14; src = arena + A_WE + l * 65536; dst = WeT + l * 65536; }
  else             { src = arena + A_WM1; dst = Wm1T; srcN = 128; }
  if (i < srcN * 256) {
    int k = i & 255, n = i >> 8;
    dst[i] = src[k * srcN + n];  // dst[n][k] = src[k][n]
  }
}

// x0 = pos @ Wp + bp (K=2), fp32 master + bf16 copy
__global__ void k_init_x(const unsigned short* __restrict__ arena,
                         float* __restrict__ xf, unsigned short* __restrict__ xbf) {
  int n = blockIdx.x, c = threadIdx.x;
  float p0 = bf2f(arena[A_POS + 2 * n]), p1 = bf2f(arena[A_POS + 2 * n + 1]);
  float v = fmaf(p0, bf2f(arena[A_WP + c]),
                 fmaf(p1, bf2f(arena[A_WP + 256 + c]), bf2f(arena[A_BP + c])));
  long idx = ((long)n << 8) + c;
  xf[idx] = v;
  xbf[idx] = f2bf(v);
}

// ---------------- CSR build (by dst). e lives in CSR row order everywhere ---
__global__ void k_hist(const int* __restrict__ dstA, int* __restrict__ deg) {
  int i = blockIdx.x * 256 + threadIdx.x;
  if (i < N_EDGES) {
    int d = dstA[i];
    if ((unsigned)d < N_NODES) atomicAdd(&deg[d], 1);
  }
}

__global__ void k_scan(const int* __restrict__ deg, int* __restrict__ rowptr,
                       int* __restrict__ cursor) {
  __shared__ int part[256];
  int tid = threadIdx.x;
  int base = tid * 40;
  int s = 0;
  for (int i = 0; i < 40; ++i) {
    int idx = base + i;
    if (idx < N_NODES) s += deg[idx];
  }
  part[tid] = s;
  __syncthreads();
  if (tid == 0) {
    int run = 0;
    for (int i = 0; i < 256; ++i) { int t = part[i]; part[i] = run; run += t; }
    rowptr[N_NODES] = run;
  }
  __syncthreads();
  int run = part[tid];
  for (int i = 0; i < 40; ++i) {
    int idx = base + i;
    if (idx < N_NODES) { rowptr[idx] = run; cursor[idx] = run; run += deg[idx]; }
  }
}

// Also emits csrc/cdst (endpoints in CSR order) and eaC (ea gathered to CSR).
__global__ void k_fill(const int* __restrict__ dstA, const int* __restrict__ srcA,
                       const unsigned short* __restrict__ arena,
                       int* __restrict__ cursor, int* __restrict__ eid,
                       int* __restrict__ csrc, int* __restrict__ cdst,
                       unsigned short* __restrict__ eaC) {
  int i = blockIdx.x * 256 + threadIdx.x;
  if (i < N_EDGES) {
    int d = dstA[i]; if ((unsigned)d >= N_NODES) d = 0;
    int p = atomicAdd(&cursor[d], 1);
    if ((unsigned)p < N_EDGES) {
      eid[p] = i;
      int s = srcA[i]; if ((unsigned)s >= N_NODES) s = 0;
      csrc[p] = s;
      cdst[p] = d;
      eaC[p] = arena[A_EA + i];
    }
  }
}

// ---------------------------------------------------------------------------
// Swapped-operand GEMM core with PERMUTED column mapping: A-frag lane ll of
// fragment mt loads WT row oc = colBase + (ll>>2)*(MT*4) + mt*4 + (ll&3).
// Lane (q,ll) reg r of frag mt then holds out-col colBase + q*(MT*4) + mt*4+r
// -> each lane's values cover MT*4 CONSECUTIVE cols (full-line epilogue).
// B-frag: LDS tile row (n=ll). D row = nt*16+ll.
// LDS pitch 528B -> <=2-way bank aliasing (free, m136).
// ---------------------------------------------------------------------------
#define SM_PITCH 528

template <bool NT>
__device__ __forceinline__ void stage_tile(char* smc, const unsigned short* src,
                                           long rowBase, long maxRow) {
  int tid = threadIdx.x;
#pragma unroll
  for (int it = 0; it < 16; ++it) {
    int lin = it * 256 + tid;       // 128 rows x 32 groups of 16B
    int row = lin >> 5, g = lin & 31;
    long rg = rowBase + row;
    if (rg > maxRow) rg = maxRow;
    const i32x4* p = (const i32x4*)((const char*)src + (rg << 9) + (g << 4));
    i32x4 v = NT ? __builtin_nontemporal_load(p) : *p;
    *(i32x4*)(smc + row * SM_PITCH + (g << 4)) = v;
  }
}

template <int MT>
__device__ __forceinline__ void gemm_swap(const char* smc, const unsigned short* WT,
                                          int colBase, fp32x4 (&acc)[MT][8]) {
  const int lane = threadIdx.x & 63;
  const int q = lane >> 4, ll = lane & 15;
  const int llperm = ((ll >> 2) * (MT * 4)) + (ll & 3);  // permuted col offset
#pragma unroll
  for (int ks = 0; ks < 8; ++ks) {
    bf16x8 a[MT];
#pragma unroll
    for (int mt = 0; mt < MT; ++mt) {
      int oc = colBase + llperm + mt * 4;
      a[mt] = *(const bf16x8*)((const char*)WT + ((long)oc << 9) + (ks << 6) + (q << 4));
    }
    bf16x8 b[8];
#pragma unroll
    for (int nt = 0; nt < 8; ++nt)
      b[nt] = *(const bf16x8*)(smc + (nt * 16 + ll) * SM_PITCH + (ks << 6) + (q << 4));
#pragma unroll
    for (int mt = 0; mt < MT; ++mt)
#pragma unroll
      for (int nt = 0; nt < 8; ++nt)
        acc[mt][nt] = __builtin_amdgcn_mfma_f32_16x16x32_bf16(a[mt], b[nt], acc[mt][nt], 0, 0, 0);
  }
}

// ---------------------------------------------------------------------------
// Fused edge kernel (CSR row order).
// MODE 0 (first layer): build e0 in LDS from eaC; agg walk; epilogue; writeback
// MODE 1 (mid layers):  stage e;                 agg walk; epilogue; writeback
// MODE 2 (final):       stage e; epilogue; fused MLP head -> out (no writeback)
// Agg walk (MODE<2): thread c sums sigmoid(e_old[row][c]) * XW2[src[row]][c]
// over dst-runs (dst-sorted rows -> uniform branch), one atomicAdd per run.
// Epilogue: e_new = e_old + relu(eWe + XWs[src] + XWt[dst] + be) written into
// the LDS tile in place, then coalesced full-line NT writeback.
// ---------------------------------------------------------------------------
template <int MODE>
__global__ __launch_bounds__(256, 2) void k_edge(
    unsigned short* __restrict__ e, const unsigned short* __restrict__ WT,
    const unsigned short* __restrict__ XW, int xw_pitch, int xs_off, int xt_off,
    int x2_off, const unsigned short* __restrict__ bePtr,
    const unsigned short* __restrict__ arena, const unsigned short* __restrict__ eaC,
    const int* __restrict__ csrc, const int* __restrict__ cdst,
    float* __restrict__ agg, const unsigned short* __restrict__ Wm1T,
    const int* __restrict__ eid, const int* __restrict__ flag,
    void* __restrict__ out) {
  __shared__ int4 sm4[128 * 33];
  __shared__ int s_src[128];
  __shared__ int s_dst[128];
  char* smc = (char*)sm4;
  const long tileBase = (long)blockIdx.x * 128;
  const int tid = threadIdx.x;
  const int wave = tid >> 6, lane = tid & 63;
  const int q = lane >> 4, ll = lane & 15;
  const int colBase = wave * 64;

  if (MODE == 0) {
#pragma unroll
    for (int it = 0; it < 16; ++it) {
      int lin = it * 256 + tid;
      int row = lin >> 5, g = lin & 31;
      float eav = bf2f(eaC[tileBase + row]);
      int c0 = g * 8;
      bf16x8 ov;
#pragma unroll
      for (int j = 0; j < 8; ++j) {
        float f = fmaf(eav, bf2f(arena[A_WA + c0 + j]), bf2f(arena[A_BA + c0 + j]));
        ((unsigned short*)&ov)[j] = f2bf(f);
      }
      *(bf16x8*)(smc + row * SM_PITCH + (g << 4)) = ov;
    }
  } else {
    stage_tile<true>(smc, e, tileBase, N_EDGES - 1);
  }
  if (tid < 128) {
    long edge = tileBase + tid;
    int s = csrc[edge]; if ((unsigned)s >= N_NODES) s = 0;
    int d = cdst[edge]; if ((unsigned)d >= N_NODES) d = 0;
    s_src[tid] = s;
    s_dst[tid] = d;
  }
  __syncthreads();

  fp32x4 acc[4][8];
#pragma unroll
  for (int mt = 0; mt < 4; ++mt)
#pragma unroll
    for (int nt = 0; nt < 8; ++nt) acc[mt][nt] = 0.f;
  gemm_swap<4>(smc, WT, colBase, acc);

  if (MODE < 2) {
    // Agg walk over e_old (still intact in LDS). Thread c = tid.
    const int c = tid;
    float a = 0.f;
    int run = s_dst[0];
#pragma unroll 4
    for (int row = 0; row < 128; ++row) {
      int d = s_dst[row];
      if (d != run) {  // uniform across the block (dst-sorted rows)
        atomicAdd(&agg[((long)run << 8) + c], a);
        a = 0.f;
        run = d;
      }
      float ev = bf2f(*(const unsigned short*)(smc + row * SM_PITCH + c * 2));
      float gate = 1.f / (1.f + __expf(-ev));
      float x2 = bf2f(XW[(long)s_src[row] * xw_pitch + x2_off + c]);
      a = fmaf(gate, x2, a);
    }
    atomicAdd(&agg[((long)run << 8) + c], a);
  }
  __syncthreads();  // walk done; safe to overwrite LDS (also orders GEMM reads)

  const int cb = colBase + q * 16;  // this lane's 16 consecutive cols
  float bec[16];
#pragma unroll
  for (int i = 0; i < 16; ++i) bec[i] = bf2f(bePtr[cb + i]);

#pragma unroll
  for (int nt = 0; nt < 8; ++nt) {
    int el = nt * 16 + ll;
    int sn = s_src[el], dn = s_dst[el];
    const unsigned short* xsrow = XW + (long)sn * xw_pitch + xs_off + cb;
    const unsigned short* xtrow = XW + (long)dn * xw_pitch + xt_off + cb;
    u16x8 xs0 = *(const u16x8*)(xsrow);
    u16x8 xs1 = *(const u16x8*)(xsrow + 8);
    u16x8 xt0 = *(const u16x8*)(xtrow);
    u16x8 xt1 = *(const u16x8*)(xtrow + 8);
    u16x8* slot = (u16x8*)(smc + el * SM_PITCH + cb * 2);
    u16x8 er0 = slot[0], er1 = slot[1];
    u16x8 o0, o1;
#pragma unroll
    for (int mt = 0; mt < 4; ++mt)
#pragma unroll
      for (int r = 0; r < 4; ++r) {
        int i = mt * 4 + r;
        float xsv = bf2f(i < 8 ? xs0[i] : xs1[i - 8]);
        float xtv = bf2f(i < 8 ? xt0[i] : xt1[i - 8]);
        float erv = bf2f(i < 8 ? er0[i] : er1[i - 8]);
        float v = acc[mt][nt][r] + xsv + xtv + bec[i];
        v = fmaxf(v, 0.f);
        unsigned short ob = f2bf(erv + v);
        if (i < 8) o0[i] = ob; else o1[i - 8] = ob;
      }
    slot[0] = o0;
    slot[1] = o1;  // e_new into LDS in place (slot owned by this lane only)
  }
  __syncthreads();  // tile fully updated

  if (MODE < 2) {
    // Coalesced full-line writeback: 16B/lane, 1KB contiguous per instruction.
#pragma unroll
    for (int it = 0; it < 16; ++it) {
      int lin = it * 256 + tid;
      int row = lin >> 5, g = lin & 31;
      i32x4 v = *(const i32x4*)(smc + row * SM_PITCH + (g << 4));
      __builtin_nontemporal_store(v, (i32x4*)((char*)e + ((tileBase + row) << 9) + (g << 4)));
    }
  } else {
    // Fused MLP head: h = prelu(e4@Wm1[:256] + eaC*Wm1[256] + bm1); out = h@Wm2+bm2
    fp32x4 acc2[2][8];
#pragma unroll
    for (int mt = 0; mt < 2; ++mt)
#pragma unroll
      for (int nt = 0; nt < 8; ++nt) acc2[mt][nt] = 0.f;
    const int colBase2 = wave * 32;
    gemm_swap<2>(smc, Wm1T, colBase2, acc2);

    const int cb2 = colBase2 + q * 8;  // 8 consecutive out-cols per lane (MT=2)
    float alphaf = bf2f(arena[A_AL]);
    float bmc[8], wl[8], w2c[8];
#pragma unroll
    for (int i = 0; i < 8; ++i) {
      bmc[i] = bf2f(arena[A_BM1 + cb2 + i]);
      wl[i] = bf2f(arena[A_WM1 + 32768 + cb2 + i]);
      w2c[i] = bf2f(arena[A_WM2 + cb2 + i]);
    }
    __syncthreads();             // all waves done reading LDS for gemm2
    float* part = (float*)smc;   // alias tile as [128][4] fp32 partials
#pragma unroll
    for (int nt = 0; nt < 8; ++nt) {
      int el = nt * 16 + ll;
      float eav = bf2f(eaC[tileBase + el]);
      float ps = 0.f;
#pragma unroll
      for (int mt = 0; mt < 2; ++mt)
#pragma unroll
        for (int r = 0; r < 4; ++r) {
          int i = mt * 4 + r;
          float h = acc2[mt][nt][r] + bmc[i] + eav * wl[i];
          h = (h > 0.f) ? h : alphaf * h;
          ps += h * w2c[i];
        }
      ps += __shfl_xor(ps, 16, 64);
      ps += __shfl_xor(ps, 32, 64);
      if (q == 0) part[el * 4 + wave] = ps;
    }
    __syncthreads();
    if (tid < 128) {
      float t = part[tid * 4] + part[tid * 4 + 1] + part[tid * 4 + 2] + part[tid * 4 + 3]
              + bf2f(arena[A_BM2]);
      long row = tileBase + tid;
      int oe = eid[row]; if ((unsigned)oe >= N_EDGES) oe = 0;
      if (*flag) ((float*)out)[oe] = t;
      else       ((unsigned short*)out)[oe] = f2bf(t);
    }
  }
}

// Node-side GEMM: XW = x_bf @ [W1|W2|Ws|Wt] (+b1|b2|0|0), bf16 out.
__global__ __launch_bounds__(256, 2) void k_node_gemm(
    const unsigned short* __restrict__ xbf, const unsigned short* __restrict__ WT,
    const unsigned short* __restrict__ bias, unsigned short* __restrict__ out,
    int out_pitch) {
  __shared__ int4 sm4[128 * 33];
  char* smc = (char*)sm4;
  const long tileBase = (long)blockIdx.x * 128;
  stage_tile<false>(smc, xbf, tileBase, N_NODES - 1);
  __syncthreads();
  fp32x4 acc[4][8];
#pragma unroll
  for (int mt = 0; mt < 4; ++mt)
#pragma unroll
    for (int nt = 0; nt < 8; ++nt) acc[mt][nt] = 0.f;
  const int tid = threadIdx.x, wave = tid >> 6, lane = tid & 63;
  const int q = lane >> 4, ll = lane & 15;
  const int colBase = blockIdx.y * 256 + wave * 64;
  gemm_swap<4>(smc, WT, colBase, acc);

  const int cb = colBase + q * 16;
  float bs[16];
#pragma unroll
  for (int i = 0; i < 16; ++i) bs[i] = bf2f(bias[cb + i]);

#pragma unroll
  for (int nt = 0; nt < 8; ++nt) {
    long nn = tileBase + nt * 16 + ll;
    if (nn >= N_NODES) continue;
    u16x8 o0, o1;
#pragma unroll
    for (int mt = 0; mt < 4; ++mt)
#pragma unroll
      for (int r = 0; r < 4; ++r) {
        int i = mt * 4 + r;
        unsigned short ob = f2bf(acc[mt][nt][r] + bs[i]);
        if (i < 8) o0[i] = ob; else o1[i - 8] = ob;
      }
    unsigned short* orow = out + nn * out_pitch + cb;
    *(u16x8*)(orow) = o0;
    *(u16x8*)(orow + 8) = o1;
  }
}

// x += relu(xW1+b1 + agg); refresh bf16 copy
__global__ void k_node_update(float* __restrict__ xf, unsigned short* __restrict__ xbf,
                              const unsigned short* __restrict__ XW,
                              const float* __restrict__ agg) {
  int n = blockIdx.x, c = threadIdx.x;
  long idx = ((long)n << 8) + c;
  float t = bf2f(XW[((long)n << 10) + c]) + agg[idx];
  float nx = xf[idx] + fmaxf(t, 0.f);
  xf[idx] = nx;
  xbf[idx] = f2bf(nx);
}

// ---------------------------------------------------------------------------
extern "C" void kernel_launch(void* const* d_in, const int* in_sizes, int n_in,
                              void* d_out, int out_size, void* d_ws, size_t ws_size,
                              hipStream_t stream) {
  const int* eidx = (const int*)d_in[2];
  const int* srcA = eidx;
  const int* dstA = eidx + N_EDGES;
  (void)in_sizes; (void)n_in; (void)out_size;

  char* ws = (char*)d_ws;
  size_t off = 0;
  auto alloc = [&](size_t bytes) -> char* {
    char* p = ws + off;
    off = (off + bytes + 255) & ~(size_t)255;
    return p;
  };
  unsigned short* e_buf   = (unsigned short*)alloc((size_t)N_EDGES * 256 * 2);  // 164 MB
  float*          xf      = (float*)alloc((size_t)N_NODES * 256 * 4);
  unsigned short* xbf     = (unsigned short*)alloc((size_t)N_NODES * 256 * 2);
  unsigned short* XW      = (unsigned short*)alloc((size_t)N_NODES * 1024 * 2);
  float*          agg     = (float*)alloc((size_t)N_NODES * 256 * 4);
  unsigned short* nodeBT  = (unsigned short*)alloc((size_t)917504 * 2);
  unsigned short* WeT     = (unsigned short*)alloc((size_t)4 * 65536 * 2);
  unsigned short* Wm1T    = (unsigned short*)alloc((size_t)32768 * 2);
  unsigned short* biascat = (unsigned short*)alloc((size_t)3584 * 2);
  unsigned short* arena   = (unsigned short*)alloc((size_t)ARENA_TOT * 2);
  int* deg    = (int*)alloc((size_t)N_NODES * 4);
  int* rowptr = (int*)alloc((size_t)(N_NODES + 1) * 4);
  int* cursor = (int*)alloc((size_t)N_NODES * 4);
  int* eid    = (int*)alloc((size_t)N_EDGES * 4);
  int* csrc   = (int*)alloc((size_t)N_EDGES * 4);
  int* cdst   = (int*)alloc((size_t)N_EDGES * 4);
  unsigned short* eaC = (unsigned short*)alloc((size_t)N_EDGES * 2);
  int* flag   = (int*)alloc(4);
  if (ws_size < off) return;  // distinctive signature: out stays all-zero

  Ptrs ptrs;
  {
    int map[19] = {0, 1, 3, 4, 5, 6, 7, 8, 9, 10, 11, 12, 13, 14, 15, 16, 17, 18, 19};
    for (int j = 0; j < 19; ++j) ptrs.p[j] = d_in[map[j]];
  }

  dim3 blk(256);
  k_detect<<<dim3(1), blk, 0, stream>>>((const unsigned short*)d_in[3], flag);
  k_cast<<<dim3((ARENA_USED + 255) / 256), blk, 0, stream>>>(ptrs, flag, arena);
  k_prep<<<dim3(256, 1, 20), blk, 0, stream>>>(arena, nodeBT, WeT, Wm1T, biascat);
  k_init_x<<<dim3(N_NODES), blk, 0, stream>>>(arena, xf, xbf);
  hipMemsetAsync(deg, 0, (size_t)N_NODES * 4, stream);
  k_hist<<<dim3(N_EDGES / 256), blk, 0, stream>>>(dstA, deg);
  k_scan<<<dim3(1), blk, 0, stream>>>(deg, rowptr, cursor);
  k_fill<<<dim3(N_EDGES / 256), blk, 0, stream>>>(dstA, srcA, arena, cursor, eid, csrc,
                                                  cdst, eaC);

  for (int l = 0; l < 3; ++l) {
    k_node_gemm<<<dim3(79, 4), blk, 0, stream>>>(xbf, nodeBT + l * 262144,
                                                 biascat + l * 1024, XW, 1024);
    hipMemsetAsync(agg, 0, (size_t)N_NODES * 256 * 4, stream);
    if (l == 0)
      k_edge<0><<<dim3(N_EDGES / 128), blk, 0, stream>>>(
          e_buf, WeT, XW, 1024, 512, 768, 256, arena + A_BE, arena, eaC,
          csrc, cdst, agg, Wm1T, eid, flag, d_out);
    else
      k_edge<1><<<dim3(N_EDGES / 128), blk, 0, stream>>>(
          e_buf, WeT + l * 65536, XW, 1024, 512, 768, 256, arena + A_BE + l * 256,
          arena, eaC, csrc, cdst, agg, Wm1T, eid, flag, d_out);
    k_node_update<<<dim3(N_NODES), blk, 0, stream>>>(xf, xbf, XW, agg);
  }
  // layer 3: edge update + fused MLP head (e4 never materialized)
  k_node_gemm<<<dim3(79, 2), blk, 0, stream>>>(xbf, nodeBT + 786432, biascat + 3072, XW, 512);
  k_edge<2><<<dim3(N_EDGES / 128), blk, 0, stream>>>(
      e_buf, WeT + 196608, XW, 512, 0, 256, 0, arena + A_BE + 768,
      arena, eaC, csrc, cdst, agg, Wm1T, eid, flag, d_out);
}

// Round 9
// 1092.730 us; speedup vs baseline: 1.3149x; 1.3149x over previous
//
#include <hip/hip_runtime.h>
#include <stdint.h>

#define N_NODES 10000
#define N_EDGES 320000

using bf16x8 = __attribute__((ext_vector_type(8))) short;
using fp32x4 = __attribute__((ext_vector_type(4))) float;
using u16x8 = __attribute__((ext_vector_type(8))) unsigned short;
using i32x4 = __attribute__((ext_vector_type(4))) int;

__device__ __forceinline__ float bf2f(unsigned short u) {
  union { unsigned int i; float f; } v; v.i = ((unsigned int)u) << 16; return v.f;
}
__device__ __forceinline__ unsigned short f2bf(float f) {
  union { float f; unsigned int i; } v; v.f = f;
  unsigned int x = v.i;
  x += 0x7fffu + ((x >> 16) & 1u);
  return (unsigned short)(x >> 16);
}

// ---------------- internal bf16 arena (element offsets) ---------------------
#define A_POS 0
#define A_EA 20000
#define A_WP 340000
#define A_BP 340512
#define A_WA 340768
#define A_BA 341024
#define A_W1 341280
#define A_B1 537888
#define A_W2 538656
#define A_B2 735264
#define A_WE 736032
#define A_BE 998176
#define A_WS 999200
#define A_WT 1261344
#define A_WM1 1523488
#define A_BM1 1556384
#define A_AL 1556512
#define A_WM2 1556544
#define A_BM2 1556672
#define ARENA_USED 1556673
#define ARENA_TOT 1556736

__constant__ int g_off[19] = {A_POS, A_EA, A_WP, A_BP, A_WA, A_BA, A_W1, A_B1,
                              A_W2, A_B2, A_WE, A_BE, A_WS, A_WT, A_WM1,
                              A_BM1, A_AL, A_WM2, A_BM2};

struct Ptrs { const void* p[19]; };

// Dtype detector: fp32 read as bf16 halves yields ~47% |v|>100; bf16 never.
__global__ void k_detect(const unsigned short* wpraw, int* flag) {
  __shared__ int cnt;
  int tid = threadIdx.x;
  if (tid == 0) cnt = 0;
  __syncthreads();
  float v0 = bf2f(wpraw[tid]);
  float v1 = bf2f(wpraw[256 + tid]);
  int big = (fabsf(v0) > 100.f ? 1 : 0) + (fabsf(v1) > 100.f ? 1 : 0);
  atomicAdd(&cnt, big);
  __syncthreads();
  if (tid == 0) *flag = (cnt > 10) ? 1 : 0;  // 1 = fp32 inputs
}

// Normalize all float inputs into the bf16 arena (flattened grid).
__global__ void k_cast(Ptrs ptrs, const int* __restrict__ flag,
                       unsigned short* __restrict__ arena) {
  int a = blockIdx.x * 256 + threadIdx.x;
  if (a >= ARENA_USED) return;
  int z = 0;
#pragma unroll
  for (int j = 1; j < 19; ++j) if (a >= g_off[j]) z = j;
  int i = a - g_off[z];
  float v;
  if (*flag) v = ((const float*)ptrs.p[z])[i];
  else       v = bf2f(((const unsigned short*)ptrs.p[z])[i]);
  arena[a] = f2bf(v);
}

// ---------------------------------------------------------------------------
// Weight prep: transpose [K,N] -> n-major [N,K] (row = out-col, 512B rows).
// nodeBT per layer l<3: [W1T|W2T|WsT|WtT] (1024x256); l==3: [WsT|WtT].
// ---------------------------------------------------------------------------
__global__ void k_prep(const unsigned short* __restrict__ arena,
                       unsigned short* nodeBT, unsigned short* WeT,
                       unsigned short* Wm1T, unsigned short* biascat) {
  int z = blockIdx.z;
  int i = blockIdx.x * 256 + threadIdx.x;
  if (z == 19) {  // bias concat: 3 x [b1|b2|0|0] (1024) then 512 zeros
    if (i < 3072) {
      int l = i >> 10, j = i & 1023;
      unsigned short v = 0;
      if (j < 256) v = arena[A_B1 + l * 256 + j];
      else if (j < 512) v = arena[A_B2 + l * 256 + (j - 256)];
      biascat[i] = v;
    } else if (i < 3584) {
      biascat[i] = 0;
    }
    return;
  }
  const unsigned short* src; unsigned short* dst; int srcN = 256;
  if (z < 3)       {                 src = arena + A_W1 + z * 65536; dst = nodeBT + z * 262144; }
  else if (z < 6)  { int l = z - 3;  src = arena + A_W2 + l * 65536; dst = nodeBT + l * 262144 + 65536; }
  else if (z < 10) { int l = z - 6;  src = arena + A_WS + l * 65536;
                     dst = (l < 3) ? nodeBT + l * 262144 + 131072 : nodeBT + 786432; }
  else if (z < 14) { int l = z - 10; src = arena + A_WT + l * 65536;
                     dst = (l < 3) ? nodeBT + l * 262144 + 196608 : nodeBT + 786432 + 65536; }
  else if (z < 18) { int l = z - 14; src = arena + A_WE + l * 65536; dst = WeT + l * 65536; }
  else             { src = arena + A_WM1; dst = Wm1T; srcN = 128; }
  if (i < srcN * 256) {
    int k = i & 255, n = i >> 8;
    dst[i] = src[k * srcN + n];  // dst[n][k] = src[k][n]
  }
}

// x0 = pos @ Wp + bp (K=2), fp32 master + bf16 copy
__global__ void k_init_x(const unsigned short* __restrict__ arena,
                         float* __restrict__ xf, unsigned short* __restrict__ xbf) {
  int n = blockIdx.x, c = threadIdx.x;
  float p0 = bf2f(arena[A_POS + 2 * n]), p1 = bf2f(arena[A_POS + 2 * n + 1]);
  float v = fmaf(p0, bf2f(arena[A_WP + c]),
                 fmaf(p1, bf2f(arena[A_WP + 256 + c]), bf2f(arena[A_BP + c])));
  long idx = ((long)n << 8) + c;
  xf[idx] = v;
  xbf[idx] = f2bf(v);
}

// ---------------- CSR build (by dst). e lives in CSR row order everywhere ---
__global__ void k_hist(const int* __restrict__ dstA, int* __restrict__ deg) {
  int i = blockIdx.x * 256 + threadIdx.x;
  if (i < N_EDGES) {
    int d = dstA[i];
    if ((unsigned)d < N_NODES) atomicAdd(&deg[d], 1);
  }
}

__global__ void k_scan(const int* __restrict__ deg, int* __restrict__ rowptr,
                       int* __restrict__ cursor) {
  __shared__ int part[256];
  int tid = threadIdx.x;
  int base = tid * 40;
  int s = 0;
  for (int i = 0; i < 40; ++i) {
    int idx = base + i;
    if (idx < N_NODES) s += deg[idx];
  }
  part[tid] = s;
  __syncthreads();
  if (tid == 0) {
    int run = 0;
    for (int i = 0; i < 256; ++i) { int t = part[i]; part[i] = run; run += t; }
    rowptr[N_NODES] = run;
  }
  __syncthreads();
  int run = part[tid];
  for (int i = 0; i < 40; ++i) {
    int idx = base + i;
    if (idx < N_NODES) { rowptr[idx] = run; cursor[idx] = run; run += deg[idx]; }
  }
}

// Also emits csrc/cdst (endpoints in CSR order) and eaC (ea gathered to CSR).
__global__ void k_fill(const int* __restrict__ dstA, const int* __restrict__ srcA,
                       const unsigned short* __restrict__ arena,
                       int* __restrict__ cursor, int* __restrict__ eid,
                       int* __restrict__ csrc, int* __restrict__ cdst,
                       unsigned short* __restrict__ eaC) {
  int i = blockIdx.x * 256 + threadIdx.x;
  if (i < N_EDGES) {
    int d = dstA[i]; if ((unsigned)d >= N_NODES) d = 0;
    int p = atomicAdd(&cursor[d], 1);
    if ((unsigned)p < N_EDGES) {
      eid[p] = i;
      int s = srcA[i]; if ((unsigned)s >= N_NODES) s = 0;
      csrc[p] = s;
      cdst[p] = d;
      eaC[p] = arena[A_EA + i];
    }
  }
}

// ---------------------------------------------------------------------------
// Swapped-operand GEMM core with PERMUTED column mapping: A-frag lane ll of
// fragment mt loads WT row oc = colBase + (ll>>2)*(MT*4) + mt*4 + (ll&3).
// Lane (q,ll) reg r of frag mt then holds out-col colBase + q*(MT*4) + mt*4+r
// -> each lane's values cover MT*4 CONSECUTIVE cols (full-line epilogue).
// B-frag: LDS tile row (n=ll). D row = nt*16+ll.
// LDS pitch 528B -> <=2-way bank aliasing (free, m136).
// ---------------------------------------------------------------------------
#define SM_PITCH 528

template <bool NT>
__device__ __forceinline__ void stage_tile(char* smc, const unsigned short* src,
                                           long rowBase, long maxRow) {
  int tid = threadIdx.x;
#pragma unroll
  for (int it = 0; it < 16; ++it) {
    int lin = it * 256 + tid;       // 128 rows x 32 groups of 16B
    int row = lin >> 5, g = lin & 31;
    long rg = rowBase + row;
    if (rg > maxRow) rg = maxRow;
    const i32x4* p = (const i32x4*)((const char*)src + (rg << 9) + (g << 4));
    i32x4 v = NT ? __builtin_nontemporal_load(p) : *p;
    *(i32x4*)(smc + row * SM_PITCH + (g << 4)) = v;
  }
}

template <int MT>
__device__ __forceinline__ void gemm_swap(const char* smc, const unsigned short* WT,
                                          int colBase, fp32x4 (&acc)[MT][8]) {
  const int lane = threadIdx.x & 63;
  const int q = lane >> 4, ll = lane & 15;
  const int llperm = ((ll >> 2) * (MT * 4)) + (ll & 3);  // permuted col offset
#pragma unroll
  for (int ks = 0; ks < 8; ++ks) {
    bf16x8 a[MT];
#pragma unroll
    for (int mt = 0; mt < MT; ++mt) {
      int oc = colBase + llperm + mt * 4;
      a[mt] = *(const bf16x8*)((const char*)WT + ((long)oc << 9) + (ks << 6) + (q << 4));
    }
    bf16x8 b[8];
#pragma unroll
    for (int nt = 0; nt < 8; ++nt)
      b[nt] = *(const bf16x8*)(smc + (nt * 16 + ll) * SM_PITCH + (ks << 6) + (q << 4));
#pragma unroll
    for (int mt = 0; mt < MT; ++mt)
#pragma unroll
      for (int nt = 0; nt < 8; ++nt)
        acc[mt][nt] = __builtin_amdgcn_mfma_f32_16x16x32_bf16(a[mt], b[nt], acc[mt][nt], 0, 0, 0);
  }
}

// ---------------------------------------------------------------------------
// Edge kernel (CSR row order): e_new = e + relu(e@We + XWs[src] + XWt[dst] + be)
// MODE 0: first layer, e0 built in LDS from eaC; writeback.
// MODE 1: mid layers, stage e; writeback.
// MODE 2: final layer: stage e; epilogue keeps e_new in LDS; fused MLP head
//         -> out (e4 never materialized in HBM).
// Epilogue: full-line 2x16B xs/xt gathers (consecutive cols per lane), e_new
// written into the LDS tile in place, then coalesced full-line NT writeback.
// ---------------------------------------------------------------------------
template <int MODE>
__global__ __launch_bounds__(256, 2) void k_edge(
    unsigned short* __restrict__ e, const unsigned short* __restrict__ WT,
    const unsigned short* __restrict__ XW, int xw_pitch, int xs_off, int xt_off,
    const unsigned short* __restrict__ bePtr, const unsigned short* __restrict__ arena,
    const unsigned short* __restrict__ eaC,
    const int* __restrict__ csrc, const int* __restrict__ cdst,
    const unsigned short* __restrict__ Wm1T, const int* __restrict__ eid,
    const int* __restrict__ flag, void* __restrict__ out) {
  __shared__ int4 sm4[128 * 33];
  __shared__ int s_src[128];
  __shared__ int s_dst[128];
  char* smc = (char*)sm4;
  const long tileBase = (long)blockIdx.x * 128;
  const int tid = threadIdx.x;
  const int wave = tid >> 6, lane = tid & 63;
  const int q = lane >> 4, ll = lane & 15;
  const int colBase = wave * 64;

  if (MODE == 0) {
#pragma unroll
    for (int it = 0; it < 16; ++it) {
      int lin = it * 256 + tid;
      int row = lin >> 5, g = lin & 31;
      float eav = bf2f(eaC[tileBase + row]);
      int c0 = g * 8;
      bf16x8 ov;
#pragma unroll
      for (int j = 0; j < 8; ++j) {
        float f = fmaf(eav, bf2f(arena[A_WA + c0 + j]), bf2f(arena[A_BA + c0 + j]));
        ((unsigned short*)&ov)[j] = f2bf(f);
      }
      *(bf16x8*)(smc + row * SM_PITCH + (g << 4)) = ov;
    }
  } else {
    stage_tile<true>(smc, e, tileBase, N_EDGES - 1);
  }
  if (tid < 128) {
    long edge = tileBase + tid;
    int s = csrc[edge]; if ((unsigned)s >= N_NODES) s = 0;
    int d = cdst[edge]; if ((unsigned)d >= N_NODES) d = 0;
    s_src[tid] = s;
    s_dst[tid] = d;
  }
  __syncthreads();

  fp32x4 acc[4][8];
#pragma unroll
  for (int mt = 0; mt < 4; ++mt)
#pragma unroll
    for (int nt = 0; nt < 8; ++nt) acc[mt][nt] = 0.f;
  gemm_swap<4>(smc, WT, colBase, acc);
  __syncthreads();  // all waves done reading A-tile before in-place update

  const int cb = colBase + q * 16;  // this lane's 16 consecutive cols
  float bec[16];
#pragma unroll
  for (int i = 0; i < 16; ++i) bec[i] = bf2f(bePtr[cb + i]);

#pragma unroll
  for (int nt = 0; nt < 8; ++nt) {
    int el = nt * 16 + ll;
    int sn = s_src[el], dn = s_dst[el];
    const unsigned short* xsrow = XW + (long)sn * xw_pitch + xs_off + cb;
    const unsigned short* xtrow = XW + (long)dn * xw_pitch + xt_off + cb;
    u16x8 xs0 = *(const u16x8*)(xsrow);
    u16x8 xs1 = *(const u16x8*)(xsrow + 8);
    u16x8 xt0 = *(const u16x8*)(xtrow);
    u16x8 xt1 = *(const u16x8*)(xtrow + 8);
    u16x8* slot = (u16x8*)(smc + el * SM_PITCH + cb * 2);
    u16x8 er0 = slot[0], er1 = slot[1];
    u16x8 o0, o1;
#pragma unroll
    for (int mt = 0; mt < 4; ++mt)
#pragma unroll
      for (int r = 0; r < 4; ++r) {
        int i = mt * 4 + r;
        float xsv = bf2f(i < 8 ? xs0[i] : xs1[i - 8]);
        float xtv = bf2f(i < 8 ? xt0[i] : xt1[i - 8]);
        float erv = bf2f(i < 8 ? er0[i] : er1[i - 8]);
        float v = acc[mt][nt][r] + xsv + xtv + bec[i];
        v = fmaxf(v, 0.f);
        unsigned short ob = f2bf(erv + v);
        if (i < 8) o0[i] = ob; else o1[i - 8] = ob;
      }
    slot[0] = o0;
    slot[1] = o1;  // e_new into LDS in place (slot owned by this lane only)
  }
  __syncthreads();  // tile fully updated

  if (MODE < 2) {
    // Coalesced full-line writeback: 16B/lane, 1KB contiguous per instruction.
#pragma unroll
    for (int it = 0; it < 16; ++it) {
      int lin = it * 256 + tid;
      int row = lin >> 5, g = lin & 31;
      i32x4 v = *(const i32x4*)(smc + row * SM_PITCH + (g << 4));
      __builtin_nontemporal_store(v, (i32x4*)((char*)e + ((tileBase + row) << 9) + (g << 4)));
    }
  } else {
    // Fused MLP head: h = prelu(e4@Wm1[:256] + eaC*Wm1[256] + bm1); out = h@Wm2+bm2
    fp32x4 acc2[2][8];
#pragma unroll
    for (int mt = 0; mt < 2; ++mt)
#pragma unroll
      for (int nt = 0; nt < 8; ++nt) acc2[mt][nt] = 0.f;
    const int colBase2 = wave * 32;
    gemm_swap<2>(smc, Wm1T, colBase2, acc2);

    const int cb2 = colBase2 + q * 8;  // 8 consecutive out-cols per lane (MT=2)
    float alphaf = bf2f(arena[A_AL]);
    float bmc[8], wl[8], w2c[8];
#pragma unroll
    for (int i = 0; i < 8; ++i) {
      bmc[i] = bf2f(arena[A_BM1 + cb2 + i]);
      wl[i] = bf2f(arena[A_WM1 + 32768 + cb2 + i]);
      w2c[i] = bf2f(arena[A_WM2 + cb2 + i]);
    }
    __syncthreads();             // all waves done reading LDS for gemm2
    float* part = (float*)smc;   // alias tile as [128][4] fp32 partials
#pragma unroll
    for (int nt = 0; nt < 8; ++nt) {
      int el = nt * 16 + ll;
      float eav = bf2f(eaC[tileBase + el]);
      float ps = 0.f;
#pragma unroll
      for (int mt = 0; mt < 2; ++mt)
#pragma unroll
        for (int r = 0; r < 4; ++r) {
          int i = mt * 4 + r;
          float h = acc2[mt][nt][r] + bmc[i] + eav * wl[i];
          h = (h > 0.f) ? h : alphaf * h;
          ps += h * w2c[i];
        }
      ps += __shfl_xor(ps, 16, 64);
      ps += __shfl_xor(ps, 32, 64);
      if (q == 0) part[el * 4 + wave] = ps;
    }
    __syncthreads();
    if (tid < 128) {
      float t = part[tid * 4] + part[tid * 4 + 1] + part[tid * 4 + 2] + part[tid * 4 + 3]
              + bf2f(arena[A_BM2]);
      long row = tileBase + tid;
      int oe = eid[row]; if ((unsigned)oe >= N_EDGES) oe = 0;
      if (*flag) ((float*)out)[oe] = t;
      else       ((unsigned short*)out)[oe] = f2bf(t);
    }
  }
}

// Node-side GEMM: XW = x_bf @ [W1|W2|Ws|Wt] (+b1|b2|0|0), bf16 out.
__global__ __launch_bounds__(256, 2) void k_node_gemm(
    const unsigned short* __restrict__ xbf, const unsigned short* __restrict__ WT,
    const unsigned short* __restrict__ bias, unsigned short* __restrict__ out,
    int out_pitch) {
  __shared__ int4 sm4[128 * 33];
  char* smc = (char*)sm4;
  const long tileBase = (long)blockIdx.x * 128;
  stage_tile<false>(smc, xbf, tileBase, N_NODES - 1);
  __syncthreads();
  fp32x4 acc[4][8];
#pragma unroll
  for (int mt = 0; mt < 4; ++mt)
#pragma unroll
    for (int nt = 0; nt < 8; ++nt) acc[mt][nt] = 0.f;
  const int tid = threadIdx.x, wave = tid >> 6, lane = tid & 63;
  const int q = lane >> 4, ll = lane & 15;
  const int colBase = blockIdx.y * 256 + wave * 64;
  gemm_swap<4>(smc, WT, colBase, acc);

  const int cb = colBase + q * 16;
  float bs[16];
#pragma unroll
  for (int i = 0; i < 16; ++i) bs[i] = bf2f(bias[cb + i]);

#pragma unroll
  for (int nt = 0; nt < 8; ++nt) {
    long nn = tileBase + nt * 16 + ll;
    if (nn >= N_NODES) continue;
    u16x8 o0, o1;
#pragma unroll
    for (int mt = 0; mt < 4; ++mt)
#pragma unroll
      for (int r = 0; r < 4; ++r) {
        int i = mt * 4 + r;
        unsigned short ob = f2bf(acc[mt][nt][r] + bs[i]);
        if (i < 8) o0[i] = ob; else o1[i - 8] = ob;
      }
    unsigned short* orow = out + nn * out_pitch + cb;
    *(u16x8*)(orow) = o0;
    *(u16x8*)(orow + 8) = o1;
  }
}

// ---------------------------------------------------------------------------
// Edge-tiled agg: block = 64 consecutive CSR rows (exact: 320000 = 64*5000).
// Thread c accumulates sigmoid(e[row][c]) * XW2[src[row]][c] over dst-runs
// (dst-sorted rows -> uniform branch), one atomicAdd per run boundary.
// e reads coalesced + nontemporal (protects XW2 L2 residency).
// ---------------------------------------------------------------------------
template <bool FIRST>
__global__ void k_agg(const int* __restrict__ csrc, const int* __restrict__ cdst,
                      const unsigned short* __restrict__ e,
                      const unsigned short* __restrict__ eaC,
                      const unsigned short* __restrict__ arena,
                      const unsigned short* __restrict__ XW, int xw_pitch, int x2_off,
                      float* __restrict__ agg) {
  __shared__ int s_src[64];
  __shared__ int s_dst[64];
  const long base = (long)blockIdx.x * 64;
  const int c = threadIdx.x;
  if (c < 64) {
    long r = base + c;
    int s = csrc[r]; if ((unsigned)s >= N_NODES) s = 0;
    int d = cdst[r]; if ((unsigned)d >= N_NODES) d = 0;
    s_src[c] = s;
    s_dst[c] = d;
  }
  __syncthreads();
  float wac = 0.f, bac = 0.f;
  if (FIRST) { wac = bf2f(arena[A_WA + c]); bac = bf2f(arena[A_BA + c]); }
  float a = 0.f;
  int run = s_dst[0];
#pragma unroll 4
  for (int row = 0; row < 64; ++row) {
    int d = s_dst[row];
    if (d != run) {  // uniform across the block (dst-sorted)
      atomicAdd(&agg[((long)run << 8) + c], a);
      a = 0.f;
      run = d;
    }
    float ev;
    if (FIRST) ev = fmaf(bf2f(eaC[base + row]), wac, bac);
    else ev = bf2f(__builtin_nontemporal_load(e + ((base + row) << 8) + c));
    float gate = 1.f / (1.f + __expf(-ev));
    a = fmaf(gate, bf2f(XW[(long)s_src[row] * xw_pitch + x2_off + c]), a);
  }
  atomicAdd(&agg[((long)run << 8) + c], a);
}

// x += relu(xW1+b1 + agg); refresh bf16 copy
__global__ void k_node_update(float* __restrict__ xf, unsigned short* __restrict__ xbf,
                              const unsigned short* __restrict__ XW,
                              const float* __restrict__ agg) {
  int n = blockIdx.x, c = threadIdx.x;
  long idx = ((long)n << 8) + c;
  float t = bf2f(XW[((long)n << 10) + c]) + agg[idx];
  float nx = xf[idx] + fmaxf(t, 0.f);
  xf[idx] = nx;
  xbf[idx] = f2bf(nx);
}

// ---------------------------------------------------------------------------
extern "C" void kernel_launch(void* const* d_in, const int* in_sizes, int n_in,
                              void* d_out, int out_size, void* d_ws, size_t ws_size,
                              hipStream_t stream) {
  const int* eidx = (const int*)d_in[2];
  const int* srcA = eidx;
  const int* dstA = eidx + N_EDGES;
  (void)in_sizes; (void)n_in; (void)out_size;

  char* ws = (char*)d_ws;
  size_t off = 0;
  auto alloc = [&](size_t bytes) -> char* {
    char* p = ws + off;
    off = (off + bytes + 255) & ~(size_t)255;
    return p;
  };
  unsigned short* e_buf   = (unsigned short*)alloc((size_t)N_EDGES * 256 * 2);  // 164 MB
  float*          xf      = (float*)alloc((size_t)N_NODES * 256 * 4);
  unsigned short* xbf     = (unsigned short*)alloc((size_t)N_NODES * 256 * 2);
  unsigned short* XW      = (unsigned short*)alloc((size_t)N_NODES * 1024 * 2);
  float*          agg     = (float*)alloc((size_t)N_NODES * 256 * 4);
  unsigned short* nodeBT  = (unsigned short*)alloc((size_t)917504 * 2);
  unsigned short* WeT     = (unsigned short*)alloc((size_t)4 * 65536 * 2);
  unsigned short* Wm1T    = (unsigned short*)alloc((size_t)32768 * 2);
  unsigned short* biascat = (unsigned short*)alloc((size_t)3584 * 2);
  unsigned short* arena   = (unsigned short*)alloc((size_t)ARENA_TOT * 2);
  int* deg    = (int*)alloc((size_t)N_NODES * 4);
  int* rowptr = (int*)alloc((size_t)(N_NODES + 1) * 4);
  int* cursor = (int*)alloc((size_t)N_NODES * 4);
  int* eid    = (int*)alloc((size_t)N_EDGES * 4);
  int* csrc   = (int*)alloc((size_t)N_EDGES * 4);
  int* cdst   = (int*)alloc((size_t)N_EDGES * 4);
  unsigned short* eaC = (unsigned short*)alloc((size_t)N_EDGES * 2);
  int* flag   = (int*)alloc(4);
  if (ws_size < off) return;  // distinctive signature: out stays all-zero

  Ptrs ptrs;
  {
    int map[19] = {0, 1, 3, 4, 5, 6, 7, 8, 9, 10, 11, 12, 13, 14, 15, 16, 17, 18, 19};
    for (int j = 0; j < 19; ++j) ptrs.p[j] = d_in[map[j]];
  }

  dim3 blk(256);
  k_detect<<<dim3(1), blk, 0, stream>>>((const unsigned short*)d_in[3], flag);
  k_cast<<<dim3((ARENA_USED + 255) / 256), blk, 0, stream>>>(ptrs, flag, arena);
  k_prep<<<dim3(256, 1, 20), blk, 0, stream>>>(arena, nodeBT, WeT, Wm1T, biascat);
  k_init_x<<<dim3(N_NODES), blk, 0, stream>>>(arena, xf, xbf);
  hipMemsetAsync(deg, 0, (size_t)N_NODES * 4, stream);
  k_hist<<<dim3(N_EDGES / 256), blk, 0, stream>>>(dstA, deg);
  k_scan<<<dim3(1), blk, 0, stream>>>(deg, rowptr, cursor);
  k_fill<<<dim3(N_EDGES / 256), blk, 0, stream>>>(dstA, srcA, arena, cursor, eid, csrc,
                                                  cdst, eaC);

  for (int l = 0; l < 3; ++l) {
    k_node_gemm<<<dim3(79, 4), blk, 0, stream>>>(xbf, nodeBT + l * 262144,
                                                 biascat + l * 1024, XW, 1024);
    hipMemsetAsync(agg, 0, (size_t)N_NODES * 256 * 4, stream);
    if (l == 0)
      k_agg<true><<<dim3(N_EDGES / 64), blk, 0, stream>>>(csrc, cdst, e_buf, eaC, arena,
                                                          XW, 1024, 256, agg);
    else
      k_agg<false><<<dim3(N_EDGES / 64), blk, 0, stream>>>(csrc, cdst, e_buf, eaC, arena,
                                                           XW, 1024, 256, agg);
    if (l == 0)
      k_edge<0><<<dim3(N_EDGES / 128), blk, 0, stream>>>(
          e_buf, WeT, XW, 1024, 512, 768, arena + A_BE, arena, eaC,
          csrc, cdst, Wm1T, eid, flag, d_out);
    else
      k_edge<1><<<dim3(N_EDGES / 128), blk, 0, stream>>>(
          e_buf, WeT + l * 65536, XW, 1024, 512, 768, arena + A_BE + l * 256,
          arena, eaC, csrc, cdst, Wm1T, eid, flag, d_out);
    k_node_update<<<dim3(N_NODES), blk, 0, stream>>>(xf, xbf, XW, agg);
  }
  // layer 3: edge update + fused MLP head (e4 never materialized)
  k_node_gemm<<<dim3(79, 2), blk, 0, stream>>>(xbf, nodeBT + 786432, biascat + 3072, XW, 512);
  k_edge<2><<<dim3(N_EDGES / 128), blk, 0, stream>>>(
      e_buf, WeT + 196608, XW, 512, 0, 256, arena + A_BE + 768,
      arena, eaC, csrc, cdst, Wm1T, eid, flag, d_out);
}

// Round 10
// 1017.692 us; speedup vs baseline: 1.4119x; 1.0737x over previous
//
#include <hip/hip_runtime.h>
#include <stdint.h>

#define N_NODES 10000
#define N_EDGES 320000

using bf16x8 = __attribute__((ext_vector_type(8))) short;
using fp32x4 = __attribute__((ext_vector_type(4))) float;
using u16x8 = __attribute__((ext_vector_type(8))) unsigned short;
using i32x4 = __attribute__((ext_vector_type(4))) int;

__device__ __forceinline__ float bf2f(unsigned short u) {
  union { unsigned int i; float f; } v; v.i = ((unsigned int)u) << 16; return v.f;
}
__device__ __forceinline__ unsigned short f2bf(float f) {
  union { float f; unsigned int i; } v; v.f = f;
  unsigned int x = v.i;
  x += 0x7fffu + ((x >> 16) & 1u);
  return (unsigned short)(x >> 16);
}

// ---------------- internal bf16 arena (element offsets) ---------------------
#define A_POS 0
#define A_EA 20000
#define A_WP 340000
#define A_BP 340512
#define A_WA 340768
#define A_BA 341024
#define A_W1 341280
#define A_B1 537888
#define A_W2 538656
#define A_B2 735264
#define A_WE 736032
#define A_BE 998176
#define A_WS 999200
#define A_WT 1261344
#define A_WM1 1523488
#define A_BM1 1556384
#define A_AL 1556512
#define A_WM2 1556544
#define A_BM2 1556672
#define ARENA_USED 1556673
#define ARENA_TOT 1556736

__constant__ int g_off[19] = {A_POS, A_EA, A_WP, A_BP, A_WA, A_BA, A_W1, A_B1,
                              A_W2, A_B2, A_WE, A_BE, A_WS, A_WT, A_WM1,
                              A_BM1, A_AL, A_WM2, A_BM2};

struct Ptrs { const void* p[19]; };

// Dtype detector: fp32 read as bf16 halves yields ~47% |v|>100; bf16 never.
__global__ void k_detect(const unsigned short* wpraw, int* flag) {
  __shared__ int cnt;
  int tid = threadIdx.x;
  if (tid == 0) cnt = 0;
  __syncthreads();
  float v0 = bf2f(wpraw[tid]);
  float v1 = bf2f(wpraw[256 + tid]);
  int big = (fabsf(v0) > 100.f ? 1 : 0) + (fabsf(v1) > 100.f ? 1 : 0);
  atomicAdd(&cnt, big);
  __syncthreads();
  if (tid == 0) *flag = (cnt > 10) ? 1 : 0;  // 1 = fp32 inputs
}

// Normalize all float inputs into the bf16 arena (flattened grid).
__global__ void k_cast(Ptrs ptrs, const int* __restrict__ flag,
                       unsigned short* __restrict__ arena) {
  int a = blockIdx.x * 256 + threadIdx.x;
  if (a >= ARENA_USED) return;
  int z = 0;
#pragma unroll
  for (int j = 1; j < 19; ++j) if (a >= g_off[j]) z = j;
  int i = a - g_off[z];
  float v;
  if (*flag) v = ((const float*)ptrs.p[z])[i];
  else       v = bf2f(((const unsigned short*)ptrs.p[z])[i]);
  arena[a] = f2bf(v);
}

// ---------------------------------------------------------------------------
// Weight prep: transpose [K,N] -> n-major [N,K] (row = out-col, 512B rows).
// nodeBT per layer l<3: [W1T|W2T|WsT|WtT] (1024x256); l==3: [WsT|WtT].
// ---------------------------------------------------------------------------
__global__ void k_prep(const unsigned short* __restrict__ arena,
                       unsigned short* nodeBT, unsigned short* WeT,
                       unsigned short* Wm1T, unsigned short* biascat) {
  int z = blockIdx.z;
  int i = blockIdx.x * 256 + threadIdx.x;
  if (z == 19) {  // bias concat: 3 x [b1|b2|0|0] (1024) then 512 zeros
    if (i < 3072) {
      int l = i >> 10, j = i & 1023;
      unsigned short v = 0;
      if (j < 256) v = arena[A_B1 + l * 256 + j];
      else if (j < 512) v = arena[A_B2 + l * 256 + (j - 256)];
      biascat[i] = v;
    } else if (i < 3584) {
      biascat[i] = 0;
    }
    return;
  }
  const unsigned short* src; unsigned short* dst; int srcN = 256;
  if (z < 3)       {                 src = arena + A_W1 + z * 65536; dst = nodeBT + z * 262144; }
  else if (z < 6)  { int l = z - 3;  src = arena + A_W2 + l * 65536; dst = nodeBT + l * 262144 + 65536; }
  else if (z < 10) { int l = z - 6;  src = arena + A_WS + l * 65536;
                     dst = (l < 3) ? nodeBT + l * 262144 + 131072 : nodeBT + 786432; }
  else if (z < 14) { int l = z - 10; src = arena + A_WT + l * 65536;
                     dst = (l < 3) ? nodeBT + l * 262144 + 196608 : nodeBT + 786432 + 65536; }
  else if (z < 18) { int l = z - 14; src = arena + A_WE + l * 65536; dst = WeT + l * 65536; }
  else             { src = arena + A_WM1; dst = Wm1T; srcN = 128; }
  if (i < srcN * 256) {
    int k = i & 255, n = i >> 8;
    dst[i] = src[k * srcN + n];  // dst[n][k] = src[k][n]
  }
}

// x0 = pos @ Wp + bp (K=2), fp32 master + bf16 copy
__global__ void k_init_x(const unsigned short* __restrict__ arena,
                         float* __restrict__ xf, unsigned short* __restrict__ xbf) {
  int n = blockIdx.x, c = threadIdx.x;
  float p0 = bf2f(arena[A_POS + 2 * n]), p1 = bf2f(arena[A_POS + 2 * n + 1]);
  float v = fmaf(p0, bf2f(arena[A_WP + c]),
                 fmaf(p1, bf2f(arena[A_WP + 256 + c]), bf2f(arena[A_BP + c])));
  long idx = ((long)n << 8) + c;
  xf[idx] = v;
  xbf[idx] = f2bf(v);
}

// ---------------- CSR build (by dst). e lives in CSR row order everywhere ---
__global__ void k_hist(const int* __restrict__ dstA, int* __restrict__ deg) {
  int i = blockIdx.x * 256 + threadIdx.x;
  if (i < N_EDGES) {
    int d = dstA[i];
    if ((unsigned)d < N_NODES) atomicAdd(&deg[d], 1);
  }
}

__global__ void k_scan(const int* __restrict__ deg, int* __restrict__ rowptr,
                       int* __restrict__ cursor) {
  __shared__ int part[256];
  int tid = threadIdx.x;
  int base = tid * 40;
  int s = 0;
  for (int i = 0; i < 40; ++i) {
    int idx = base + i;
    if (idx < N_NODES) s += deg[idx];
  }
  part[tid] = s;
  __syncthreads();
  if (tid == 0) {
    int run = 0;
    for (int i = 0; i < 256; ++i) { int t = part[i]; part[i] = run; run += t; }
    rowptr[N_NODES] = run;
  }
  __syncthreads();
  int run = part[tid];
  for (int i = 0; i < 40; ++i) {
    int idx = base + i;
    if (idx < N_NODES) { rowptr[idx] = run; cursor[idx] = run; run += deg[idx]; }
  }
}

// Also emits csrc/cdst (endpoints in CSR order) and eaC (ea gathered to CSR).
__global__ void k_fill(const int* __restrict__ dstA, const int* __restrict__ srcA,
                       const unsigned short* __restrict__ arena,
                       int* __restrict__ cursor, int* __restrict__ eid,
                       int* __restrict__ csrc, int* __restrict__ cdst,
                       unsigned short* __restrict__ eaC) {
  int i = blockIdx.x * 256 + threadIdx.x;
  if (i < N_EDGES) {
    int d = dstA[i]; if ((unsigned)d >= N_NODES) d = 0;
    int p = atomicAdd(&cursor[d], 1);
    if ((unsigned)p < N_EDGES) {
      eid[p] = i;
      int s = srcA[i]; if ((unsigned)s >= N_NODES) s = 0;
      csrc[p] = s;
      cdst[p] = d;
      eaC[p] = arena[A_EA + i];
    }
  }
}

// ---------------------------------------------------------------------------
// Swapped-operand GEMM core with PERMUTED column mapping: A-frag lane ll of
// fragment mt loads WT row oc = colBase + (ll>>2)*(MT*4) + mt*4 + (ll&3).
// Lane (q,ll) reg r of frag mt then holds out-col colBase + q*(MT*4) + mt*4+r
// -> each lane's values cover MT*4 CONSECUTIVE cols (full-line epilogue).
// B-frag: LDS tile row (n=ll). D row = nt*16+ll. NTT = row-tiles (rows/16).
// LDS pitch 528B -> <=2-way bank aliasing (free, m136).
// ---------------------------------------------------------------------------
#define SM_PITCH 528
#define TROWS 64                 // edge tile rows; 320000 = 64*5000 exact
#define EDGE_GRID (N_EDGES / TROWS)

template <bool NT, int ROWS>
__device__ __forceinline__ void stage_tile(char* smc, const unsigned short* src,
                                           long rowBase) {
  int tid = threadIdx.x;
#pragma unroll
  for (int it = 0; it < ROWS / 8; ++it) {   // ROWS rows x 32 groups of 16B
    int lin = it * 256 + tid;
    int row = lin >> 5, g = lin & 31;
    const i32x4* p = (const i32x4*)((const char*)src + ((rowBase + row) << 9) + (g << 4));
    i32x4 v = NT ? __builtin_nontemporal_load(p) : *p;
    *(i32x4*)(smc + row * SM_PITCH + (g << 4)) = v;
  }
}

template <int MT, int NTT>
__device__ __forceinline__ void gemm_swap(const char* smc, const unsigned short* WT,
                                          int colBase, fp32x4 (&acc)[MT][NTT]) {
  const int lane = threadIdx.x & 63;
  const int q = lane >> 4, ll = lane & 15;
  const int llperm = ((ll >> 2) * (MT * 4)) + (ll & 3);  // permuted col offset
#pragma unroll
  for (int ks = 0; ks < 8; ++ks) {
    bf16x8 a[MT];
#pragma unroll
    for (int mt = 0; mt < MT; ++mt) {
      int oc = colBase + llperm + mt * 4;
      a[mt] = *(const bf16x8*)((const char*)WT + ((long)oc << 9) + (ks << 6) + (q << 4));
    }
    bf16x8 b[NTT];
#pragma unroll
    for (int nt = 0; nt < NTT; ++nt)
      b[nt] = *(const bf16x8*)(smc + (nt * 16 + ll) * SM_PITCH + (ks << 6) + (q << 4));
#pragma unroll
    for (int mt = 0; mt < MT; ++mt)
#pragma unroll
      for (int nt = 0; nt < NTT; ++nt)
        acc[mt][nt] = __builtin_amdgcn_mfma_f32_16x16x32_bf16(a[mt], b[nt], acc[mt][nt], 0, 0, 0);
  }
}

// ---------------------------------------------------------------------------
// Edge kernel (CSR row order), 64-row tiles: acc[4][4]=64 AGPR + 33.8KB LDS
// -> 3 waves/SIMD occupancy (vs 2 at 128-row tiles).
// MODE 0: first layer, e0 built in LDS from eaC; writeback.
// MODE 1: mid layers, stage e; writeback.
// MODE 2: final: stage e; epilogue keeps e_new in LDS; fused MLP head -> out.
// ---------------------------------------------------------------------------
template <int MODE>
__global__ __launch_bounds__(256, 3) void k_edge(
    unsigned short* __restrict__ e, const unsigned short* __restrict__ WT,
    const unsigned short* __restrict__ XW, int xw_pitch, int xs_off, int xt_off,
    const unsigned short* __restrict__ bePtr, const unsigned short* __restrict__ arena,
    const unsigned short* __restrict__ eaC,
    const int* __restrict__ csrc, const int* __restrict__ cdst,
    const unsigned short* __restrict__ Wm1T, const int* __restrict__ eid,
    const int* __restrict__ flag, void* __restrict__ out) {
  __shared__ int4 sm4[TROWS * 33];
  __shared__ int s_src[TROWS];
  __shared__ int s_dst[TROWS];
  char* smc = (char*)sm4;
  const long tileBase = (long)blockIdx.x * TROWS;
  const int tid = threadIdx.x;
  const int wave = tid >> 6, lane = tid & 63;
  const int q = lane >> 4, ll = lane & 15;
  const int colBase = wave * 64;

  if (MODE == 0) {
#pragma unroll
    for (int it = 0; it < TROWS / 8; ++it) {
      int lin = it * 256 + tid;
      int row = lin >> 5, g = lin & 31;
      float eav = bf2f(eaC[tileBase + row]);
      int c0 = g * 8;
      bf16x8 ov;
#pragma unroll
      for (int j = 0; j < 8; ++j) {
        float f = fmaf(eav, bf2f(arena[A_WA + c0 + j]), bf2f(arena[A_BA + c0 + j]));
        ((unsigned short*)&ov)[j] = f2bf(f);
      }
      *(bf16x8*)(smc + row * SM_PITCH + (g << 4)) = ov;
    }
  } else {
    stage_tile<true, TROWS>(smc, e, tileBase);
  }
  if (tid < TROWS) {
    long edge = tileBase + tid;
    int s = csrc[edge]; if ((unsigned)s >= N_NODES) s = 0;
    int d = cdst[edge]; if ((unsigned)d >= N_NODES) d = 0;
    s_src[tid] = s;
    s_dst[tid] = d;
  }
  __syncthreads();

  fp32x4 acc[4][TROWS / 16];
#pragma unroll
  for (int mt = 0; mt < 4; ++mt)
#pragma unroll
    for (int nt = 0; nt < TROWS / 16; ++nt) acc[mt][nt] = 0.f;
  gemm_swap<4, TROWS / 16>(smc, WT, colBase, acc);
  __syncthreads();  // all waves done reading A-tile before in-place update

  const int cb = colBase + q * 16;  // this lane's 16 consecutive cols
  float bec[16];
#pragma unroll
  for (int i = 0; i < 16; ++i) bec[i] = bf2f(bePtr[cb + i]);

#pragma unroll
  for (int nt = 0; nt < TROWS / 16; ++nt) {
    int el = nt * 16 + ll;
    int sn = s_src[el], dn = s_dst[el];
    const unsigned short* xsrow = XW + (long)sn * xw_pitch + xs_off + cb;
    const unsigned short* xtrow = XW + (long)dn * xw_pitch + xt_off + cb;
    u16x8 xs0 = *(const u16x8*)(xsrow);
    u16x8 xs1 = *(const u16x8*)(xsrow + 8);
    u16x8 xt0 = *(const u16x8*)(xtrow);
    u16x8 xt1 = *(const u16x8*)(xtrow + 8);
    u16x8* slot = (u16x8*)(smc + el * SM_PITCH + cb * 2);
    u16x8 er0 = slot[0], er1 = slot[1];
    u16x8 o0, o1;
#pragma unroll
    for (int mt = 0; mt < 4; ++mt)
#pragma unroll
      for (int r = 0; r < 4; ++r) {
        int i = mt * 4 + r;
        float xsv = bf2f(i < 8 ? xs0[i] : xs1[i - 8]);
        float xtv = bf2f(i < 8 ? xt0[i] : xt1[i - 8]);
        float erv = bf2f(i < 8 ? er0[i] : er1[i - 8]);
        float v = acc[mt][nt][r] + xsv + xtv + bec[i];
        v = fmaxf(v, 0.f);
        unsigned short ob = f2bf(erv + v);
        if (i < 8) o0[i] = ob; else o1[i - 8] = ob;
      }
    slot[0] = o0;
    slot[1] = o1;  // e_new into LDS in place (slot owned by this lane only)
  }
  __syncthreads();  // tile fully updated

  if (MODE < 2) {
    // Coalesced full-line writeback: 16B/lane, 1KB contiguous per instruction.
#pragma unroll
    for (int it = 0; it < TROWS / 8; ++it) {
      int lin = it * 256 + tid;
      int row = lin >> 5, g = lin & 31;
      i32x4 v = *(const i32x4*)(smc + row * SM_PITCH + (g << 4));
      __builtin_nontemporal_store(v, (i32x4*)((char*)e + ((tileBase + row) << 9) + (g << 4)));
    }
  } else {
    // Fused MLP head: h = prelu(e4@Wm1[:256] + eaC*Wm1[256] + bm1); out = h@Wm2+bm2
    fp32x4 acc2[2][TROWS / 16];
#pragma unroll
    for (int mt = 0; mt < 2; ++mt)
#pragma unroll
      for (int nt = 0; nt < TROWS / 16; ++nt) acc2[mt][nt] = 0.f;
    const int colBase2 = wave * 32;
    gemm_swap<2, TROWS / 16>(smc, Wm1T, colBase2, acc2);

    const int cb2 = colBase2 + q * 8;  // 8 consecutive out-cols per lane (MT=2)
    float alphaf = bf2f(arena[A_AL]);
    float bmc[8], wl[8], w2c[8];
#pragma unroll
    for (int i = 0; i < 8; ++i) {
      bmc[i] = bf2f(arena[A_BM1 + cb2 + i]);
      wl[i] = bf2f(arena[A_WM1 + 32768 + cb2 + i]);
      w2c[i] = bf2f(arena[A_WM2 + cb2 + i]);
    }
    __syncthreads();             // all waves done reading LDS for gemm2
    float* part = (float*)smc;   // alias tile as [TROWS][4] fp32 partials
#pragma unroll
    for (int nt = 0; nt < TROWS / 16; ++nt) {
      int el = nt * 16 + ll;
      float eav = bf2f(eaC[tileBase + el]);
      float ps = 0.f;
#pragma unroll
      for (int mt = 0; mt < 2; ++mt)
#pragma unroll
        for (int r = 0; r < 4; ++r) {
          int i = mt * 4 + r;
          float h = acc2[mt][nt][r] + bmc[i] + eav * wl[i];
          h = (h > 0.f) ? h : alphaf * h;
          ps += h * w2c[i];
        }
      ps += __shfl_xor(ps, 16, 64);
      ps += __shfl_xor(ps, 32, 64);
      if (q == 0) part[el * 4 + wave] = ps;
    }
    __syncthreads();
    if (tid < TROWS) {
      float t = part[tid * 4] + part[tid * 4 + 1] + part[tid * 4 + 2] + part[tid * 4 + 3]
              + bf2f(arena[A_BM2]);
      long row = tileBase + tid;
      int oe = eid[row]; if ((unsigned)oe >= N_EDGES) oe = 0;
      if (*flag) ((float*)out)[oe] = t;
      else       ((unsigned short*)out)[oe] = f2bf(t);
    }
  }
}

// Node-side GEMM: XW = x_bf @ [W1|W2|Ws|Wt] (+b1|b2|0|0), bf16 out (128-row).
__global__ __launch_bounds__(256, 2) void k_node_gemm(
    const unsigned short* __restrict__ xbf, const unsigned short* __restrict__ WT,
    const unsigned short* __restrict__ bias, unsigned short* __restrict__ out,
    int out_pitch) {
  __shared__ int4 sm4[128 * 33];
  char* smc = (char*)sm4;
  const long tileBase = (long)blockIdx.x * 128;
  // clamped staging (10000 rows not divisible by 128)
  {
    int tid = threadIdx.x;
#pragma unroll
    for (int it = 0; it < 16; ++it) {
      int lin = it * 256 + tid;
      int row = lin >> 5, g = lin & 31;
      long rg = tileBase + row;
      if (rg > N_NODES - 1) rg = N_NODES - 1;
      i32x4 v = *(const i32x4*)((const char*)xbf + (rg << 9) + (g << 4));
      *(i32x4*)(smc + row * SM_PITCH + (g << 4)) = v;
    }
  }
  __syncthreads();
  fp32x4 acc[4][8];
#pragma unroll
  for (int mt = 0; mt < 4; ++mt)
#pragma unroll
    for (int nt = 0; nt < 8; ++nt) acc[mt][nt] = 0.f;
  const int tid = threadIdx.x, wave = tid >> 6, lane = tid & 63;
  const int q = lane >> 4, ll = lane & 15;
  const int colBase = blockIdx.y * 256 + wave * 64;
  gemm_swap<4, 8>(smc, WT, colBase, acc);

  const int cb = colBase + q * 16;
  float bs[16];
#pragma unroll
  for (int i = 0; i < 16; ++i) bs[i] = bf2f(bias[cb + i]);

#pragma unroll
  for (int nt = 0; nt < 8; ++nt) {
    long nn = tileBase + nt * 16 + ll;
    if (nn >= N_NODES) continue;
    u16x8 o0, o1;
#pragma unroll
    for (int mt = 0; mt < 4; ++mt)
#pragma unroll
      for (int r = 0; r < 4; ++r) {
        int i = mt * 4 + r;
        unsigned short ob = f2bf(acc[mt][nt][r] + bs[i]);
        if (i < 8) o0[i] = ob; else o1[i - 8] = ob;
      }
    unsigned short* orow = out + nn * out_pitch + cb;
    *(u16x8*)(orow) = o0;
    *(u16x8*)(orow + 8) = o1;
  }
}

// ---------------------------------------------------------------------------
// Edge-tiled agg: block = 64 consecutive CSR rows. Loads batched 8-wide ahead
// of the run-boundary branch so they pipeline (r8 lesson: branch-interleaved
// loads serialize at ~700cyc/row). One atomicAdd per dst-run boundary.
// ---------------------------------------------------------------------------
template <bool FIRST>
__global__ void k_agg(const int* __restrict__ csrc, const int* __restrict__ cdst,
                      const unsigned short* __restrict__ e,
                      const unsigned short* __restrict__ eaC,
                      const unsigned short* __restrict__ arena,
                      const unsigned short* __restrict__ XW, int xw_pitch, int x2_off,
                      float* __restrict__ agg) {
  __shared__ int s_src[64];
  __shared__ int s_dst[64];
  const long base = (long)blockIdx.x * 64;
  const int c = threadIdx.x;
  if (c < 64) {
    long r = base + c;
    int s = csrc[r]; if ((unsigned)s >= N_NODES) s = 0;
    int d = cdst[r]; if ((unsigned)d >= N_NODES) d = 0;
    s_src[c] = s;
    s_dst[c] = d;
  }
  __syncthreads();
  float wac = 0.f, bac = 0.f;
  if (FIRST) { wac = bf2f(arena[A_WA + c]); bac = bf2f(arena[A_BA + c]); }
  float a = 0.f;
  int run = s_dst[0];
  for (int b8 = 0; b8 < 64; b8 += 8) {
    float evv[8], x2v[8];
#pragma unroll
    for (int j = 0; j < 8; ++j) {
      int row = b8 + j;
      if (FIRST) evv[j] = fmaf(bf2f(eaC[base + row]), wac, bac);
      else evv[j] = bf2f(__builtin_nontemporal_load(e + ((base + row) << 8) + c));
      x2v[j] = bf2f(XW[(long)s_src[row] * xw_pitch + x2_off + c]);
    }
#pragma unroll
    for (int j = 0; j < 8; ++j) {
      int d = s_dst[b8 + j];
      if (d != run) {  // uniform across the block (dst-sorted)
        atomicAdd(&agg[((long)run << 8) + c], a);
        a = 0.f;
        run = d;
      }
      float gate = 1.f / (1.f + __expf(-evv[j]));
      a = fmaf(gate, x2v[j], a);
    }
  }
  atomicAdd(&agg[((long)run << 8) + c], a);
}

// x += relu(xW1+b1 + agg); refresh bf16 copy
__global__ void k_node_update(float* __restrict__ xf, unsigned short* __restrict__ xbf,
                              const unsigned short* __restrict__ XW,
                              const float* __restrict__ agg) {
  int n = blockIdx.x, c = threadIdx.x;
  long idx = ((long)n << 8) + c;
  float t = bf2f(XW[((long)n << 10) + c]) + agg[idx];
  float nx = xf[idx] + fmaxf(t, 0.f);
  xf[idx] = nx;
  xbf[idx] = f2bf(nx);
}

// ---------------------------------------------------------------------------
extern "C" void kernel_launch(void* const* d_in, const int* in_sizes, int n_in,
                              void* d_out, int out_size, void* d_ws, size_t ws_size,
                              hipStream_t stream) {
  const int* eidx = (const int*)d_in[2];
  const int* srcA = eidx;
  const int* dstA = eidx + N_EDGES;
  (void)in_sizes; (void)n_in; (void)out_size;

  char* ws = (char*)d_ws;
  size_t off = 0;
  auto alloc = [&](size_t bytes) -> char* {
    char* p = ws + off;
    off = (off + bytes + 255) & ~(size_t)255;
    return p;
  };
  unsigned short* e_buf   = (unsigned short*)alloc((size_t)N_EDGES * 256 * 2);  // 164 MB
  float*          xf      = (float*)alloc((size_t)N_NODES * 256 * 4);
  unsigned short* xbf     = (unsigned short*)alloc((size_t)N_NODES * 256 * 2);
  unsigned short* XW      = (unsigned short*)alloc((size_t)N_NODES * 1024 * 2);
  float*          agg     = (float*)alloc((size_t)N_NODES * 256 * 4);
  unsigned short* nodeBT  = (unsigned short*)alloc((size_t)917504 * 2);
  unsigned short* WeT     = (unsigned short*)alloc((size_t)4 * 65536 * 2);
  unsigned short* Wm1T    = (unsigned short*)alloc((size_t)32768 * 2);
  unsigned short* biascat = (unsigned short*)alloc((size_t)3584 * 2);
  unsigned short* arena   = (unsigned short*)alloc((size_t)ARENA_TOT * 2);
  int* deg    = (int*)alloc((size_t)N_NODES * 4);
  int* rowptr = (int*)alloc((size_t)(N_NODES + 1) * 4);
  int* cursor = (int*)alloc((size_t)N_NODES * 4);
  int* eid    = (int*)alloc((size_t)N_EDGES * 4);
  int* csrc   = (int*)alloc((size_t)N_EDGES * 4);
  int* cdst   = (int*)alloc((size_t)N_EDGES * 4);
  unsigned short* eaC = (unsigned short*)alloc((size_t)N_EDGES * 2);
  int* flag   = (int*)alloc(4);
  if (ws_size < off) return;  // distinctive signature: out stays all-zero

  Ptrs ptrs;
  {
    int map[19] = {0, 1, 3, 4, 5, 6, 7, 8, 9, 10, 11, 12, 13, 14, 15, 16, 17, 18, 19};
    for (int j = 0; j < 19; ++j) ptrs.p[j] = d_in[map[j]];
  }

  dim3 blk(256);
  k_detect<<<dim3(1), blk, 0, stream>>>((const unsigned short*)d_in[3], flag);
  k_cast<<<dim3((ARENA_USED + 255) / 256), blk, 0, stream>>>(ptrs, flag, arena);
  k_prep<<<dim3(256, 1, 20), blk, 0, stream>>>(arena, nodeBT, WeT, Wm1T, biascat);
  k_init_x<<<dim3(N_NODES), blk, 0, stream>>>(arena, xf, xbf);
  hipMemsetAsync(deg, 0, (size_t)N_NODES * 4, stream);
  k_hist<<<dim3(N_EDGES / 256), blk, 0, stream>>>(dstA, deg);
  k_scan<<<dim3(1), blk, 0, stream>>>(deg, rowptr, cursor);
  k_fill<<<dim3(N_EDGES / 256), blk, 0, stream>>>(dstA, srcA, arena, cursor, eid, csrc,
                                                  cdst, eaC);

  for (int l = 0; l < 3; ++l) {
    k_node_gemm<<<dim3(79, 4), blk, 0, stream>>>(xbf, nodeBT + l * 262144,
                                                 biascat + l * 1024, XW, 1024);
    hipMemsetAsync(agg, 0, (size_t)N_NODES * 256 * 4, stream);
    if (l == 0)
      k_agg<true><<<dim3(N_EDGES / 64), blk, 0, stream>>>(csrc, cdst, e_buf, eaC, arena,
                                                          XW, 1024, 256, agg);
    else
      k_agg<false><<<dim3(N_EDGES / 64), blk, 0, stream>>>(csrc, cdst, e_buf, eaC, arena,
                                                           XW, 1024, 256, agg);
    if (l == 0)
      k_edge<0><<<dim3(EDGE_GRID), blk, 0, stream>>>(
          e_buf, WeT, XW, 1024, 512, 768, arena + A_BE, arena, eaC,
          csrc, cdst, Wm1T, eid, flag, d_out);
    else
      k_edge<1><<<dim3(EDGE_GRID), blk, 0, stream>>>(
          e_buf, WeT + l * 65536, XW, 1024, 512, 768, arena + A_BE + l * 256,
          arena, eaC, csrc, cdst, Wm1T, eid, flag, d_out);
    k_node_update<<<dim3(N_NODES), blk, 0, stream>>>(xf, xbf, XW, agg);
  }
  // layer 3: edge update + fused MLP head (e4 never materialized)
  k_node_gemm<<<dim3(79, 2), blk, 0, stream>>>(xbf, nodeBT + 786432, biascat + 3072, XW, 512);
  k_edge<2><<<dim3(EDGE_GRID), blk, 0, stream>>>(
      e_buf, WeT + 196608, XW, 512, 0, 256, arena + A_BE + 768,
      arena, eaC, csrc, cdst, Wm1T, eid, flag, d_out);
}

// Round 11
// 1010.837 us; speedup vs baseline: 1.4215x; 1.0068x over previous
//
#include <hip/hip_runtime.h>
#include <stdint.h>

#define N_NODES 10000
#define N_EDGES 320000

using bf16x8 = __attribute__((ext_vector_type(8))) short;
using fp32x4 = __attribute__((ext_vector_type(4))) float;
using u16x8 = __attribute__((ext_vector_type(8))) unsigned short;
using i32x4 = __attribute__((ext_vector_type(4))) int;

__device__ __forceinline__ float bf2f(unsigned short u) {
  union { unsigned int i; float f; } v; v.i = ((unsigned int)u) << 16; return v.f;
}
__device__ __forceinline__ unsigned short f2bf(float f) {
  union { float f; unsigned int i; } v; v.f = f;
  unsigned int x = v.i;
  x += 0x7fffu + ((x >> 16) & 1u);
  return (unsigned short)(x >> 16);
}

// ---------------- internal bf16 arena (element offsets) ---------------------
#define A_POS 0
#define A_EA 20000
#define A_WP 340000
#define A_BP 340512
#define A_WA 340768
#define A_BA 341024
#define A_W1 341280
#define A_B1 537888
#define A_W2 538656
#define A_B2 735264
#define A_WE 736032
#define A_BE 998176
#define A_WS 999200
#define A_WT 1261344
#define A_WM1 1523488
#define A_BM1 1556384
#define A_AL 1556512
#define A_WM2 1556544
#define A_BM2 1556672
#define ARENA_USED 1556673
#define ARENA_TOT 1556736

__constant__ int g_off[19] = {A_POS, A_EA, A_WP, A_BP, A_WA, A_BA, A_W1, A_B1,
                              A_W2, A_B2, A_WE, A_BE, A_WS, A_WT, A_WM1,
                              A_BM1, A_AL, A_WM2, A_BM2};

struct Ptrs { const void* p[19]; };

// Dtype detector: fp32 read as bf16 halves yields ~47% |v|>100; bf16 never.
__global__ void k_detect(const unsigned short* wpraw, int* flag) {
  __shared__ int cnt;
  int tid = threadIdx.x;
  if (tid == 0) cnt = 0;
  __syncthreads();
  float v0 = bf2f(wpraw[tid]);
  float v1 = bf2f(wpraw[256 + tid]);
  int big = (fabsf(v0) > 100.f ? 1 : 0) + (fabsf(v1) > 100.f ? 1 : 0);
  atomicAdd(&cnt, big);
  __syncthreads();
  if (tid == 0) *flag = (cnt > 10) ? 1 : 0;  // 1 = fp32 inputs
}

// Normalize all float inputs into the bf16 arena (flattened grid).
__global__ void k_cast(Ptrs ptrs, const int* __restrict__ flag,
                       unsigned short* __restrict__ arena) {
  int a = blockIdx.x * 256 + threadIdx.x;
  if (a >= ARENA_USED) return;
  int z = 0;
#pragma unroll
  for (int j = 1; j < 19; ++j) if (a >= g_off[j]) z = j;
  int i = a - g_off[z];
  float v;
  if (*flag) v = ((const float*)ptrs.p[z])[i];
  else       v = bf2f(((const unsigned short*)ptrs.p[z])[i]);
  arena[a] = f2bf(v);
}

// ---------------------------------------------------------------------------
// Weight prep: transpose [K,N] -> n-major [N,K] (row = out-col, 512B rows).
// nodeBT per layer l<3: [W1T|W2T|WsT|WtT] (1024x256); l==3: [WsT|WtT].
// ---------------------------------------------------------------------------
__global__ void k_prep(const unsigned short* __restrict__ arena,
                       unsigned short* nodeBT, unsigned short* WeT,
                       unsigned short* Wm1T, unsigned short* biascat) {
  int z = blockIdx.z;
  int i = blockIdx.x * 256 + threadIdx.x;
  if (z == 19) {  // bias concat: 3 x [b1|b2|0|0] (1024) then 512 zeros
    if (i < 3072) {
      int l = i >> 10, j = i & 1023;
      unsigned short v = 0;
      if (j < 256) v = arena[A_B1 + l * 256 + j];
      else if (j < 512) v = arena[A_B2 + l * 256 + (j - 256)];
      biascat[i] = v;
    } else if (i < 3584) {
      biascat[i] = 0;
    }
    return;
  }
  const unsigned short* src; unsigned short* dst; int srcN = 256;
  if (z < 3)       {                 src = arena + A_W1 + z * 65536; dst = nodeBT + z * 262144; }
  else if (z < 6)  { int l = z - 3;  src = arena + A_W2 + l * 65536; dst = nodeBT + l * 262144 + 65536; }
  else if (z < 10) { int l = z - 6;  src = arena + A_WS + l * 65536;
                     dst = (l < 3) ? nodeBT + l * 262144 + 131072 : nodeBT + 786432; }
  else if (z < 14) { int l = z - 10; src = arena + A_WT + l * 65536;
                     dst = (l < 3) ? nodeBT + l * 262144 + 196608 : nodeBT + 786432 + 65536; }
  else if (z < 18) { int l = z - 14; src = arena + A_WE + l * 65536; dst = WeT + l * 65536; }
  else             { src = arena + A_WM1; dst = Wm1T; srcN = 128; }
  if (i < srcN * 256) {
    int k = i & 255, n = i >> 8;
    dst[i] = src[k * srcN + n];  // dst[n][k] = src[k][n]
  }
}

// x0 = pos @ Wp + bp (K=2), fp32 master + bf16 copy
__global__ void k_init_x(const unsigned short* __restrict__ arena,
                         float* __restrict__ xf, unsigned short* __restrict__ xbf) {
  int n = blockIdx.x, c = threadIdx.x;
  float p0 = bf2f(arena[A_POS + 2 * n]), p1 = bf2f(arena[A_POS + 2 * n + 1]);
  float v = fmaf(p0, bf2f(arena[A_WP + c]),
                 fmaf(p1, bf2f(arena[A_WP + 256 + c]), bf2f(arena[A_BP + c])));
  long idx = ((long)n << 8) + c;
  xf[idx] = v;
  xbf[idx] = f2bf(v);
}

// ---------------- CSR build (by dst). e lives in CSR row order everywhere ---
__global__ void k_hist(const int* __restrict__ dstA, int* __restrict__ deg) {
  int i = blockIdx.x * 256 + threadIdx.x;
  if (i < N_EDGES) {
    int d = dstA[i];
    if ((unsigned)d < N_NODES) atomicAdd(&deg[d], 1);
  }
}

__global__ void k_scan(const int* __restrict__ deg, int* __restrict__ rowptr,
                       int* __restrict__ cursor) {
  __shared__ int part[256];
  int tid = threadIdx.x;
  int base = tid * 40;
  int s = 0;
  for (int i = 0; i < 40; ++i) {
    int idx = base + i;
    if (idx < N_NODES) s += deg[idx];
  }
  part[tid] = s;
  __syncthreads();
  if (tid == 0) {
    int run = 0;
    for (int i = 0; i < 256; ++i) { int t = part[i]; part[i] = run; run += t; }
    rowptr[N_NODES] = run;
  }
  __syncthreads();
  int run = part[tid];
  for (int i = 0; i < 40; ++i) {
    int idx = base + i;
    if (idx < N_NODES) { rowptr[idx] = run; cursor[idx] = run; run += deg[idx]; }
  }
}

// Also emits csrc/cdst (endpoints in CSR order) and eaC (ea gathered to CSR).
__global__ void k_fill(const int* __restrict__ dstA, const int* __restrict__ srcA,
                       const unsigned short* __restrict__ arena,
                       int* __restrict__ cursor, int* __restrict__ eid,
                       int* __restrict__ csrc, int* __restrict__ cdst,
                       unsigned short* __restrict__ eaC) {
  int i = blockIdx.x * 256 + threadIdx.x;
  if (i < N_EDGES) {
    int d = dstA[i]; if ((unsigned)d >= N_NODES) d = 0;
    int p = atomicAdd(&cursor[d], 1);
    if ((unsigned)p < N_EDGES) {
      eid[p] = i;
      int s = srcA[i]; if ((unsigned)s >= N_NODES) s = 0;
      csrc[p] = s;
      cdst[p] = d;
      eaC[p] = arena[A_EA + i];
    }
  }
}

// ---------------------------------------------------------------------------
// Swapped-operand GEMM core with PERMUTED column mapping: A-frag lane ll of
// fragment mt loads WT row oc = colBase + (ll>>2)*(MT*4) + mt*4 + (ll&3).
// Lane (q,ll) reg r of frag mt then holds out-col colBase + q*(MT*4) + mt*4+r
// -> each lane's values cover MT*4 CONSECUTIVE cols (full-line epilogue).
// B-frag: LDS tile row (n=ll). D row = nt*16+ll. NTT = row-tiles (rows/16).
// LDS pitch 528B -> <=2-way bank aliasing (free, m136).
// ---------------------------------------------------------------------------
#define SM_PITCH 528
#define TROWS 64                 // edge tile rows (MODE 0/1); 320000 = 64*5000
#define EDGE_GRID (N_EDGES / TROWS)

template <bool NT, int ROWS>
__device__ __forceinline__ void stage_tile(char* smc, const unsigned short* src,
                                           long rowBase) {
  int tid = threadIdx.x;
#pragma unroll
  for (int it = 0; it < ROWS / 8; ++it) {   // ROWS rows x 32 groups of 16B
    int lin = it * 256 + tid;
    int row = lin >> 5, g = lin & 31;
    const i32x4* p = (const i32x4*)((const char*)src + ((rowBase + row) << 9) + (g << 4));
    i32x4 v = NT ? __builtin_nontemporal_load(p) : *p;
    *(i32x4*)(smc + row * SM_PITCH + (g << 4)) = v;
  }
}

template <int MT, int NTT>
__device__ __forceinline__ void gemm_swap(const char* smc, const unsigned short* WT,
                                          int colBase, fp32x4 (&acc)[MT][NTT]) {
  const int lane = threadIdx.x & 63;
  const int q = lane >> 4, ll = lane & 15;
  const int llperm = ((ll >> 2) * (MT * 4)) + (ll & 3);  // permuted col offset
#pragma unroll
  for (int ks = 0; ks < 8; ++ks) {
    bf16x8 a[MT];
#pragma unroll
    for (int mt = 0; mt < MT; ++mt) {
      int oc = colBase + llperm + mt * 4;
      a[mt] = *(const bf16x8*)((const char*)WT + ((long)oc << 9) + (ks << 6) + (q << 4));
    }
    bf16x8 b[NTT];
#pragma unroll
    for (int nt = 0; nt < NTT; ++nt)
      b[nt] = *(const bf16x8*)(smc + (nt * 16 + ll) * SM_PITCH + (ks << 6) + (q << 4));
#pragma unroll
    for (int mt = 0; mt < MT; ++mt)
#pragma unroll
      for (int nt = 0; nt < NTT; ++nt)
        acc[mt][nt] = __builtin_amdgcn_mfma_f32_16x16x32_bf16(a[mt], b[nt], acc[mt][nt], 0, 0, 0);
  }
}

// ---------------------------------------------------------------------------
// Edge kernel (CSR row order), 64-row tiles, 4 blocks/CU (64 VGPR + 64 AGPR
// = 128/wave exactly fits 4 waves/EU; LDS 4x34.3KB = 137KB < 160KB).
// MODE 0: first layer, e0 built in LDS from eaC; writeback.
// MODE 1: mid layers, stage e; writeback.
// ---------------------------------------------------------------------------
template <int MODE>
__global__ __launch_bounds__(256, 4) void k_edge(
    unsigned short* __restrict__ e, const unsigned short* __restrict__ WT,
    const unsigned short* __restrict__ XW, int xw_pitch, int xs_off, int xt_off,
    const unsigned short* __restrict__ bePtr, const unsigned short* __restrict__ arena,
    const unsigned short* __restrict__ eaC,
    const int* __restrict__ csrc, const int* __restrict__ cdst) {
  __shared__ int4 sm4[TROWS * 33];
  __shared__ int s_src[TROWS];
  __shared__ int s_dst[TROWS];
  char* smc = (char*)sm4;
  const long tileBase = (long)blockIdx.x * TROWS;
  const int tid = threadIdx.x;
  const int wave = tid >> 6, lane = tid & 63;
  const int q = lane >> 4, ll = lane & 15;
  const int colBase = wave * 64;

  if (MODE == 0) {
#pragma unroll
    for (int it = 0; it < TROWS / 8; ++it) {
      int lin = it * 256 + tid;
      int row = lin >> 5, g = lin & 31;
      float eav = bf2f(eaC[tileBase + row]);
      int c0 = g * 8;
      bf16x8 ov;
#pragma unroll
      for (int j = 0; j < 8; ++j) {
        float f = fmaf(eav, bf2f(arena[A_WA + c0 + j]), bf2f(arena[A_BA + c0 + j]));
        ((unsigned short*)&ov)[j] = f2bf(f);
      }
      *(bf16x8*)(smc + row * SM_PITCH + (g << 4)) = ov;
    }
  } else {
    stage_tile<true, TROWS>(smc, e, tileBase);
  }
  if (tid < TROWS) {
    long edge = tileBase + tid;
    int s = csrc[edge]; if ((unsigned)s >= N_NODES) s = 0;
    int d = cdst[edge]; if ((unsigned)d >= N_NODES) d = 0;
    s_src[tid] = s;
    s_dst[tid] = d;
  }
  __syncthreads();

  fp32x4 acc[4][TROWS / 16];
#pragma unroll
  for (int mt = 0; mt < 4; ++mt)
#pragma unroll
    for (int nt = 0; nt < TROWS / 16; ++nt) acc[mt][nt] = 0.f;
  gemm_swap<4, TROWS / 16>(smc, WT, colBase, acc);
  __syncthreads();  // all waves done reading A-tile before in-place update

  const int cb = colBase + q * 16;  // this lane's 16 consecutive cols
  float bec[16];
#pragma unroll
  for (int i = 0; i < 16; ++i) bec[i] = bf2f(bePtr[cb + i]);

#pragma unroll
  for (int nt = 0; nt < TROWS / 16; ++nt) {
    int el = nt * 16 + ll;
    int sn = s_src[el], dn = s_dst[el];
    const unsigned short* xsrow = XW + (long)sn * xw_pitch + xs_off + cb;
    const unsigned short* xtrow = XW + (long)dn * xw_pitch + xt_off + cb;
    u16x8 xs0 = *(const u16x8*)(xsrow);
    u16x8 xs1 = *(const u16x8*)(xsrow + 8);
    u16x8 xt0 = *(const u16x8*)(xtrow);
    u16x8 xt1 = *(const u16x8*)(xtrow + 8);
    u16x8* slot = (u16x8*)(smc + el * SM_PITCH + cb * 2);
    u16x8 er0 = slot[0], er1 = slot[1];
    u16x8 o0, o1;
#pragma unroll
    for (int mt = 0; mt < 4; ++mt)
#pragma unroll
      for (int r = 0; r < 4; ++r) {
        int i = mt * 4 + r;
        float xsv = bf2f(i < 8 ? xs0[i] : xs1[i - 8]);
        float xtv = bf2f(i < 8 ? xt0[i] : xt1[i - 8]);
        float erv = bf2f(i < 8 ? er0[i] : er1[i - 8]);
        float v = acc[mt][nt][r] + xsv + xtv + bec[i];
        v = fmaxf(v, 0.f);
        unsigned short ob = f2bf(erv + v);
        if (i < 8) o0[i] = ob; else o1[i - 8] = ob;
      }
    slot[0] = o0;
    slot[1] = o1;  // e_new into LDS in place (slot owned by this lane only)
  }
  __syncthreads();  // tile fully updated

  // Coalesced full-line writeback: 16B/lane, 1KB contiguous per instruction.
#pragma unroll
  for (int it = 0; it < TROWS / 8; ++it) {
    int lin = it * 256 + tid;
    int row = lin >> 5, g = lin & 31;
    i32x4 v = *(const i32x4*)(smc + row * SM_PITCH + (g << 4));
    __builtin_nontemporal_store(v, (i32x4*)((char*)e + ((tileBase + row) << 9) + (g << 4)));
  }
}

// ---------------------------------------------------------------------------
// Final edge kernel, 128-row tiles (double-GEMM amortizes fixed latency; the
// 64-row variant measured 173us vs <=143 at 128 rows — r10 post-mortem).
// stage e; epilogue keeps e_new in LDS; fused MLP head -> out.
// ---------------------------------------------------------------------------
__global__ __launch_bounds__(256, 2) void k_edge_final(
    const unsigned short* __restrict__ e, const unsigned short* __restrict__ WT,
    const unsigned short* __restrict__ XW, int xw_pitch, int xs_off, int xt_off,
    const unsigned short* __restrict__ bePtr, const unsigned short* __restrict__ arena,
    const unsigned short* __restrict__ eaC,
    const int* __restrict__ csrc, const int* __restrict__ cdst,
    const unsigned short* __restrict__ Wm1T, const int* __restrict__ eid,
    const int* __restrict__ flag, void* __restrict__ out) {
  __shared__ int4 sm4[128 * 33];
  __shared__ int s_src[128];
  __shared__ int s_dst[128];
  char* smc = (char*)sm4;
  const long tileBase = (long)blockIdx.x * 128;
  const int tid = threadIdx.x;
  const int wave = tid >> 6, lane = tid & 63;
  const int q = lane >> 4, ll = lane & 15;
  const int colBase = wave * 64;

  stage_tile<true, 128>(smc, e, tileBase);
  if (tid < 128) {
    long edge = tileBase + tid;
    int s = csrc[edge]; if ((unsigned)s >= N_NODES) s = 0;
    int d = cdst[edge]; if ((unsigned)d >= N_NODES) d = 0;
    s_src[tid] = s;
    s_dst[tid] = d;
  }
  __syncthreads();

  fp32x4 acc[4][8];
#pragma unroll
  for (int mt = 0; mt < 4; ++mt)
#pragma unroll
    for (int nt = 0; nt < 8; ++nt) acc[mt][nt] = 0.f;
  gemm_swap<4, 8>(smc, WT, colBase, acc);
  __syncthreads();  // all waves done reading A-tile before in-place update

  const int cb = colBase + q * 16;
  float bec[16];
#pragma unroll
  for (int i = 0; i < 16; ++i) bec[i] = bf2f(bePtr[cb + i]);

#pragma unroll
  for (int nt = 0; nt < 8; ++nt) {
    int el = nt * 16 + ll;
    int sn = s_src[el], dn = s_dst[el];
    const unsigned short* xsrow = XW + (long)sn * xw_pitch + xs_off + cb;
    const unsigned short* xtrow = XW + (long)dn * xw_pitch + xt_off + cb;
    u16x8 xs0 = *(const u16x8*)(xsrow);
    u16x8 xs1 = *(const u16x8*)(xsrow + 8);
    u16x8 xt0 = *(const u16x8*)(xtrow);
    u16x8 xt1 = *(const u16x8*)(xtrow + 8);
    u16x8* slot = (u16x8*)(smc + el * SM_PITCH + cb * 2);
    u16x8 er0 = slot[0], er1 = slot[1];
    u16x8 o0, o1;
#pragma unroll
    for (int mt = 0; mt < 4; ++mt)
#pragma unroll
      for (int r = 0; r < 4; ++r) {
        int i = mt * 4 + r;
        float xsv = bf2f(i < 8 ? xs0[i] : xs1[i - 8]);
        float xtv = bf2f(i < 8 ? xt0[i] : xt1[i - 8]);
        float erv = bf2f(i < 8 ? er0[i] : er1[i - 8]);
        float v = acc[mt][nt][r] + xsv + xtv + bec[i];
        v = fmaxf(v, 0.f);
        unsigned short ob = f2bf(erv + v);
        if (i < 8) o0[i] = ob; else o1[i - 8] = ob;
      }
    slot[0] = o0;
    slot[1] = o1;
  }
  __syncthreads();  // tile fully updated (e4 stays in LDS only)

  // Fused MLP head: h = prelu(e4@Wm1[:256] + eaC*Wm1[256] + bm1); out = h@Wm2+bm2
  fp32x4 acc2[2][8];
#pragma unroll
  for (int mt = 0; mt < 2; ++mt)
#pragma unroll
    for (int nt = 0; nt < 8; ++nt) acc2[mt][nt] = 0.f;
  const int colBase2 = wave * 32;
  gemm_swap<2, 8>(smc, Wm1T, colBase2, acc2);

  const int cb2 = colBase2 + q * 8;  // 8 consecutive out-cols per lane (MT=2)
  float alphaf = bf2f(arena[A_AL]);
  float bmc[8], wl[8], w2c[8];
#pragma unroll
  for (int i = 0; i < 8; ++i) {
    bmc[i] = bf2f(arena[A_BM1 + cb2 + i]);
    wl[i] = bf2f(arena[A_WM1 + 32768 + cb2 + i]);
    w2c[i] = bf2f(arena[A_WM2 + cb2 + i]);
  }
  __syncthreads();             // all waves done reading LDS for gemm2
  float* part = (float*)smc;   // alias tile as [128][4] fp32 partials
#pragma unroll
  for (int nt = 0; nt < 8; ++nt) {
    int el = nt * 16 + ll;
    float eav = bf2f(eaC[tileBase + el]);
    float ps = 0.f;
#pragma unroll
    for (int mt = 0; mt < 2; ++mt)
#pragma unroll
      for (int r = 0; r < 4; ++r) {
        int i = mt * 4 + r;
        float h = acc2[mt][nt][r] + bmc[i] + eav * wl[i];
        h = (h > 0.f) ? h : alphaf * h;
        ps += h * w2c[i];
      }
    ps += __shfl_xor(ps, 16, 64);
    ps += __shfl_xor(ps, 32, 64);
    if (q == 0) part[el * 4 + wave] = ps;
  }
  __syncthreads();
  if (tid < 128) {
    float t = part[tid * 4] + part[tid * 4 + 1] + part[tid * 4 + 2] + part[tid * 4 + 3]
            + bf2f(arena[A_BM2]);
    long row = tileBase + tid;
    int oe = eid[row]; if ((unsigned)oe >= N_EDGES) oe = 0;
    if (*flag) ((float*)out)[oe] = t;
    else       ((unsigned short*)out)[oe] = f2bf(t);
  }
}

// Node-side GEMM: XW = x_bf @ [W1|W2|Ws|Wt] (+b1|b2|0|0), bf16 out (128-row).
__global__ __launch_bounds__(256, 2) void k_node_gemm(
    const unsigned short* __restrict__ xbf, const unsigned short* __restrict__ WT,
    const unsigned short* __restrict__ bias, unsigned short* __restrict__ out,
    int out_pitch) {
  __shared__ int4 sm4[128 * 33];
  char* smc = (char*)sm4;
  const long tileBase = (long)blockIdx.x * 128;
  // clamped staging (10000 rows not divisible by 128)
  {
    int tid = threadIdx.x;
#pragma unroll
    for (int it = 0; it < 16; ++it) {
      int lin = it * 256 + tid;
      int row = lin >> 5, g = lin & 31;
      long rg = tileBase + row;
      if (rg > N_NODES - 1) rg = N_NODES - 1;
      i32x4 v = *(const i32x4*)((const char*)xbf + (rg << 9) + (g << 4));
      *(i32x4*)(smc + row * SM_PITCH + (g << 4)) = v;
    }
  }
  __syncthreads();
  fp32x4 acc[4][8];
#pragma unroll
  for (int mt = 0; mt < 4; ++mt)
#pragma unroll
    for (int nt = 0; nt < 8; ++nt) acc[mt][nt] = 0.f;
  const int tid = threadIdx.x, wave = tid >> 6, lane = tid & 63;
  const int q = lane >> 4, ll = lane & 15;
  const int colBase = blockIdx.y * 256 + wave * 64;
  gemm_swap<4, 8>(smc, WT, colBase, acc);

  const int cb = colBase + q * 16;
  float bs[16];
#pragma unroll
  for (int i = 0; i < 16; ++i) bs[i] = bf2f(bias[cb + i]);

#pragma unroll
  for (int nt = 0; nt < 8; ++nt) {
    long nn = tileBase + nt * 16 + ll;
    if (nn >= N_NODES) continue;
    u16x8 o0, o1;
#pragma unroll
    for (int mt = 0; mt < 4; ++mt)
#pragma unroll
      for (int r = 0; r < 4; ++r) {
        int i = mt * 4 + r;
        unsigned short ob = f2bf(acc[mt][nt][r] + bs[i]);
        if (i < 8) o0[i] = ob; else o1[i - 8] = ob;
      }
    unsigned short* orow = out + nn * out_pitch + cb;
    *(u16x8*)(orow) = o0;
    *(u16x8*)(orow + 8) = o1;
  }
}

// ---------------------------------------------------------------------------
// Edge-tiled agg: block = 64 consecutive CSR rows. Loads batched 8-wide ahead
// of the run-boundary branch so they pipeline. One atomicAdd per dst-run.
// ---------------------------------------------------------------------------
template <bool FIRST>
__global__ void k_agg(const int* __restrict__ csrc, const int* __restrict__ cdst,
                      const unsigned short* __restrict__ e,
                      const unsigned short* __restrict__ eaC,
                      const unsigned short* __restrict__ arena,
                      const unsigned short* __restrict__ XW, int xw_pitch, int x2_off,
                      float* __restrict__ agg) {
  __shared__ int s_src[64];
  __shared__ int s_dst[64];
  const long base = (long)blockIdx.x * 64;
  const int c = threadIdx.x;
  if (c < 64) {
    long r = base + c;
    int s = csrc[r]; if ((unsigned)s >= N_NODES) s = 0;
    int d = cdst[r]; if ((unsigned)d >= N_NODES) d = 0;
    s_src[c] = s;
    s_dst[c] = d;
  }
  __syncthreads();
  float wac = 0.f, bac = 0.f;
  if (FIRST) { wac = bf2f(arena[A_WA + c]); bac = bf2f(arena[A_BA + c]); }
  float a = 0.f;
  int run = s_dst[0];
  for (int b8 = 0; b8 < 64; b8 += 8) {
    float evv[8], x2v[8];
#pragma unroll
    for (int j = 0; j < 8; ++j) {
      int row = b8 + j;
      if (FIRST) evv[j] = fmaf(bf2f(eaC[base + row]), wac, bac);
      else evv[j] = bf2f(__builtin_nontemporal_load(e + ((base + row) << 8) + c));
      x2v[j] = bf2f(XW[(long)s_src[row] * xw_pitch + x2_off + c]);
    }
#pragma unroll
    for (int j = 0; j < 8; ++j) {
      int d = s_dst[b8 + j];
      if (d != run) {  // uniform across the block (dst-sorted)
        atomicAdd(&agg[((long)run << 8) + c], a);
        a = 0.f;
        run = d;
      }
      float gate = 1.f / (1.f + __expf(-evv[j]));
      a = fmaf(gate, x2v[j], a);
    }
  }
  atomicAdd(&agg[((long)run << 8) + c], a);
}

// x += relu(xW1+b1 + agg); refresh bf16 copy; zero agg for the next layer
// (replaces 2 of the 3 hipMemsetAsync launches).
__global__ void k_node_update(float* __restrict__ xf, unsigned short* __restrict__ xbf,
                              const unsigned short* __restrict__ XW,
                              float* __restrict__ agg) {
  int n = blockIdx.x, c = threadIdx.x;
  long idx = ((long)n << 8) + c;
  float av = agg[idx];
  agg[idx] = 0.f;
  float t = bf2f(XW[((long)n << 10) + c]) + av;
  float nx = xf[idx] + fmaxf(t, 0.f);
  xf[idx] = nx;
  xbf[idx] = f2bf(nx);
}

// ---------------------------------------------------------------------------
extern "C" void kernel_launch(void* const* d_in, const int* in_sizes, int n_in,
                              void* d_out, int out_size, void* d_ws, size_t ws_size,
                              hipStream_t stream) {
  const int* eidx = (const int*)d_in[2];
  const int* srcA = eidx;
  const int* dstA = eidx + N_EDGES;
  (void)in_sizes; (void)n_in; (void)out_size;

  char* ws = (char*)d_ws;
  size_t off = 0;
  auto alloc = [&](size_t bytes) -> char* {
    char* p = ws + off;
    off = (off + bytes + 255) & ~(size_t)255;
    return p;
  };
  unsigned short* e_buf   = (unsigned short*)alloc((size_t)N_EDGES * 256 * 2);  // 164 MB
  float*          xf      = (float*)alloc((size_t)N_NODES * 256 * 4);
  unsigned short* xbf     = (unsigned short*)alloc((size_t)N_NODES * 256 * 2);
  unsigned short* XW      = (unsigned short*)alloc((size_t)N_NODES * 1024 * 2);
  float*          agg     = (float*)alloc((size_t)N_NODES * 256 * 4);
  unsigned short* nodeBT  = (unsigned short*)alloc((size_t)917504 * 2);
  unsigned short* WeT     = (unsigned short*)alloc((size_t)4 * 65536 * 2);
  unsigned short* Wm1T    = (unsigned short*)alloc((size_t)32768 * 2);
  unsigned short* biascat = (unsigned short*)alloc((size_t)3584 * 2);
  unsigned short* arena   = (unsigned short*)alloc((size_t)ARENA_TOT * 2);
  int* deg    = (int*)alloc((size_t)N_NODES * 4);
  int* rowptr = (int*)alloc((size_t)(N_NODES + 1) * 4);
  int* cursor = (int*)alloc((size_t)N_NODES * 4);
  int* eid    = (int*)alloc((size_t)N_EDGES * 4);
  int* csrc   = (int*)alloc((size_t)N_EDGES * 4);
  int* cdst   = (int*)alloc((size_t)N_EDGES * 4);
  unsigned short* eaC = (unsigned short*)alloc((size_t)N_EDGES * 2);
  int* flag   = (int*)alloc(4);
  if (ws_size < off) return;  // distinctive signature: out stays all-zero

  Ptrs ptrs;
  {
    int map[19] = {0, 1, 3, 4, 5, 6, 7, 8, 9, 10, 11, 12, 13, 14, 15, 16, 17, 18, 19};
    for (int j = 0; j < 19; ++j) ptrs.p[j] = d_in[map[j]];
  }

  dim3 blk(256);
  k_detect<<<dim3(1), blk, 0, stream>>>((const unsigned short*)d_in[3], flag);
  k_cast<<<dim3((ARENA_USED + 255) / 256), blk, 0, stream>>>(ptrs, flag, arena);
  k_prep<<<dim3(256, 1, 20), blk, 0, stream>>>(arena, nodeBT, WeT, Wm1T, biascat);
  k_init_x<<<dim3(N_NODES), blk, 0, stream>>>(arena, xf, xbf);
  hipMemsetAsync(deg, 0, (size_t)N_NODES * 4, stream);
  hipMemsetAsync(agg, 0, (size_t)N_NODES * 256 * 4, stream);
  k_hist<<<dim3(N_EDGES / 256), blk, 0, stream>>>(dstA, deg);
  k_scan<<<dim3(1), blk, 0, stream>>>(deg, rowptr, cursor);
  k_fill<<<dim3(N_EDGES / 256), blk, 0, stream>>>(dstA, srcA, arena, cursor, eid, csrc,
                                                  cdst, eaC);

  for (int l = 0; l < 3; ++l) {
    k_node_gemm<<<dim3(79, 4), blk, 0, stream>>>(xbf, nodeBT + l * 262144,
                                                 biascat + l * 1024, XW, 1024);
    if (l == 0)
      k_agg<true><<<dim3(N_EDGES / 64), blk, 0, stream>>>(csrc, cdst, e_buf, eaC, arena,
                                                          XW, 1024, 256, agg);
    else
      k_agg<false><<<dim3(N_EDGES / 64), blk, 0, stream>>>(csrc, cdst, e_buf, eaC, arena,
                                                           XW, 1024, 256, agg);
    if (l == 0)
      k_edge<0><<<dim3(EDGE_GRID), blk, 0, stream>>>(
          e_buf, WeT, XW, 1024, 512, 768, arena + A_BE, arena, eaC, csrc, cdst);
    else
      k_edge<1><<<dim3(EDGE_GRID), blk, 0, stream>>>(
          e_buf, WeT + l * 65536, XW, 1024, 512, 768, arena + A_BE + l * 256,
          arena, eaC, csrc, cdst);
    k_node_update<<<dim3(N_NODES), blk, 0, stream>>>(xf, xbf, XW, agg);
  }
  // layer 3: edge update + fused MLP head (e4 never materialized), 128-row
  k_node_gemm<<<dim3(79, 2), blk, 0, stream>>>(xbf, nodeBT + 786432, biascat + 3072, XW, 512);
  k_edge_final<<<dim3(N_EDGES / 128), blk, 0, stream>>>(
      e_buf, WeT + 196608, XW, 512, 0, 256, arena + A_BE + 768,
      arena, eaC, csrc, cdst, Wm1T, eid, flag, d_out);
}

// Round 12
// 939.977 us; speedup vs baseline: 1.5286x; 1.0754x over previous
//
#include <hip/hip_runtime.h>
#include <stdint.h>

#define N_NODES 10000
#define N_EDGES 320000

using bf16x8 = __attribute__((ext_vector_type(8))) short;
using fp32x4 = __attribute__((ext_vector_type(4))) float;
using u16x8 = __attribute__((ext_vector_type(8))) unsigned short;
using i32x4 = __attribute__((ext_vector_type(4))) int;

__device__ __forceinline__ float bf2f(unsigned short u) {
  union { unsigned int i; float f; } v; v.i = ((unsigned int)u) << 16; return v.f;
}
__device__ __forceinline__ unsigned short f2bf(float f) {
  union { float f; unsigned int i; } v; v.f = f;
  unsigned int x = v.i;
  x += 0x7fffu + ((x >> 16) & 1u);
  return (unsigned short)(x >> 16);
}

// ---------------- internal bf16 arena (element offsets) ---------------------
#define A_POS 0
#define A_EA 20000
#define A_WP 340000
#define A_BP 340512
#define A_WA 340768
#define A_BA 341024
#define A_W1 341280
#define A_B1 537888
#define A_W2 538656
#define A_B2 735264
#define A_WE 736032
#define A_BE 998176
#define A_WS 999200
#define A_WT 1261344
#define A_WM1 1523488
#define A_BM1 1556384
#define A_AL 1556512
#define A_WM2 1556544
#define A_BM2 1556672
#define ARENA_USED 1556673
#define ARENA_TOT 1556736

__constant__ int g_off[19] = {A_POS, A_EA, A_WP, A_BP, A_WA, A_BA, A_W1, A_B1,
                              A_W2, A_B2, A_WE, A_BE, A_WS, A_WT, A_WM1,
                              A_BM1, A_AL, A_WM2, A_BM2};

struct Ptrs { const void* p[19]; };

// Dtype detector: fp32 read as bf16 halves yields ~47% |v|>100; bf16 never.
__global__ void k_detect(const unsigned short* wpraw, int* flag) {
  __shared__ int cnt;
  int tid = threadIdx.x;
  if (tid == 0) cnt = 0;
  __syncthreads();
  float v0 = bf2f(wpraw[tid]);
  float v1 = bf2f(wpraw[256 + tid]);
  int big = (fabsf(v0) > 100.f ? 1 : 0) + (fabsf(v1) > 100.f ? 1 : 0);
  atomicAdd(&cnt, big);
  __syncthreads();
  if (tid == 0) *flag = (cnt > 10) ? 1 : 0;  // 1 = fp32 inputs
}

// Normalize all float inputs into the bf16 arena (flattened grid).
__global__ void k_cast(Ptrs ptrs, const int* __restrict__ flag,
                       unsigned short* __restrict__ arena) {
  int a = blockIdx.x * 256 + threadIdx.x;
  if (a >= ARENA_USED) return;
  int z = 0;
#pragma unroll
  for (int j = 1; j < 19; ++j) if (a >= g_off[j]) z = j;
  int i = a - g_off[z];
  float v;
  if (*flag) v = ((const float*)ptrs.p[z])[i];
  else       v = bf2f(((const unsigned short*)ptrs.p[z])[i]);
  arena[a] = f2bf(v);
}

// ---------------------------------------------------------------------------
// Weight prep: transpose [K,N] -> n-major [N,K] (row = out-col, 512B rows).
// nodeBT per layer l<3: [W1T|W2T|WsT|WtT] (1024x256); l==3: [WsT|WtT].
// ---------------------------------------------------------------------------
__global__ void k_prep(const unsigned short* __restrict__ arena,
                       unsigned short* nodeBT, unsigned short* WeT,
                       unsigned short* Wm1T, unsigned short* biascat) {
  int z = blockIdx.z;
  int i = blockIdx.x * 256 + threadIdx.x;
  if (z == 19) {  // bias concat: 3 x [b1|b2|0|0] (1024) then 512 zeros
    if (i < 3072) {
      int l = i >> 10, j = i & 1023;
      unsigned short v = 0;
      if (j < 256) v = arena[A_B1 + l * 256 + j];
      else if (j < 512) v = arena[A_B2 + l * 256 + (j - 256)];
      biascat[i] = v;
    } else if (i < 3584) {
      biascat[i] = 0;
    }
    return;
  }
  const unsigned short* src; unsigned short* dst; int srcN = 256;
  if (z < 3)       {                 src = arena + A_W1 + z * 65536; dst = nodeBT + z * 262144; }
  else if (z < 6)  { int l = z - 3;  src = arena + A_W2 + l * 65536; dst = nodeBT + l * 262144 + 65536; }
  else if (z < 10) { int l = z - 6;  src = arena + A_WS + l * 65536;
                     dst = (l < 3) ? nodeBT + l * 262144 + 131072 : nodeBT + 786432; }
  else if (z < 14) { int l = z - 10; src = arena + A_WT + l * 65536;
                     dst = (l < 3) ? nodeBT + l * 262144 + 196608 : nodeBT + 786432 + 65536; }
  else if (z < 18) { int l = z - 14; src = arena + A_WE + l * 65536; dst = WeT + l * 65536; }
  else             { src = arena + A_WM1; dst = Wm1T; srcN = 128; }
  if (i < srcN * 256) {
    int k = i & 255, n = i >> 8;
    dst[i] = src[k * srcN + n];  // dst[n][k] = src[k][n]
  }
}

// x0 = pos @ Wp + bp (K=2), fp32 master + bf16 copy
__global__ void k_init_x(const unsigned short* __restrict__ arena,
                         float* __restrict__ xf, unsigned short* __restrict__ xbf) {
  int n = blockIdx.x, c = threadIdx.x;
  float p0 = bf2f(arena[A_POS + 2 * n]), p1 = bf2f(arena[A_POS + 2 * n + 1]);
  float v = fmaf(p0, bf2f(arena[A_WP + c]),
                 fmaf(p1, bf2f(arena[A_WP + 256 + c]), bf2f(arena[A_BP + c])));
  long idx = ((long)n << 8) + c;
  xf[idx] = v;
  xbf[idx] = f2bf(v);
}

// ---------------- CSR build (by dst). e lives in CSR row order everywhere ---
__global__ void k_hist(const int* __restrict__ dstA, int* __restrict__ deg) {
  int i = blockIdx.x * 256 + threadIdx.x;
  if (i < N_EDGES) {
    int d = dstA[i];
    if ((unsigned)d < N_NODES) atomicAdd(&deg[d], 1);
  }
}

__global__ void k_scan(const int* __restrict__ deg, int* __restrict__ rowptr,
                       int* __restrict__ cursor) {
  __shared__ int part[256];
  int tid = threadIdx.x;
  int base = tid * 40;
  int s = 0;
  for (int i = 0; i < 40; ++i) {
    int idx = base + i;
    if (idx < N_NODES) s += deg[idx];
  }
  part[tid] = s;
  __syncthreads();
  if (tid == 0) {
    int run = 0;
    for (int i = 0; i < 256; ++i) { int t = part[i]; part[i] = run; run += t; }
    rowptr[N_NODES] = run;
  }
  __syncthreads();
  int run = part[tid];
  for (int i = 0; i < 40; ++i) {
    int idx = base + i;
    if (idx < N_NODES) { rowptr[idx] = run; cursor[idx] = run; run += deg[idx]; }
  }
}

// Also emits csrc/cdst (endpoints in CSR order) and eaC (ea gathered to CSR).
__global__ void k_fill(const int* __restrict__ dstA, const int* __restrict__ srcA,
                       const unsigned short* __restrict__ arena,
                       int* __restrict__ cursor, int* __restrict__ eid,
                       int* __restrict__ csrc, int* __restrict__ cdst,
                       unsigned short* __restrict__ eaC) {
  int i = blockIdx.x * 256 + threadIdx.x;
  if (i < N_EDGES) {
    int d = dstA[i]; if ((unsigned)d >= N_NODES) d = 0;
    int p = atomicAdd(&cursor[d], 1);
    if ((unsigned)p < N_EDGES) {
      eid[p] = i;
      int s = srcA[i]; if ((unsigned)s >= N_NODES) s = 0;
      csrc[p] = s;
      cdst[p] = d;
      eaC[p] = arena[A_EA + i];
    }
  }
}

// ---------------------------------------------------------------------------
// Swapped-operand GEMM core with PERMUTED column mapping: A-frag lane ll of
// fragment mt loads WT row oc = colBase + (ll>>2)*(MT*4) + mt*4 + (ll&3).
// Lane (q,ll) reg r of frag mt then holds out-col colBase + q*(MT*4) + mt*4+r
// -> each lane's values cover MT*4 CONSECUTIVE cols (full-line epilogue).
// B-frag: LDS tile row (n=ll). D row = nt*16+ll. NTT = row-tiles (rows/16).
// LDS pitch 528B -> <=2-way bank aliasing (free, m136).
// NOTE (r11 post-mortem): per-thread A-frag VMEM count (8ks x MT) is
// INDEPENDENT of tile rows, so bigger row-tiles amortize it -> 128-row tiles
// measured fastest for the edge kernels (r9: 143us vs 64-row: 169us).
// ---------------------------------------------------------------------------
#define SM_PITCH 528

template <bool NT, int ROWS>
__device__ __forceinline__ void stage_tile(char* smc, const unsigned short* src,
                                           long rowBase) {
  int tid = threadIdx.x;
#pragma unroll
  for (int it = 0; it < ROWS / 8; ++it) {   // ROWS rows x 32 groups of 16B
    int lin = it * 256 + tid;
    int row = lin >> 5, g = lin & 31;
    const i32x4* p = (const i32x4*)((const char*)src + ((rowBase + row) << 9) + (g << 4));
    i32x4 v = NT ? __builtin_nontemporal_load(p) : *p;
    *(i32x4*)(smc + row * SM_PITCH + (g << 4)) = v;
  }
}

template <int MT, int NTT>
__device__ __forceinline__ void gemm_swap(const char* smc, const unsigned short* WT,
                                          int colBase, fp32x4 (&acc)[MT][NTT]) {
  const int lane = threadIdx.x & 63;
  const int q = lane >> 4, ll = lane & 15;
  const int llperm = ((ll >> 2) * (MT * 4)) + (ll & 3);  // permuted col offset
#pragma unroll
  for (int ks = 0; ks < 8; ++ks) {
    bf16x8 a[MT];
#pragma unroll
    for (int mt = 0; mt < MT; ++mt) {
      int oc = colBase + llperm + mt * 4;
      a[mt] = *(const bf16x8*)((const char*)WT + ((long)oc << 9) + (ks << 6) + (q << 4));
    }
    bf16x8 b[NTT];
#pragma unroll
    for (int nt = 0; nt < NTT; ++nt)
      b[nt] = *(const bf16x8*)(smc + (nt * 16 + ll) * SM_PITCH + (ks << 6) + (q << 4));
#pragma unroll
    for (int mt = 0; mt < MT; ++mt)
#pragma unroll
      for (int nt = 0; nt < NTT; ++nt)
        acc[mt][nt] = __builtin_amdgcn_mfma_f32_16x16x32_bf16(a[mt], b[nt], acc[mt][nt], 0, 0, 0);
  }
}

// Shared epilogue: e_new = e_old + relu(acc + xs + xt + be), updated in LDS.
template <int NTT>
__device__ __forceinline__ void edge_epilogue(
    char* smc, const fp32x4 (&acc)[4][NTT], const int* s_src, const int* s_dst,
    const unsigned short* XW, int xw_pitch, int xs_off, int xt_off,
    const unsigned short* bePtr, int cb, int ll) {
  u16x8 be0 = *(const u16x8*)(bePtr + cb);
  u16x8 be1 = *(const u16x8*)(bePtr + cb + 8);
#pragma unroll
  for (int nt = 0; nt < NTT; ++nt) {
    int el = nt * 16 + ll;
    int sn = s_src[el], dn = s_dst[el];
    const unsigned short* xsrow = XW + (long)sn * xw_pitch + xs_off + cb;
    const unsigned short* xtrow = XW + (long)dn * xw_pitch + xt_off + cb;
    u16x8 xs0 = *(const u16x8*)(xsrow);
    u16x8 xs1 = *(const u16x8*)(xsrow + 8);
    u16x8 xt0 = *(const u16x8*)(xtrow);
    u16x8 xt1 = *(const u16x8*)(xtrow + 8);
    u16x8* slot = (u16x8*)(smc + el * SM_PITCH + cb * 2);
    u16x8 er0 = slot[0], er1 = slot[1];
    u16x8 o0, o1;
#pragma unroll
    for (int mt = 0; mt < 4; ++mt)
#pragma unroll
      for (int r = 0; r < 4; ++r) {
        int i = mt * 4 + r;
        float xsv = bf2f(i < 8 ? xs0[i] : xs1[i - 8]);
        float xtv = bf2f(i < 8 ? xt0[i] : xt1[i - 8]);
        float erv = bf2f(i < 8 ? er0[i] : er1[i - 8]);
        float bev = bf2f(i < 8 ? be0[i] : be1[i - 8]);
        float v = acc[mt][nt][r] + xsv + xtv + bev;
        v = fmaxf(v, 0.f);
        unsigned short ob = f2bf(erv + v);
        if (i < 8) o0[i] = ob; else o1[i - 8] = ob;
      }
    slot[0] = o0;
    slot[1] = o1;  // slot owned by this lane only
  }
}

// ---------------------------------------------------------------------------
// Edge kernel (CSR row order), 128-row tiles @ 2 blocks/CU (r9's measured-best
// shape for the writeback path: 143us).
// MODE 0: first layer, e0 built in LDS from eaC; writeback.
// MODE 1: mid layers, stage e; writeback.
// ---------------------------------------------------------------------------
template <int MODE>
__global__ __launch_bounds__(256, 2) void k_edge(
    unsigned short* __restrict__ e, const unsigned short* __restrict__ WT,
    const unsigned short* __restrict__ XW, int xw_pitch, int xs_off, int xt_off,
    const unsigned short* __restrict__ bePtr, const unsigned short* __restrict__ arena,
    const unsigned short* __restrict__ eaC,
    const int* __restrict__ csrc, const int* __restrict__ cdst) {
  __shared__ int4 sm4[128 * 33];
  __shared__ int s_src[128];
  __shared__ int s_dst[128];
  char* smc = (char*)sm4;
  const long tileBase = (long)blockIdx.x * 128;
  const int tid = threadIdx.x;
  const int wave = tid >> 6, lane = tid & 63;
  const int q = lane >> 4, ll = lane & 15;
  const int colBase = wave * 64;

  if (MODE == 0) {
#pragma unroll
    for (int it = 0; it < 16; ++it) {
      int lin = it * 256 + tid;
      int row = lin >> 5, g = lin & 31;
      float eav = bf2f(eaC[tileBase + row]);
      int c0 = g * 8;
      bf16x8 ov;
#pragma unroll
      for (int j = 0; j < 8; ++j) {
        float f = fmaf(eav, bf2f(arena[A_WA + c0 + j]), bf2f(arena[A_BA + c0 + j]));
        ((unsigned short*)&ov)[j] = f2bf(f);
      }
      *(bf16x8*)(smc + row * SM_PITCH + (g << 4)) = ov;
    }
  } else {
    stage_tile<true, 128>(smc, e, tileBase);
  }
  if (tid < 128) {
    long edge = tileBase + tid;
    int s = csrc[edge]; if ((unsigned)s >= N_NODES) s = 0;
    int d = cdst[edge]; if ((unsigned)d >= N_NODES) d = 0;
    s_src[tid] = s;
    s_dst[tid] = d;
  }
  __syncthreads();

  fp32x4 acc[4][8];
#pragma unroll
  for (int mt = 0; mt < 4; ++mt)
#pragma unroll
    for (int nt = 0; nt < 8; ++nt) acc[mt][nt] = 0.f;
  gemm_swap<4, 8>(smc, WT, colBase, acc);
  __syncthreads();  // all waves done reading A-tile before in-place update

  edge_epilogue<8>(smc, acc, s_src, s_dst, XW, xw_pitch, xs_off, xt_off,
                   bePtr, colBase + q * 16, ll);
  __syncthreads();  // tile fully updated

  // Coalesced full-line writeback: 16B/lane, 1KB contiguous per instruction.
#pragma unroll
  for (int it = 0; it < 16; ++it) {
    int lin = it * 256 + tid;
    int row = lin >> 5, g = lin & 31;
    i32x4 v = *(const i32x4*)(smc + row * SM_PITCH + (g << 4));
    __builtin_nontemporal_store(v, (i32x4*)((char*)e + ((tileBase + row) << 9) + (g << 4)));
  }
}

// ---------------------------------------------------------------------------
// Final edge kernel, 128-row tiles: stage e; epilogue keeps e_new in LDS;
// fused MLP head -> out (e4 never materialized in HBM).
// ---------------------------------------------------------------------------
__global__ __launch_bounds__(256, 2) void k_edge_final(
    const unsigned short* __restrict__ e, const unsigned short* __restrict__ WT,
    const unsigned short* __restrict__ XW, int xw_pitch, int xs_off, int xt_off,
    const unsigned short* __restrict__ bePtr, const unsigned short* __restrict__ arena,
    const unsigned short* __restrict__ eaC,
    const int* __restrict__ csrc, const int* __restrict__ cdst,
    const unsigned short* __restrict__ Wm1T, const int* __restrict__ eid,
    const int* __restrict__ flag, void* __restrict__ out) {
  __shared__ int4 sm4[128 * 33];
  __shared__ int s_src[128];
  __shared__ int s_dst[128];
  char* smc = (char*)sm4;
  const long tileBase = (long)blockIdx.x * 128;
  const int tid = threadIdx.x;
  const int wave = tid >> 6, lane = tid & 63;
  const int q = lane >> 4, ll = lane & 15;
  const int colBase = wave * 64;

  stage_tile<true, 128>(smc, e, tileBase);
  if (tid < 128) {
    long edge = tileBase + tid;
    int s = csrc[edge]; if ((unsigned)s >= N_NODES) s = 0;
    int d = cdst[edge]; if ((unsigned)d >= N_NODES) d = 0;
    s_src[tid] = s;
    s_dst[tid] = d;
  }
  __syncthreads();

  fp32x4 acc[4][8];
#pragma unroll
  for (int mt = 0; mt < 4; ++mt)
#pragma unroll
    for (int nt = 0; nt < 8; ++nt) acc[mt][nt] = 0.f;
  gemm_swap<4, 8>(smc, WT, colBase, acc);
  __syncthreads();

  edge_epilogue<8>(smc, acc, s_src, s_dst, XW, xw_pitch, xs_off, xt_off,
                   bePtr, colBase + q * 16, ll);
  __syncthreads();  // tile fully updated (e4 stays in LDS only)

  // Fused MLP head: h = prelu(e4@Wm1[:256] + eaC*Wm1[256] + bm1); out = h@Wm2+bm2
  fp32x4 acc2[2][8];
#pragma unroll
  for (int mt = 0; mt < 2; ++mt)
#pragma unroll
    for (int nt = 0; nt < 8; ++nt) acc2[mt][nt] = 0.f;
  const int colBase2 = wave * 32;
  gemm_swap<2, 8>(smc, Wm1T, colBase2, acc2);

  const int cb2 = colBase2 + q * 8;  // 8 consecutive out-cols per lane (MT=2)
  float alphaf = bf2f(arena[A_AL]);
  float bmc[8], wl[8], w2c[8];
#pragma unroll
  for (int i = 0; i < 8; ++i) {
    bmc[i] = bf2f(arena[A_BM1 + cb2 + i]);
    wl[i] = bf2f(arena[A_WM1 + 32768 + cb2 + i]);
    w2c[i] = bf2f(arena[A_WM2 + cb2 + i]);
  }
  __syncthreads();             // all waves done reading LDS for gemm2
  float* part = (float*)smc;   // alias tile as [128][4] fp32 partials
#pragma unroll
  for (int nt = 0; nt < 8; ++nt) {
    int el = nt * 16 + ll;
    float eav = bf2f(eaC[tileBase + el]);
    float ps = 0.f;
#pragma unroll
    for (int mt = 0; mt < 2; ++mt)
#pragma unroll
      for (int r = 0; r < 4; ++r) {
        int i = mt * 4 + r;
        float h = acc2[mt][nt][r] + bmc[i] + eav * wl[i];
        h = (h > 0.f) ? h : alphaf * h;
        ps += h * w2c[i];
      }
    ps += __shfl_xor(ps, 16, 64);
    ps += __shfl_xor(ps, 32, 64);
    if (q == 0) part[el * 4 + wave] = ps;
  }
  __syncthreads();
  if (tid < 128) {
    float t = part[tid * 4] + part[tid * 4 + 1] + part[tid * 4 + 2] + part[tid * 4 + 3]
            + bf2f(arena[A_BM2]);
    long row = tileBase + tid;
    int oe = eid[row]; if ((unsigned)oe >= N_EDGES) oe = 0;
    if (*flag) ((float*)out)[oe] = t;
    else       ((unsigned short*)out)[oe] = f2bf(t);
  }
}

// Node-side GEMM: XW = x_bf @ [W1|W2|Ws|Wt] (+b1|b2|0|0), bf16 out (128-row).
__global__ __launch_bounds__(256, 2) void k_node_gemm(
    const unsigned short* __restrict__ xbf, const unsigned short* __restrict__ WT,
    const unsigned short* __restrict__ bias, unsigned short* __restrict__ out,
    int out_pitch) {
  __shared__ int4 sm4[128 * 33];
  char* smc = (char*)sm4;
  const long tileBase = (long)blockIdx.x * 128;
  // clamped staging (10000 rows not divisible by 128)
  {
    int tid = threadIdx.x;
#pragma unroll
    for (int it = 0; it < 16; ++it) {
      int lin = it * 256 + tid;
      int row = lin >> 5, g = lin & 31;
      long rg = tileBase + row;
      if (rg > N_NODES - 1) rg = N_NODES - 1;
      i32x4 v = *(const i32x4*)((const char*)xbf + (rg << 9) + (g << 4));
      *(i32x4*)(smc + row * SM_PITCH + (g << 4)) = v;
    }
  }
  __syncthreads();
  fp32x4 acc[4][8];
#pragma unroll
  for (int mt = 0; mt < 4; ++mt)
#pragma unroll
    for (int nt = 0; nt < 8; ++nt) acc[mt][nt] = 0.f;
  const int tid = threadIdx.x, wave = tid >> 6, lane = tid & 63;
  const int q = lane >> 4, ll = lane & 15;
  const int colBase = blockIdx.y * 256 + wave * 64;
  gemm_swap<4, 8>(smc, WT, colBase, acc);

  const int cb = colBase + q * 16;
  float bs[16];
#pragma unroll
  for (int i = 0; i < 16; ++i) bs[i] = bf2f(bias[cb + i]);

#pragma unroll
  for (int nt = 0; nt < 8; ++nt) {
    long nn = tileBase + nt * 16 + ll;
    if (nn >= N_NODES) continue;
    u16x8 o0, o1;
#pragma unroll
    for (int mt = 0; mt < 4; ++mt)
#pragma unroll
      for (int r = 0; r < 4; ++r) {
        int i = mt * 4 + r;
        unsigned short ob = f2bf(acc[mt][nt][r] + bs[i]);
        if (i < 8) o0[i] = ob; else o1[i - 8] = ob;
      }
    unsigned short* orow = out + nn * out_pitch + cb;
    *(u16x8*)(orow) = o0;
    *(u16x8*)(orow + 8) = o1;
  }
}

// ---------------------------------------------------------------------------
// Edge-tiled agg: block = 64 consecutive CSR rows. Loads batched 8-wide ahead
// of the run-boundary branch so they pipeline. One atomicAdd per dst-run.
// ---------------------------------------------------------------------------
template <bool FIRST>
__global__ void k_agg(const int* __restrict__ csrc, const int* __restrict__ cdst,
                      const unsigned short* __restrict__ e,
                      const unsigned short* __restrict__ eaC,
                      const unsigned short* __restrict__ arena,
                      const unsigned short* __restrict__ XW, int xw_pitch, int x2_off,
                      float* __restrict__ agg) {
  __shared__ int s_src[64];
  __shared__ int s_dst[64];
  const long base = (long)blockIdx.x * 64;
  const int c = threadIdx.x;
  if (c < 64) {
    long r = base + c;
    int s = csrc[r]; if ((unsigned)s >= N_NODES) s = 0;
    int d = cdst[r]; if ((unsigned)d >= N_NODES) d = 0;
    s_src[c] = s;
    s_dst[c] = d;
  }
  __syncthreads();
  float wac = 0.f, bac = 0.f;
  if (FIRST) { wac = bf2f(arena[A_WA + c]); bac = bf2f(arena[A_BA + c]); }
  float a = 0.f;
  int run = s_dst[0];
  for (int b8 = 0; b8 < 64; b8 += 8) {
    float evv[8], x2v[8];
#pragma unroll
    for (int j = 0; j < 8; ++j) {
      int row = b8 + j;
      if (FIRST) evv[j] = fmaf(bf2f(eaC[base + row]), wac, bac);
      else evv[j] = bf2f(__builtin_nontemporal_load(e + ((base + row) << 8) + c));
      x2v[j] = bf2f(XW[(long)s_src[row] * xw_pitch + x2_off + c]);
    }
#pragma unroll
    for (int j = 0; j < 8; ++j) {
      int d = s_dst[b8 + j];
      if (d != run) {  // uniform across the block (dst-sorted)
        atomicAdd(&agg[((long)run << 8) + c], a);
        a = 0.f;
        run = d;
      }
      float gate = 1.f / (1.f + __expf(-evv[j]));
      a = fmaf(gate, x2v[j], a);
    }
  }
  atomicAdd(&agg[((long)run << 8) + c], a);
}

// x += relu(xW1+b1 + agg); refresh bf16 copy; zero agg for the next layer.
__global__ void k_node_update(float* __restrict__ xf, unsigned short* __restrict__ xbf,
                              const unsigned short* __restrict__ XW,
                              float* __restrict__ agg) {
  int n = blockIdx.x, c = threadIdx.x;
  long idx = ((long)n << 8) + c;
  float av = agg[idx];
  agg[idx] = 0.f;
  float t = bf2f(XW[((long)n << 10) + c]) + av;
  float nx = xf[idx] + fmaxf(t, 0.f);
  xf[idx] = nx;
  xbf[idx] = f2bf(nx);
}

// ---------------------------------------------------------------------------
extern "C" void kernel_launch(void* const* d_in, const int* in_sizes, int n_in,
                              void* d_out, int out_size, void* d_ws, size_t ws_size,
                              hipStream_t stream) {
  const int* eidx = (const int*)d_in[2];
  const int* srcA = eidx;
  const int* dstA = eidx + N_EDGES;
  (void)in_sizes; (void)n_in; (void)out_size;

  char* ws = (char*)d_ws;
  size_t off = 0;
  auto alloc = [&](size_t bytes) -> char* {
    char* p = ws + off;
    off = (off + bytes + 255) & ~(size_t)255;
    return p;
  };
  unsigned short* e_buf   = (unsigned short*)alloc((size_t)N_EDGES * 256 * 2);  // 164 MB
  float*          xf      = (float*)alloc((size_t)N_NODES * 256 * 4);
  unsigned short* xbf     = (unsigned short*)alloc((size_t)N_NODES * 256 * 2);
  unsigned short* XW      = (unsigned short*)alloc((size_t)N_NODES * 1024 * 2);
  float*          agg     = (float*)alloc((size_t)N_NODES * 256 * 4);
  unsigned short* nodeBT  = (unsigned short*)alloc((size_t)917504 * 2);
  unsigned short* WeT     = (unsigned short*)alloc((size_t)4 * 65536 * 2);
  unsigned short* Wm1T    = (unsigned short*)alloc((size_t)32768 * 2);
  unsigned short* biascat = (unsigned short*)alloc((size_t)3584 * 2);
  unsigned short* arena   = (unsigned short*)alloc((size_t)ARENA_TOT * 2);
  int* deg    = (int*)alloc((size_t)N_NODES * 4);
  int* rowptr = (int*)alloc((size_t)(N_NODES + 1) * 4);
  int* cursor = (int*)alloc((size_t)N_NODES * 4);
  int* eid    = (int*)alloc((size_t)N_EDGES * 4);
  int* csrc   = (int*)alloc((size_t)N_EDGES * 4);
  int* cdst   = (int*)alloc((size_t)N_EDGES * 4);
  unsigned short* eaC = (unsigned short*)alloc((size_t)N_EDGES * 2);
  int* flag   = (int*)alloc(4);
  if (ws_size < off) return;  // distinctive signature: out stays all-zero

  Ptrs ptrs;
  {
    int map[19] = {0, 1, 3, 4, 5, 6, 7, 8, 9, 10, 11, 12, 13, 14, 15, 16, 17, 18, 19};
    for (int j = 0; j < 19; ++j) ptrs.p[j] = d_in[map[j]];
  }

  dim3 blk(256);
  k_detect<<<dim3(1), blk, 0, stream>>>((const unsigned short*)d_in[3], flag);
  k_cast<<<dim3((ARENA_USED + 255) / 256), blk, 0, stream>>>(ptrs, flag, arena);
  k_prep<<<dim3(256, 1, 20), blk, 0, stream>>>(arena, nodeBT, WeT, Wm1T, biascat);
  k_init_x<<<dim3(N_NODES), blk, 0, stream>>>(arena, xf, xbf);
  hipMemsetAsync(deg, 0, (size_t)N_NODES * 4, stream);
  hipMemsetAsync(agg, 0, (size_t)N_NODES * 256 * 4, stream);
  k_hist<<<dim3(N_EDGES / 256), blk, 0, stream>>>(dstA, deg);
  k_scan<<<dim3(1), blk, 0, stream>>>(deg, rowptr, cursor);
  k_fill<<<dim3(N_EDGES / 256), blk, 0, stream>>>(dstA, srcA, arena, cursor, eid, csrc,
                                                  cdst, eaC);

  for (int l = 0; l < 3; ++l) {
    k_node_gemm<<<dim3(79, 4), blk, 0, stream>>>(xbf, nodeBT + l * 262144,
                                                 biascat + l * 1024, XW, 1024);
    if (l == 0)
      k_agg<true><<<dim3(N_EDGES / 64), blk, 0, stream>>>(csrc, cdst, e_buf, eaC, arena,
                                                          XW, 1024, 256, agg);
    else
      k_agg<false><<<dim3(N_EDGES / 64), blk, 0, stream>>>(csrc, cdst, e_buf, eaC, arena,
                                                           XW, 1024, 256, agg);
    if (l == 0)
      k_edge<0><<<dim3(N_EDGES / 128), blk, 0, stream>>>(
          e_buf, WeT, XW, 1024, 512, 768, arena + A_BE, arena, eaC, csrc, cdst);
    else
      k_edge<1><<<dim3(N_EDGES / 128), blk, 0, stream>>>(
          e_buf, WeT + l * 65536, XW, 1024, 512, 768, arena + A_BE + l * 256,
          arena, eaC, csrc, cdst);
    k_node_update<<<dim3(N_NODES), blk, 0, stream>>>(xf, xbf, XW, agg);
  }
  // layer 3: edge update + fused MLP head (e4 never materialized), 128-row
  k_node_gemm<<<dim3(79, 2), blk, 0, stream>>>(xbf, nodeBT + 786432, biascat + 3072, XW, 512);
  k_edge_final<<<dim3(N_EDGES / 128), blk, 0, stream>>>(
      e_buf, WeT + 196608, XW, 512, 0, 256, arena + A_BE + 768,
      arena, eaC, csrc, cdst, Wm1T, eid, flag, d_out);
}

// Round 13
// 886.002 us; speedup vs baseline: 1.6218x; 1.0609x over previous
//
#include <hip/hip_runtime.h>
#include <stdint.h>

#define N_NODES 10000
#define N_EDGES 320000

using bf16x8 = __attribute__((ext_vector_type(8))) short;
using fp32x4 = __attribute__((ext_vector_type(4))) float;
using u16x8 = __attribute__((ext_vector_type(8))) unsigned short;
using i32x4 = __attribute__((ext_vector_type(4))) int;

__device__ __forceinline__ float bf2f(unsigned short u) {
  union { unsigned int i; float f; } v; v.i = ((unsigned int)u) << 16; return v.f;
}
__device__ __forceinline__ unsigned short f2bf(float f) {
  union { float f; unsigned int i; } v; v.f = f;
  unsigned int x = v.i;
  x += 0x7fffu + ((x >> 16) & 1u);
  return (unsigned short)(x >> 16);
}

// ---------------- internal bf16 arena (element offsets) ---------------------
#define A_POS 0
#define A_EA 20000
#define A_WP 340000
#define A_BP 340512
#define A_WA 340768
#define A_BA 341024
#define A_W1 341280
#define A_B1 537888
#define A_W2 538656
#define A_B2 735264
#define A_WE 736032
#define A_BE 998176
#define A_WS 999200
#define A_WT 1261344
#define A_WM1 1523488
#define A_BM1 1556384
#define A_AL 1556512
#define A_WM2 1556544
#define A_BM2 1556672
#define ARENA_USED 1556673
#define ARENA_TOT 1556736

__constant__ int g_off[19] = {A_POS, A_EA, A_WP, A_BP, A_WA, A_BA, A_W1, A_B1,
                              A_W2, A_B2, A_WE, A_BE, A_WS, A_WT, A_WM1,
                              A_BM1, A_AL, A_WM2, A_BM2};

struct Ptrs { const void* p[19]; };

// Dtype detector: fp32 read as bf16 halves yields ~47% |v|>100; bf16 never.
__global__ void k_detect(const unsigned short* wpraw, int* flag) {
  __shared__ int cnt;
  int tid = threadIdx.x;
  if (tid == 0) cnt = 0;
  __syncthreads();
  float v0 = bf2f(wpraw[tid]);
  float v1 = bf2f(wpraw[256 + tid]);
  int big = (fabsf(v0) > 100.f ? 1 : 0) + (fabsf(v1) > 100.f ? 1 : 0);
  atomicAdd(&cnt, big);
  __syncthreads();
  if (tid == 0) *flag = (cnt > 10) ? 1 : 0;  // 1 = fp32 inputs
}

// Normalize all float inputs into the bf16 arena (flattened grid).
__global__ void k_cast(Ptrs ptrs, const int* __restrict__ flag,
                       unsigned short* __restrict__ arena) {
  int a = blockIdx.x * 256 + threadIdx.x;
  if (a >= ARENA_USED) return;
  int z = 0;
#pragma unroll
  for (int j = 1; j < 19; ++j) if (a >= g_off[j]) z = j;
  int i = a - g_off[z];
  float v;
  if (*flag) v = ((const float*)ptrs.p[z])[i];
  else       v = bf2f(((const unsigned short*)ptrs.p[z])[i]);
  arena[a] = f2bf(v);
}

// ---------------------------------------------------------------------------
// Weight prep: transpose [K,N] -> n-major [N,K] (row = out-col, 512B rows).
// nodeBT per layer l<3: [W1T|W2T|WsT|WtT] (1024x256); l==3: [WsT|WtT].
// ---------------------------------------------------------------------------
__global__ void k_prep(const unsigned short* __restrict__ arena,
                       unsigned short* nodeBT, unsigned short* WeT,
                       unsigned short* Wm1T, unsigned short* biascat) {
  int z = blockIdx.z;
  int i = blockIdx.x * 256 + threadIdx.x;
  if (z == 19) {  // bias concat: 3 x [b1|b2|0|0] (1024) then 512 zeros
    if (i < 3072) {
      int l = i >> 10, j = i & 1023;
      unsigned short v = 0;
      if (j < 256) v = arena[A_B1 + l * 256 + j];
      else if (j < 512) v = arena[A_B2 + l * 256 + (j - 256)];
      biascat[i] = v;
    } else if (i < 3584) {
      biascat[i] = 0;
    }
    return;
  }
  const unsigned short* src; unsigned short* dst; int srcN = 256;
  if (z < 3)       {                 src = arena + A_W1 + z * 65536; dst = nodeBT + z * 262144; }
  else if (z < 6)  { int l = z - 3;  src = arena + A_W2 + l * 65536; dst = nodeBT + l * 262144 + 65536; }
  else if (z < 10) { int l = z - 6;  src = arena + A_WS + l * 65536;
                     dst = (l < 3) ? nodeBT + l * 262144 + 131072 : nodeBT + 786432; }
  else if (z < 14) { int l = z - 10; src = arena + A_WT + l * 65536;
                     dst = (l < 3) ? nodeBT + l * 262144 + 196608 : nodeBT + 786432 + 65536; }
  else if (z < 18) { int l = z - 14; src = arena + A_WE + l * 65536; dst = WeT + l * 65536; }
  else             { src = arena + A_WM1; dst = Wm1T; srcN = 128; }
  if (i < srcN * 256) {
    int k = i & 255, n = i >> 8;
    dst[i] = src[k * srcN + n];  // dst[n][k] = src[k][n]
  }
}

// x0 = pos @ Wp + bp (K=2), fp32 master + bf16 copy
__global__ void k_init_x(const unsigned short* __restrict__ arena,
                         float* __restrict__ xf, unsigned short* __restrict__ xbf) {
  int n = blockIdx.x, c = threadIdx.x;
  float p0 = bf2f(arena[A_POS + 2 * n]), p1 = bf2f(arena[A_POS + 2 * n + 1]);
  float v = fmaf(p0, bf2f(arena[A_WP + c]),
                 fmaf(p1, bf2f(arena[A_WP + 256 + c]), bf2f(arena[A_BP + c])));
  long idx = ((long)n << 8) + c;
  xf[idx] = v;
  xbf[idx] = f2bf(v);
}

// ---------------- CSR build (by dst). e lives in CSR row order everywhere ---
__global__ void k_hist(const int* __restrict__ dstA, int* __restrict__ deg) {
  int i = blockIdx.x * 256 + threadIdx.x;
  if (i < N_EDGES) {
    int d = dstA[i];
    if ((unsigned)d < N_NODES) atomicAdd(&deg[d], 1);
  }
}

__global__ void k_scan(const int* __restrict__ deg, int* __restrict__ rowptr,
                       int* __restrict__ cursor) {
  __shared__ int part[256];
  int tid = threadIdx.x;
  int base = tid * 40;
  int s = 0;
  for (int i = 0; i < 40; ++i) {
    int idx = base + i;
    if (idx < N_NODES) s += deg[idx];
  }
  part[tid] = s;
  __syncthreads();
  if (tid == 0) {
    int run = 0;
    for (int i = 0; i < 256; ++i) { int t = part[i]; part[i] = run; run += t; }
    rowptr[N_NODES] = run;
  }
  __syncthreads();
  int run = part[tid];
  for (int i = 0; i < 40; ++i) {
    int idx = base + i;
    if (idx < N_NODES) { rowptr[idx] = run; cursor[idx] = run; run += deg[idx]; }
  }
}

// Also emits csrc/cdst (endpoints in CSR order) and eaC (ea gathered to CSR).
__global__ void k_fill(const int* __restrict__ dstA, const int* __restrict__ srcA,
                       const unsigned short* __restrict__ arena,
                       int* __restrict__ cursor, int* __restrict__ eid,
                       int* __restrict__ csrc, int* __restrict__ cdst,
                       unsigned short* __restrict__ eaC) {
  int i = blockIdx.x * 256 + threadIdx.x;
  if (i < N_EDGES) {
    int d = dstA[i]; if ((unsigned)d >= N_NODES) d = 0;
    int p = atomicAdd(&cursor[d], 1);
    if ((unsigned)p < N_EDGES) {
      eid[p] = i;
      int s = srcA[i]; if ((unsigned)s >= N_NODES) s = 0;
      csrc[p] = s;
      cdst[p] = d;
      eaC[p] = arena[A_EA + i];
    }
  }
}

// ---------------------------------------------------------------------------
// Swapped-operand GEMM core with PERMUTED column mapping: A-frag lane ll of
// fragment mt loads WT row oc = colBase + (ll>>2)*(MT*4) + mt*4 + (ll&3).
// Lane (q,ll) reg r of frag mt then holds out-col colBase + q*(MT*4) + mt*4+r
// -> each lane's values cover MT*4 CONSECUTIVE cols (full-line epilogue).
// B-frag: LDS tile row (n=ll). D row = nt*16+ll. NTT = row-tiles (rows/16).
// LDS pitch 528B -> <=2-way bank aliasing (free, m136).
// NOTE (r11): per-thread A-frag VMEM (8ks x MT) is independent of tile rows
// -> 128-row tiles measured fastest for edge kernels (143 vs 169 at 64-row).
// ---------------------------------------------------------------------------
#define SM_PITCH 528

template <bool NT, int ROWS>
__device__ __forceinline__ void stage_tile(char* smc, const unsigned short* src,
                                           long rowBase) {
  int tid = threadIdx.x;
#pragma unroll
  for (int it = 0; it < ROWS / 8; ++it) {   // ROWS rows x 32 groups of 16B
    int lin = it * 256 + tid;
    int row = lin >> 5, g = lin & 31;
    const i32x4* p = (const i32x4*)((const char*)src + ((rowBase + row) << 9) + (g << 4));
    i32x4 v = NT ? __builtin_nontemporal_load(p) : *p;
    *(i32x4*)(smc + row * SM_PITCH + (g << 4)) = v;
  }
}

template <int MT, int NTT>
__device__ __forceinline__ void gemm_swap(const char* smc, const unsigned short* WT,
                                          int colBase, fp32x4 (&acc)[MT][NTT]) {
  const int lane = threadIdx.x & 63;
  const int q = lane >> 4, ll = lane & 15;
  const int llperm = ((ll >> 2) * (MT * 4)) + (ll & 3);  // permuted col offset
#pragma unroll
  for (int ks = 0; ks < 8; ++ks) {
    bf16x8 a[MT];
#pragma unroll
    for (int mt = 0; mt < MT; ++mt) {
      int oc = colBase + llperm + mt * 4;
      a[mt] = *(const bf16x8*)((const char*)WT + ((long)oc << 9) + (ks << 6) + (q << 4));
    }
    bf16x8 b[NTT];
#pragma unroll
    for (int nt = 0; nt < NTT; ++nt)
      b[nt] = *(const bf16x8*)(smc + (nt * 16 + ll) * SM_PITCH + (ks << 6) + (q << 4));
#pragma unroll
    for (int mt = 0; mt < MT; ++mt)
#pragma unroll
      for (int nt = 0; nt < NTT; ++nt)
        acc[mt][nt] = __builtin_amdgcn_mfma_f32_16x16x32_bf16(a[mt], b[nt], acc[mt][nt], 0, 0, 0);
  }
}

// Shared epilogue: e_new = e_old + relu(acc + xs + xt + be), updated in LDS.
template <int NTT>
__device__ __forceinline__ void edge_epilogue(
    char* smc, const fp32x4 (&acc)[4][NTT], const int* s_src, const int* s_dst,
    const unsigned short* XW, int xw_pitch, int xs_off, int xt_off,
    const unsigned short* bePtr, int cb, int ll) {
  u16x8 be0 = *(const u16x8*)(bePtr + cb);
  u16x8 be1 = *(const u16x8*)(bePtr + cb + 8);
#pragma unroll
  for (int nt = 0; nt < NTT; ++nt) {
    int el = nt * 16 + ll;
    int sn = s_src[el], dn = s_dst[el];
    const unsigned short* xsrow = XW + (long)sn * xw_pitch + xs_off + cb;
    const unsigned short* xtrow = XW + (long)dn * xw_pitch + xt_off + cb;
    u16x8 xs0 = *(const u16x8*)(xsrow);
    u16x8 xs1 = *(const u16x8*)(xsrow + 8);
    u16x8 xt0 = *(const u16x8*)(xtrow);
    u16x8 xt1 = *(const u16x8*)(xtrow + 8);
    u16x8* slot = (u16x8*)(smc + el * SM_PITCH + cb * 2);
    u16x8 er0 = slot[0], er1 = slot[1];
    u16x8 o0, o1;
#pragma unroll
    for (int mt = 0; mt < 4; ++mt)
#pragma unroll
      for (int r = 0; r < 4; ++r) {
        int i = mt * 4 + r;
        float xsv = bf2f(i < 8 ? xs0[i] : xs1[i - 8]);
        float xtv = bf2f(i < 8 ? xt0[i] : xt1[i - 8]);
        float erv = bf2f(i < 8 ? er0[i] : er1[i - 8]);
        float bev = bf2f(i < 8 ? be0[i] : be1[i - 8]);
        float v = acc[mt][nt][r] + xsv + xtv + bev;
        v = fmaxf(v, 0.f);
        unsigned short ob = f2bf(erv + v);
        if (i < 8) o0[i] = ob; else o1[i - 8] = ob;
      }
    slot[0] = o0;
    slot[1] = o1;  // slot owned by this lane only
  }
}

// ---------------------------------------------------------------------------
// Edge kernel (CSR row order), 128-row tiles @ 2 blocks/CU.
// MODE 0: first layer, e0 built in LDS from eaC; writeback.
// MODE 1: mid layer, stage e; writeback.
// ---------------------------------------------------------------------------
template <int MODE>
__global__ __launch_bounds__(256, 2) void k_edge(
    unsigned short* __restrict__ e, const unsigned short* __restrict__ WT,
    const unsigned short* __restrict__ XW, int xw_pitch, int xs_off, int xt_off,
    const unsigned short* __restrict__ bePtr, const unsigned short* __restrict__ arena,
    const unsigned short* __restrict__ eaC,
    const int* __restrict__ csrc, const int* __restrict__ cdst) {
  __shared__ int4 sm4[128 * 33];
  __shared__ int s_src[128];
  __shared__ int s_dst[128];
  char* smc = (char*)sm4;
  const long tileBase = (long)blockIdx.x * 128;
  const int tid = threadIdx.x;
  const int wave = tid >> 6, lane = tid & 63;
  const int q = lane >> 4, ll = lane & 15;
  const int colBase = wave * 64;

  if (MODE == 0) {
#pragma unroll
    for (int it = 0; it < 16; ++it) {
      int lin = it * 256 + tid;
      int row = lin >> 5, g = lin & 31;
      float eav = bf2f(eaC[tileBase + row]);
      int c0 = g * 8;
      bf16x8 ov;
#pragma unroll
      for (int j = 0; j < 8; ++j) {
        float f = fmaf(eav, bf2f(arena[A_WA + c0 + j]), bf2f(arena[A_BA + c0 + j]));
        ((unsigned short*)&ov)[j] = f2bf(f);
      }
      *(bf16x8*)(smc + row * SM_PITCH + (g << 4)) = ov;
    }
  } else {
    stage_tile<true, 128>(smc, e, tileBase);
  }
  if (tid < 128) {
    long edge = tileBase + tid;
    int s = csrc[edge]; if ((unsigned)s >= N_NODES) s = 0;
    int d = cdst[edge]; if ((unsigned)d >= N_NODES) d = 0;
    s_src[tid] = s;
    s_dst[tid] = d;
  }
  __syncthreads();

  fp32x4 acc[4][8];
#pragma unroll
  for (int mt = 0; mt < 4; ++mt)
#pragma unroll
    for (int nt = 0; nt < 8; ++nt) acc[mt][nt] = 0.f;
  gemm_swap<4, 8>(smc, WT, colBase, acc);
  __syncthreads();  // all waves done reading A-tile before in-place update

  edge_epilogue<8>(smc, acc, s_src, s_dst, XW, xw_pitch, xs_off, xt_off,
                   bePtr, colBase + q * 16, ll);
  __syncthreads();  // tile fully updated

  // Coalesced full-line writeback: 16B/lane, 1KB contiguous per instruction.
#pragma unroll
  for (int it = 0; it < 16; ++it) {
    int lin = it * 256 + tid;
    int row = lin >> 5, g = lin & 31;
    i32x4 v = *(const i32x4*)(smc + row * SM_PITCH + (g << 4));
    __builtin_nontemporal_store(v, (i32x4*)((char*)e + ((tileBase + row) << 9) + (g << 4)));
  }
}

// ---------------------------------------------------------------------------
// Fused last-2 edge kernel: stage e2; edge-update(l=2) -> e3 in LDS;
// edge-update(l=3) -> e4 in LDS; fused MLP head -> out.
// e3 and e4 NEVER touch HBM (saves 328MB of traffic + a dispatch).
// Requires XW2 (layer-2 node gemm, pitch 1024) and XW3 (layer-3, pitch 512)
// both resident — node_update(2) + node_gemm(3) run before this.
// ---------------------------------------------------------------------------
__global__ __launch_bounds__(256, 2) void k_edge_last2(
    const unsigned short* __restrict__ e, const unsigned short* __restrict__ WeT2,
    const unsigned short* __restrict__ WeT3,
    const unsigned short* __restrict__ XW2, const unsigned short* __restrict__ XW3,
    const unsigned short* __restrict__ arena, const unsigned short* __restrict__ eaC,
    const int* __restrict__ csrc, const int* __restrict__ cdst,
    const unsigned short* __restrict__ Wm1T, const int* __restrict__ eid,
    const int* __restrict__ flag, void* __restrict__ out) {
  __shared__ int4 sm4[128 * 33];
  __shared__ int s_src[128];
  __shared__ int s_dst[128];
  char* smc = (char*)sm4;
  const long tileBase = (long)blockIdx.x * 128;
  const int tid = threadIdx.x;
  const int wave = tid >> 6, lane = tid & 63;
  const int q = lane >> 4, ll = lane & 15;
  const int colBase = wave * 64;

  stage_tile<true, 128>(smc, e, tileBase);
  if (tid < 128) {
    long edge = tileBase + tid;
    int s = csrc[edge]; if ((unsigned)s >= N_NODES) s = 0;
    int d = cdst[edge]; if ((unsigned)d >= N_NODES) d = 0;
    s_src[tid] = s;
    s_dst[tid] = d;
  }
  __syncthreads();

  // ---- edge update l=2: e3 = e2 + relu(e2@We2 + XW2s + XW2t + be2) ----
  fp32x4 acc[4][8];
#pragma unroll
  for (int mt = 0; mt < 4; ++mt)
#pragma unroll
    for (int nt = 0; nt < 8; ++nt) acc[mt][nt] = 0.f;
  gemm_swap<4, 8>(smc, WeT2, colBase, acc);
  __syncthreads();
  edge_epilogue<8>(smc, acc, s_src, s_dst, XW2, 1024, 512, 768,
                   arena + A_BE + 2 * 256, colBase + q * 16, ll);
  __syncthreads();  // e3 complete in LDS

  // ---- edge update l=3: e4 = e3 + relu(e3@We3 + XW3s + XW3t + be3) ----
#pragma unroll
  for (int mt = 0; mt < 4; ++mt)
#pragma unroll
    for (int nt = 0; nt < 8; ++nt) acc[mt][nt] = 0.f;
  gemm_swap<4, 8>(smc, WeT3, colBase, acc);
  __syncthreads();
  edge_epilogue<8>(smc, acc, s_src, s_dst, XW3, 512, 0, 256,
                   arena + A_BE + 3 * 256, colBase + q * 16, ll);
  __syncthreads();  // e4 complete in LDS

  // ---- fused MLP head: h = prelu(e4@Wm1[:256] + eaC*Wm1[256] + bm1); out = h@Wm2+bm2
  fp32x4 acc2[2][8];
#pragma unroll
  for (int mt = 0; mt < 2; ++mt)
#pragma unroll
    for (int nt = 0; nt < 8; ++nt) acc2[mt][nt] = 0.f;
  const int colBase2 = wave * 32;
  gemm_swap<2, 8>(smc, Wm1T, colBase2, acc2);

  const int cb2 = colBase2 + q * 8;  // 8 consecutive out-cols per lane (MT=2)
  float alphaf = bf2f(arena[A_AL]);
  float bmc[8], wl[8], w2c[8];
#pragma unroll
  for (int i = 0; i < 8; ++i) {
    bmc[i] = bf2f(arena[A_BM1 + cb2 + i]);
    wl[i] = bf2f(arena[A_WM1 + 32768 + cb2 + i]);
    w2c[i] = bf2f(arena[A_WM2 + cb2 + i]);
  }
  __syncthreads();             // all waves done reading LDS for gemm2
  float* part = (float*)smc;   // alias tile as [128][4] fp32 partials
#pragma unroll
  for (int nt = 0; nt < 8; ++nt) {
    int el = nt * 16 + ll;
    float eav = bf2f(eaC[tileBase + el]);
    float ps = 0.f;
#pragma unroll
    for (int mt = 0; mt < 2; ++mt)
#pragma unroll
      for (int r = 0; r < 4; ++r) {
        int i = mt * 4 + r;
        float h = acc2[mt][nt][r] + bmc[i] + eav * wl[i];
        h = (h > 0.f) ? h : alphaf * h;
        ps += h * w2c[i];
      }
    ps += __shfl_xor(ps, 16, 64);
    ps += __shfl_xor(ps, 32, 64);
    if (q == 0) part[el * 4 + wave] = ps;
  }
  __syncthreads();
  if (tid < 128) {
    float t = part[tid * 4] + part[tid * 4 + 1] + part[tid * 4 + 2] + part[tid * 4 + 3]
            + bf2f(arena[A_BM2]);
    long row = tileBase + tid;
    int oe = eid[row]; if ((unsigned)oe >= N_EDGES) oe = 0;
    if (*flag) ((float*)out)[oe] = t;
    else       ((unsigned short*)out)[oe] = f2bf(t);
  }
}

// Node-side GEMM: XW = x_bf @ weights (+bias), bf16 out. 128 rows x 128 cols
// per block (MT=2: halves per-thread A-frag VMEM, doubles block parallelism).
__global__ __launch_bounds__(256, 2) void k_node_gemm(
    const unsigned short* __restrict__ xbf, const unsigned short* __restrict__ WT,
    const unsigned short* __restrict__ bias, unsigned short* __restrict__ out,
    int out_pitch) {
  __shared__ int4 sm4[128 * 33];
  char* smc = (char*)sm4;
  const long tileBase = (long)blockIdx.x * 128;
  // clamped staging (10000 rows not divisible by 128)
  {
    int tid = threadIdx.x;
#pragma unroll
    for (int it = 0; it < 16; ++it) {
      int lin = it * 256 + tid;
      int row = lin >> 5, g = lin & 31;
      long rg = tileBase + row;
      if (rg > N_NODES - 1) rg = N_NODES - 1;
      i32x4 v = *(const i32x4*)((const char*)xbf + (rg << 9) + (g << 4));
      *(i32x4*)(smc + row * SM_PITCH + (g << 4)) = v;
    }
  }
  __syncthreads();
  fp32x4 acc[2][8];
#pragma unroll
  for (int mt = 0; mt < 2; ++mt)
#pragma unroll
    for (int nt = 0; nt < 8; ++nt) acc[mt][nt] = 0.f;
  const int tid = threadIdx.x, wave = tid >> 6, lane = tid & 63;
  const int q = lane >> 4, ll = lane & 15;
  const int colBase = blockIdx.y * 128 + wave * 32;
  gemm_swap<2, 8>(smc, WT, colBase, acc);

  const int cb = colBase + q * 8;  // 8 consecutive out-cols per lane
  u16x8 bs8 = *(const u16x8*)(bias + cb);

#pragma unroll
  for (int nt = 0; nt < 8; ++nt) {
    long nn = tileBase + nt * 16 + ll;
    if (nn >= N_NODES) continue;
    u16x8 o0;
#pragma unroll
    for (int mt = 0; mt < 2; ++mt)
#pragma unroll
      for (int r = 0; r < 4; ++r) {
        int i = mt * 4 + r;
        o0[i] = f2bf(acc[mt][nt][r] + bf2f(bs8[i]));
      }
    *(u16x8*)(out + nn * out_pitch + cb) = o0;
  }
}

// ---------------------------------------------------------------------------
// Edge-tiled agg: block = 64 consecutive CSR rows. Loads batched 8-wide ahead
// of the run-boundary branch so they pipeline. One atomicAdd per dst-run.
// At 33us it sits at its 164MB e-read HBM floor.
// ---------------------------------------------------------------------------
template <bool FIRST>
__global__ void k_agg(const int* __restrict__ csrc, const int* __restrict__ cdst,
                      const unsigned short* __restrict__ e,
                      const unsigned short* __restrict__ eaC,
                      const unsigned short* __restrict__ arena,
                      const unsigned short* __restrict__ XW, int xw_pitch, int x2_off,
                      float* __restrict__ agg) {
  __shared__ int s_src[64];
  __shared__ int s_dst[64];
  const long base = (long)blockIdx.x * 64;
  const int c = threadIdx.x;
  if (c < 64) {
    long r = base + c;
    int s = csrc[r]; if ((unsigned)s >= N_NODES) s = 0;
    int d = cdst[r]; if ((unsigned)d >= N_NODES) d = 0;
    s_src[c] = s;
    s_dst[c] = d;
  }
  __syncthreads();
  float wac = 0.f, bac = 0.f;
  if (FIRST) { wac = bf2f(arena[A_WA + c]); bac = bf2f(arena[A_BA + c]); }
  float a = 0.f;
  int run = s_dst[0];
  for (int b8 = 0; b8 < 64; b8 += 8) {
    float evv[8], x2v[8];
#pragma unroll
    for (int j = 0; j < 8; ++j) {
      int row = b8 + j;
      if (FIRST) evv[j] = fmaf(bf2f(eaC[base + row]), wac, bac);
      else evv[j] = bf2f(__builtin_nontemporal_load(e + ((base + row) << 8) + c));
      x2v[j] = bf2f(XW[(long)s_src[row] * xw_pitch + x2_off + c]);
    }
#pragma unroll
    for (int j = 0; j < 8; ++j) {
      int d = s_dst[b8 + j];
      if (d != run) {  // uniform across the block (dst-sorted)
        atomicAdd(&agg[((long)run << 8) + c], a);
        a = 0.f;
        run = d;
      }
      float gate = 1.f / (1.f + __expf(-evv[j]));
      a = fmaf(gate, x2v[j], a);
    }
  }
  atomicAdd(&agg[((long)run << 8) + c], a);
}

// x += relu(xW1+b1 + agg); refresh bf16 copy; zero agg for the next layer.
__global__ void k_node_update(float* __restrict__ xf, unsigned short* __restrict__ xbf,
                              const unsigned short* __restrict__ XW,
                              float* __restrict__ agg) {
  int n = blockIdx.x, c = threadIdx.x;
  long idx = ((long)n << 8) + c;
  float av = agg[idx];
  agg[idx] = 0.f;
  float t = bf2f(XW[((long)n << 10) + c]) + av;
  float nx = xf[idx] + fmaxf(t, 0.f);
  xf[idx] = nx;
  xbf[idx] = f2bf(nx);
}

// ---------------------------------------------------------------------------
extern "C" void kernel_launch(void* const* d_in, const int* in_sizes, int n_in,
                              void* d_out, int out_size, void* d_ws, size_t ws_size,
                              hipStream_t stream) {
  const int* eidx = (const int*)d_in[2];
  const int* srcA = eidx;
  const int* dstA = eidx + N_EDGES;
  (void)in_sizes; (void)n_in; (void)out_size;

  char* ws = (char*)d_ws;
  size_t off = 0;
  auto alloc = [&](size_t bytes) -> char* {
    char* p = ws + off;
    off = (off + bytes + 255) & ~(size_t)255;
    return p;
  };
  unsigned short* e_buf   = (unsigned short*)alloc((size_t)N_EDGES * 256 * 2);  // 164 MB
  float*          xf      = (float*)alloc((size_t)N_NODES * 256 * 4);
  unsigned short* xbf     = (unsigned short*)alloc((size_t)N_NODES * 256 * 2);
  unsigned short* XW      = (unsigned short*)alloc((size_t)N_NODES * 1024 * 2);
  unsigned short* XW3     = (unsigned short*)alloc((size_t)N_NODES * 512 * 2);
  float*          agg     = (float*)alloc((size_t)N_NODES * 256 * 4);
  unsigned short* nodeBT  = (unsigned short*)alloc((size_t)917504 * 2);
  unsigned short* WeT     = (unsigned short*)alloc((size_t)4 * 65536 * 2);
  unsigned short* Wm1T    = (unsigned short*)alloc((size_t)32768 * 2);
  unsigned short* biascat = (unsigned short*)alloc((size_t)3584 * 2);
  unsigned short* arena   = (unsigned short*)alloc((size_t)ARENA_TOT * 2);
  int* deg    = (int*)alloc((size_t)N_NODES * 4);
  int* rowptr = (int*)alloc((size_t)(N_NODES + 1) * 4);
  int* cursor = (int*)alloc((size_t)N_NODES * 4);
  int* eid    = (int*)alloc((size_t)N_EDGES * 4);
  int* csrc   = (int*)alloc((size_t)N_EDGES * 4);
  int* cdst   = (int*)alloc((size_t)N_EDGES * 4);
  unsigned short* eaC = (unsigned short*)alloc((size_t)N_EDGES * 2);
  int* flag   = (int*)alloc(4);
  if (ws_size < off) return;  // distinctive signature: out stays all-zero

  Ptrs ptrs;
  {
    int map[19] = {0, 1, 3, 4, 5, 6, 7, 8, 9, 10, 11, 12, 13, 14, 15, 16, 17, 18, 19};
    for (int j = 0; j < 19; ++j) ptrs.p[j] = d_in[map[j]];
  }

  dim3 blk(256);
  k_detect<<<dim3(1), blk, 0, stream>>>((const unsigned short*)d_in[3], flag);
  k_cast<<<dim3((ARENA_USED + 255) / 256), blk, 0, stream>>>(ptrs, flag, arena);
  k_prep<<<dim3(256, 1, 20), blk, 0, stream>>>(arena, nodeBT, WeT, Wm1T, biascat);
  k_init_x<<<dim3(N_NODES), blk, 0, stream>>>(arena, xf, xbf);
  hipMemsetAsync(deg, 0, (size_t)N_NODES * 4, stream);
  hipMemsetAsync(agg, 0, (size_t)N_NODES * 256 * 4, stream);
  k_hist<<<dim3(N_EDGES / 256), blk, 0, stream>>>(dstA, deg);
  k_scan<<<dim3(1), blk, 0, stream>>>(deg, rowptr, cursor);
  k_fill<<<dim3(N_EDGES / 256), blk, 0, stream>>>(dstA, srcA, arena, cursor, eid, csrc,
                                                  cdst, eaC);

  for (int l = 0; l < 3; ++l) {
    k_node_gemm<<<dim3(79, 8), blk, 0, stream>>>(xbf, nodeBT + l * 262144,
                                                 biascat + l * 1024, XW, 1024);
    if (l == 0)
      k_agg<true><<<dim3(N_EDGES / 64), blk, 0, stream>>>(csrc, cdst, e_buf, eaC, arena,
                                                          XW, 1024, 256, agg);
    else
      k_agg<false><<<dim3(N_EDGES / 64), blk, 0, stream>>>(csrc, cdst, e_buf, eaC, arena,
                                                           XW, 1024, 256, agg);
    if (l == 0)
      k_edge<0><<<dim3(N_EDGES / 128), blk, 0, stream>>>(
          e_buf, WeT, XW, 1024, 512, 768, arena + A_BE, arena, eaC, csrc, cdst);
    else if (l == 1)
      k_edge<1><<<dim3(N_EDGES / 128), blk, 0, stream>>>(
          e_buf, WeT + l * 65536, XW, 1024, 512, 768, arena + A_BE + l * 256,
          arena, eaC, csrc, cdst);
    k_node_update<<<dim3(N_NODES), blk, 0, stream>>>(xf, xbf, XW, agg);
    // l == 2: edge update deferred into k_edge_last2 (e2 stays valid; agg2
    // and node_update2 already consumed it / don't touch it).
  }
  // layer-3 node gemm (XW3 = x3 @ [Ws3|Wt3]), then the fused last-2 kernel.
  k_node_gemm<<<dim3(79, 4), blk, 0, stream>>>(xbf, nodeBT + 786432, biascat + 3072, XW3, 512);
  k_edge_last2<<<dim3(N_EDGES / 128), blk, 0, stream>>>(
      e_buf, WeT + 2 * 65536, WeT + 3 * 65536, XW, XW3, arena, eaC,
      csrc, cdst, Wm1T, eid, flag, d_out);
}

// Round 14
// 868.742 us; speedup vs baseline: 1.6540x; 1.0199x over previous
//
#include <hip/hip_runtime.h>
#include <stdint.h>

#define N_NODES 10000
#define N_EDGES 320000

using bf16x8 = __attribute__((ext_vector_type(8))) short;
using fp32x4 = __attribute__((ext_vector_type(4))) float;
using u16x8 = __attribute__((ext_vector_type(8))) unsigned short;
using i32x4 = __attribute__((ext_vector_type(4))) int;

__device__ __forceinline__ float bf2f(unsigned short u) {
  union { unsigned int i; float f; } v; v.i = ((unsigned int)u) << 16; return v.f;
}
__device__ __forceinline__ unsigned short f2bf(float f) {
  union { float f; unsigned int i; } v; v.f = f;
  unsigned int x = v.i;
  x += 0x7fffu + ((x >> 16) & 1u);
  return (unsigned short)(x >> 16);
}

// ---------------- internal bf16 arena (element offsets) ---------------------
#define A_POS 0
#define A_EA 20000
#define A_WP 340000
#define A_BP 340512
#define A_WA 340768
#define A_BA 341024
#define A_W1 341280
#define A_B1 537888
#define A_W2 538656
#define A_B2 735264
#define A_WE 736032
#define A_BE 998176
#define A_WS 999200
#define A_WT 1261344
#define A_WM1 1523488
#define A_BM1 1556384
#define A_AL 1556512
#define A_WM2 1556544
#define A_BM2 1556672
#define ARENA_USED 1556673
#define ARENA_TOT 1556736

__constant__ int g_off[19] = {A_POS, A_EA, A_WP, A_BP, A_WA, A_BA, A_W1, A_B1,
                              A_W2, A_B2, A_WE, A_BE, A_WS, A_WT, A_WM1,
                              A_BM1, A_AL, A_WM2, A_BM2};

struct Ptrs { const void* p[19]; };

// Dtype detector (block 0) + deg zeroing (all blocks).
__global__ void k_detect(const unsigned short* wpraw, int* flag, int* deg) {
  int i = blockIdx.x * 256 + threadIdx.x;
  if (i < N_NODES) deg[i] = 0;
  if (blockIdx.x == 0) {
    __shared__ int cnt;
    int tid = threadIdx.x;
    if (tid == 0) cnt = 0;
    __syncthreads();
    float v0 = bf2f(wpraw[tid]);
    float v1 = bf2f(wpraw[256 + tid]);
    int big = (fabsf(v0) > 100.f ? 1 : 0) + (fabsf(v1) > 100.f ? 1 : 0);
    atomicAdd(&cnt, big);
    __syncthreads();
    if (tid == 0) *flag = (cnt > 10) ? 1 : 0;  // 1 = fp32 inputs
  }
}

// Normalize all float inputs into the bf16 arena (flattened grid).
__global__ void k_cast(Ptrs ptrs, const int* __restrict__ flag,
                       unsigned short* __restrict__ arena) {
  int a = blockIdx.x * 256 + threadIdx.x;
  if (a >= ARENA_USED) return;
  int z = 0;
#pragma unroll
  for (int j = 1; j < 19; ++j) if (a >= g_off[j]) z = j;
  int i = a - g_off[z];
  float v;
  if (*flag) v = ((const float*)ptrs.p[z])[i];
  else       v = bf2f(((const unsigned short*)ptrs.p[z])[i]);
  arena[a] = f2bf(v);
}

// ---------------------------------------------------------------------------
// Weight prep: transpose [K,N] -> n-major [N,K] (row = out-col, 512B rows).
// nodeBT per layer l<3: [W1T|W2T|WsT|WtT] (1024x256); l==3: [WsT|WtT].
// ---------------------------------------------------------------------------
__global__ void k_prep(const unsigned short* __restrict__ arena,
                       unsigned short* nodeBT, unsigned short* WeT,
                       unsigned short* Wm1T, unsigned short* biascat) {
  int z = blockIdx.z;
  int i = blockIdx.x * 256 + threadIdx.x;
  if (z == 19) {  // bias concat: 3 x [b1|b2|0|0] (1024) then 512 zeros
    if (i < 3072) {
      int l = i >> 10, j = i & 1023;
      unsigned short v = 0;
      if (j < 256) v = arena[A_B1 + l * 256 + j];
      else if (j < 512) v = arena[A_B2 + l * 256 + (j - 256)];
      biascat[i] = v;
    } else if (i < 3584) {
      biascat[i] = 0;
    }
    return;
  }
  const unsigned short* src; unsigned short* dst; int srcN = 256;
  if (z < 3)       {                 src = arena + A_W1 + z * 65536; dst = nodeBT + z * 262144; }
  else if (z < 6)  { int l = z - 3;  src = arena + A_W2 + l * 65536; dst = nodeBT + l * 262144 + 65536; }
  else if (z < 10) { int l = z - 6;  src = arena + A_WS + l * 65536;
                     dst = (l < 3) ? nodeBT + l * 262144 + 131072 : nodeBT + 786432; }
  else if (z < 14) { int l = z - 10; src = arena + A_WT + l * 65536;
                     dst = (l < 3) ? nodeBT + l * 262144 + 196608 : nodeBT + 786432 + 65536; }
  else if (z < 18) { int l = z - 14; src = arena + A_WE + l * 65536; dst = WeT + l * 65536; }
  else             { src = arena + A_WM1; dst = Wm1T; srcN = 128; }
  if (i < srcN * 256) {
    int k = i & 255, n = i >> 8;
    dst[i] = src[k * srcN + n];  // dst[n][k] = src[k][n]
  }
}

// x0 = pos @ Wp + bp (K=2), fp32 master + bf16 copy; also zeroes agg
// (one thread per agg element — replaces the agg memset each call).
__global__ void k_init_x(const unsigned short* __restrict__ arena,
                         float* __restrict__ xf, unsigned short* __restrict__ xbf,
                         float* __restrict__ agg) {
  int n = blockIdx.x, c = threadIdx.x;
  float p0 = bf2f(arena[A_POS + 2 * n]), p1 = bf2f(arena[A_POS + 2 * n + 1]);
  float v = fmaf(p0, bf2f(arena[A_WP + c]),
                 fmaf(p1, bf2f(arena[A_WP + 256 + c]), bf2f(arena[A_BP + c])));
  long idx = ((long)n << 8) + c;
  xf[idx] = v;
  xbf[idx] = f2bf(v);
  agg[idx] = 0.f;
}

// ---------------- CSR build (by dst). e lives in CSR row order everywhere ---
__global__ void k_hist(const int* __restrict__ dstA, int* __restrict__ deg) {
  int i = blockIdx.x * 256 + threadIdx.x;
  if (i < N_EDGES) {
    int d = dstA[i];
    if ((unsigned)d < N_NODES) atomicAdd(&deg[d], 1);
  }
}

__global__ void k_scan(const int* __restrict__ deg, int* __restrict__ rowptr,
                       int* __restrict__ cursor) {
  __shared__ int part[256];
  int tid = threadIdx.x;
  int base = tid * 40;
  int s = 0;
  for (int i = 0; i < 40; ++i) {
    int idx = base + i;
    if (idx < N_NODES) s += deg[idx];
  }
  part[tid] = s;
  __syncthreads();
  if (tid == 0) {
    int run = 0;
    for (int i = 0; i < 256; ++i) { int t = part[i]; part[i] = run; run += t; }
    rowptr[N_NODES] = run;
  }
  __syncthreads();
  int run = part[tid];
  for (int i = 0; i < 40; ++i) {
    int idx = base + i;
    if (idx < N_NODES) { rowptr[idx] = run; cursor[idx] = run; run += deg[idx]; }
  }
}

// Also emits csrc/cdst (endpoints in CSR order) and eaC (ea gathered to CSR).
__global__ void k_fill(const int* __restrict__ dstA, const int* __restrict__ srcA,
                       const unsigned short* __restrict__ arena,
                       int* __restrict__ cursor, int* __restrict__ eid,
                       int* __restrict__ csrc, int* __restrict__ cdst,
                       unsigned short* __restrict__ eaC) {
  int i = blockIdx.x * 256 + threadIdx.x;
  if (i < N_EDGES) {
    int d = dstA[i]; if ((unsigned)d >= N_NODES) d = 0;
    int p = atomicAdd(&cursor[d], 1);
    if ((unsigned)p < N_EDGES) {
      eid[p] = i;
      int s = srcA[i]; if ((unsigned)s >= N_NODES) s = 0;
      csrc[p] = s;
      cdst[p] = d;
      eaC[p] = arena[A_EA + i];
    }
  }
}

// ---------------------------------------------------------------------------
// Swapped-operand GEMM core with PERMUTED column mapping (see r7): lane
// (q,ll) reg r of frag mt holds out-col colBase + q*(MT*4) + mt*4 + r ->
// consecutive cols per lane -> full-line epilogue. 128-row tiles measured
// fastest for edge kernels (r11: A-frag VMEM independent of tile rows).
// LDS pitch 528B -> <=2-way bank aliasing (free).
// ---------------------------------------------------------------------------
#define SM_PITCH 528
#define EDGE_BLOCKS (N_EDGES / 128)   // 2500

template <bool NT, int ROWS>
__device__ __forceinline__ void stage_tile(char* smc, const unsigned short* src,
                                           long rowBase) {
  int tid = threadIdx.x;
#pragma unroll
  for (int it = 0; it < ROWS / 8; ++it) {   // ROWS rows x 32 groups of 16B
    int lin = it * 256 + tid;
    int row = lin >> 5, g = lin & 31;
    const i32x4* p = (const i32x4*)((const char*)src + ((rowBase + row) << 9) + (g << 4));
    i32x4 v = NT ? __builtin_nontemporal_load(p) : *p;
    *(i32x4*)(smc + row * SM_PITCH + (g << 4)) = v;
  }
}

template <int MT, int NTT>
__device__ __forceinline__ void gemm_swap(const char* smc, const unsigned short* WT,
                                          int colBase, fp32x4 (&acc)[MT][NTT]) {
  const int lane = threadIdx.x & 63;
  const int q = lane >> 4, ll = lane & 15;
  const int llperm = ((ll >> 2) * (MT * 4)) + (ll & 3);  // permuted col offset
#pragma unroll
  for (int ks = 0; ks < 8; ++ks) {
    bf16x8 a[MT];
#pragma unroll
    for (int mt = 0; mt < MT; ++mt) {
      int oc = colBase + llperm + mt * 4;
      a[mt] = *(const bf16x8*)((const char*)WT + ((long)oc << 9) + (ks << 6) + (q << 4));
    }
    bf16x8 b[NTT];
#pragma unroll
    for (int nt = 0; nt < NTT; ++nt)
      b[nt] = *(const bf16x8*)(smc + (nt * 16 + ll) * SM_PITCH + (ks << 6) + (q << 4));
#pragma unroll
    for (int mt = 0; mt < MT; ++mt)
#pragma unroll
      for (int nt = 0; nt < NTT; ++nt)
        acc[mt][nt] = __builtin_amdgcn_mfma_f32_16x16x32_bf16(a[mt], b[nt], acc[mt][nt], 0, 0, 0);
  }
}

// Shared epilogue: e_new = e_old + relu(acc + xs + xt + be), updated in LDS.
template <int NTT>
__device__ __forceinline__ void edge_epilogue(
    char* smc, const fp32x4 (&acc)[4][NTT], const int* s_src, const int* s_dst,
    const unsigned short* XW, int xw_pitch, int xs_off, int xt_off,
    const unsigned short* bePtr, int cb, int ll) {
  u16x8 be0 = *(const u16x8*)(bePtr + cb);
  u16x8 be1 = *(const u16x8*)(bePtr + cb + 8);
#pragma unroll
  for (int nt = 0; nt < NTT; ++nt) {
    int el = nt * 16 + ll;
    int sn = s_src[el], dn = s_dst[el];
    const unsigned short* xsrow = XW + (long)sn * xw_pitch + xs_off + cb;
    const unsigned short* xtrow = XW + (long)dn * xw_pitch + xt_off + cb;
    u16x8 xs0 = *(const u16x8*)(xsrow);
    u16x8 xs1 = *(const u16x8*)(xsrow + 8);
    u16x8 xt0 = *(const u16x8*)(xtrow);
    u16x8 xt1 = *(const u16x8*)(xtrow + 8);
    u16x8* slot = (u16x8*)(smc + el * SM_PITCH + cb * 2);
    u16x8 er0 = slot[0], er1 = slot[1];
    u16x8 o0, o1;
#pragma unroll
    for (int mt = 0; mt < 4; ++mt)
#pragma unroll
      for (int r = 0; r < 4; ++r) {
        int i = mt * 4 + r;
        float xsv = bf2f(i < 8 ? xs0[i] : xs1[i - 8]);
        float xtv = bf2f(i < 8 ? xt0[i] : xt1[i - 8]);
        float erv = bf2f(i < 8 ? er0[i] : er1[i - 8]);
        float bev = bf2f(i < 8 ? be0[i] : be1[i - 8]);
        float v = acc[mt][nt][r] + xsv + xtv + bev;
        v = fmaxf(v, 0.f);
        unsigned short ob = f2bf(erv + v);
        if (i < 8) o0[i] = ob; else o1[i - 8] = ob;
      }
    slot[0] = o0;
    slot[1] = o1;  // slot owned by this lane only
  }
}

// ---------------------------------------------------------------------------
// FAT kernel: blocks [0, 2500) run edge-update layer l (128-row tiles,
// in-place e writeback); blocks [2500, 3132) run node_gemm(l+1) into the
// OTHER XW buffer (ping-pong -> no RAW/WAR conflict). The small gemm hides
// inside the latency-bound edge kernel's idle issue slots.
// MODE 0: edge builds e0 in LDS from eaC. MODE 1: edge stages e.
// ---------------------------------------------------------------------------
template <int MODE>
__global__ __launch_bounds__(256, 2) void k_fat(
    unsigned short* __restrict__ e, const unsigned short* __restrict__ WT_edge,
    const unsigned short* __restrict__ XW_edge,
    const unsigned short* __restrict__ bePtr, const unsigned short* __restrict__ arena,
    const unsigned short* __restrict__ eaC,
    const int* __restrict__ csrc, const int* __restrict__ cdst,
    const unsigned short* __restrict__ xbf, const unsigned short* __restrict__ WT_node,
    const unsigned short* __restrict__ bias, unsigned short* __restrict__ XW_out) {
  __shared__ int4 sm4[128 * 33];
  __shared__ int s_src[128];
  __shared__ int s_dst[128];
  char* smc = (char*)sm4;
  const int tid = threadIdx.x;
  const int wave = tid >> 6, lane = tid & 63;
  const int q = lane >> 4, ll = lane & 15;

  if (blockIdx.x < EDGE_BLOCKS) {
    // ---------------- edge role ----------------
    const long tileBase = (long)blockIdx.x * 128;
    const int colBase = wave * 64;
    if (MODE == 0) {
#pragma unroll
      for (int it = 0; it < 16; ++it) {
        int lin = it * 256 + tid;
        int row = lin >> 5, g = lin & 31;
        float eav = bf2f(eaC[tileBase + row]);
        int c0 = g * 8;
        bf16x8 ov;
#pragma unroll
        for (int j = 0; j < 8; ++j) {
          float f = fmaf(eav, bf2f(arena[A_WA + c0 + j]), bf2f(arena[A_BA + c0 + j]));
          ((unsigned short*)&ov)[j] = f2bf(f);
        }
        *(bf16x8*)(smc + row * SM_PITCH + (g << 4)) = ov;
      }
    } else {
      stage_tile<true, 128>(smc, e, tileBase);
    }
    if (tid < 128) {
      long edge = tileBase + tid;
      int s = csrc[edge]; if ((unsigned)s >= N_NODES) s = 0;
      int d = cdst[edge]; if ((unsigned)d >= N_NODES) d = 0;
      s_src[tid] = s;
      s_dst[tid] = d;
    }
    __syncthreads();

    fp32x4 acc[4][8];
#pragma unroll
    for (int mt = 0; mt < 4; ++mt)
#pragma unroll
      for (int nt = 0; nt < 8; ++nt) acc[mt][nt] = 0.f;
    gemm_swap<4, 8>(smc, WT_edge, colBase, acc);
    __syncthreads();  // all waves done reading A-tile before in-place update

    edge_epilogue<8>(smc, acc, s_src, s_dst, XW_edge, 1024, 512, 768,
                     bePtr, colBase + q * 16, ll);
    __syncthreads();  // tile fully updated

    // Coalesced full-line writeback.
#pragma unroll
    for (int it = 0; it < 16; ++it) {
      int lin = it * 256 + tid;
      int row = lin >> 5, g = lin & 31;
      i32x4 v = *(const i32x4*)(smc + row * SM_PITCH + (g << 4));
      __builtin_nontemporal_store(v, (i32x4*)((char*)e + ((tileBase + row) << 9) + (g << 4)));
    }
  } else {
    // ---------------- node_gemm role (128 rows x 128 cols per block) -------
    int b = blockIdx.x - EDGE_BLOCKS;   // 0..631 = (79 x, 8 y)
    int bx = b % 79, by = b / 79;
    const long tileBase = (long)bx * 128;
#pragma unroll
    for (int it = 0; it < 16; ++it) {
      int lin = it * 256 + tid;
      int row = lin >> 5, g = lin & 31;
      long rg = tileBase + row;
      if (rg > N_NODES - 1) rg = N_NODES - 1;
      i32x4 v = *(const i32x4*)((const char*)xbf + (rg << 9) + (g << 4));
      *(i32x4*)(smc + row * SM_PITCH + (g << 4)) = v;
    }
    __syncthreads();
    fp32x4 acc[2][8];
#pragma unroll
    for (int mt = 0; mt < 2; ++mt)
#pragma unroll
      for (int nt = 0; nt < 8; ++nt) acc[mt][nt] = 0.f;
    const int colBase = by * 128 + wave * 32;
    gemm_swap<2, 8>(smc, WT_node, colBase, acc);

    const int cb = colBase + q * 8;
    u16x8 bs8 = *(const u16x8*)(bias + cb);
#pragma unroll
    for (int nt = 0; nt < 8; ++nt) {
      long nn = tileBase + nt * 16 + ll;
      if (nn >= N_NODES) continue;
      u16x8 o0;
#pragma unroll
      for (int mt = 0; mt < 2; ++mt)
#pragma unroll
        for (int r = 0; r < 4; ++r) {
          int i = mt * 4 + r;
          o0[i] = f2bf(acc[mt][nt][r] + bf2f(bs8[i]));
        }
      *(u16x8*)(XW_out + nn * 1024 + cb) = o0;
    }
  }
}

// ---------------------------------------------------------------------------
// Fused last-2 edge kernel: stage e2; edge-update(l=2) -> e3 in LDS;
// edge-update(l=3) -> e4 in LDS; fused MLP head -> out. e3/e4 never hit HBM.
// ---------------------------------------------------------------------------
__global__ __launch_bounds__(256, 2) void k_edge_last2(
    const unsigned short* __restrict__ e, const unsigned short* __restrict__ WeT2,
    const unsigned short* __restrict__ WeT3,
    const unsigned short* __restrict__ XW2, const unsigned short* __restrict__ XW3,
    const unsigned short* __restrict__ arena, const unsigned short* __restrict__ eaC,
    const int* __restrict__ csrc, const int* __restrict__ cdst,
    const unsigned short* __restrict__ Wm1T, const int* __restrict__ eid,
    const int* __restrict__ flag, void* __restrict__ out) {
  __shared__ int4 sm4[128 * 33];
  __shared__ int s_src[128];
  __shared__ int s_dst[128];
  char* smc = (char*)sm4;
  const long tileBase = (long)blockIdx.x * 128;
  const int tid = threadIdx.x;
  const int wave = tid >> 6, lane = tid & 63;
  const int q = lane >> 4, ll = lane & 15;
  const int colBase = wave * 64;

  stage_tile<true, 128>(smc, e, tileBase);
  if (tid < 128) {
    long edge = tileBase + tid;
    int s = csrc[edge]; if ((unsigned)s >= N_NODES) s = 0;
    int d = cdst[edge]; if ((unsigned)d >= N_NODES) d = 0;
    s_src[tid] = s;
    s_dst[tid] = d;
  }
  __syncthreads();

  // ---- edge update l=2 ----
  fp32x4 acc[4][8];
#pragma unroll
  for (int mt = 0; mt < 4; ++mt)
#pragma unroll
    for (int nt = 0; nt < 8; ++nt) acc[mt][nt] = 0.f;
  gemm_swap<4, 8>(smc, WeT2, colBase, acc);
  __syncthreads();
  edge_epilogue<8>(smc, acc, s_src, s_dst, XW2, 1024, 512, 768,
                   arena + A_BE + 2 * 256, colBase + q * 16, ll);
  __syncthreads();  // e3 complete in LDS

  // ---- edge update l=3 ----
#pragma unroll
  for (int mt = 0; mt < 4; ++mt)
#pragma unroll
    for (int nt = 0; nt < 8; ++nt) acc[mt][nt] = 0.f;
  gemm_swap<4, 8>(smc, WeT3, colBase, acc);
  __syncthreads();
  edge_epilogue<8>(smc, acc, s_src, s_dst, XW3, 512, 0, 256,
                   arena + A_BE + 3 * 256, colBase + q * 16, ll);
  __syncthreads();  // e4 complete in LDS

  // ---- fused MLP head ----
  fp32x4 acc2[2][8];
#pragma unroll
  for (int mt = 0; mt < 2; ++mt)
#pragma unroll
    for (int nt = 0; nt < 8; ++nt) acc2[mt][nt] = 0.f;
  const int colBase2 = wave * 32;
  gemm_swap<2, 8>(smc, Wm1T, colBase2, acc2);

  const int cb2 = colBase2 + q * 8;
  float alphaf = bf2f(arena[A_AL]);
  float bmc[8], wl[8], w2c[8];
#pragma unroll
  for (int i = 0; i < 8; ++i) {
    bmc[i] = bf2f(arena[A_BM1 + cb2 + i]);
    wl[i] = bf2f(arena[A_WM1 + 32768 + cb2 + i]);
    w2c[i] = bf2f(arena[A_WM2 + cb2 + i]);
  }
  __syncthreads();             // all waves done reading LDS for gemm2
  float* part = (float*)smc;   // alias tile as [128][4] fp32 partials
#pragma unroll
  for (int nt = 0; nt < 8; ++nt) {
    int el = nt * 16 + ll;
    float eav = bf2f(eaC[tileBase + el]);
    float ps = 0.f;
#pragma unroll
    for (int mt = 0; mt < 2; ++mt)
#pragma unroll
      for (int r = 0; r < 4; ++r) {
        int i = mt * 4 + r;
        float h = acc2[mt][nt][r] + bmc[i] + eav * wl[i];
        h = (h > 0.f) ? h : alphaf * h;
        ps += h * w2c[i];
      }
    ps += __shfl_xor(ps, 16, 64);
    ps += __shfl_xor(ps, 32, 64);
    if (q == 0) part[el * 4 + wave] = ps;
  }
  __syncthreads();
  if (tid < 128) {
    float t = part[tid * 4] + part[tid * 4 + 1] + part[tid * 4 + 2] + part[tid * 4 + 3]
            + bf2f(arena[A_BM2]);
    long row = tileBase + tid;
    int oe = eid[row]; if ((unsigned)oe >= N_EDGES) oe = 0;
    if (*flag) ((float*)out)[oe] = t;
    else       ((unsigned short*)out)[oe] = f2bf(t);
  }
}

// Node-side GEMM (standalone, for layer 0 and layer 3).
__global__ __launch_bounds__(256, 2) void k_node_gemm(
    const unsigned short* __restrict__ xbf, const unsigned short* __restrict__ WT,
    const unsigned short* __restrict__ bias, unsigned short* __restrict__ out,
    int out_pitch) {
  __shared__ int4 sm4[128 * 33];
  char* smc = (char*)sm4;
  const long tileBase = (long)blockIdx.x * 128;
  {
    int tid = threadIdx.x;
#pragma unroll
    for (int it = 0; it < 16; ++it) {
      int lin = it * 256 + tid;
      int row = lin >> 5, g = lin & 31;
      long rg = tileBase + row;
      if (rg > N_NODES - 1) rg = N_NODES - 1;
      i32x4 v = *(const i32x4*)((const char*)xbf + (rg << 9) + (g << 4));
      *(i32x4*)(smc + row * SM_PITCH + (g << 4)) = v;
    }
  }
  __syncthreads();
  fp32x4 acc[2][8];
#pragma unroll
  for (int mt = 0; mt < 2; ++mt)
#pragma unroll
    for (int nt = 0; nt < 8; ++nt) acc[mt][nt] = 0.f;
  const int tid = threadIdx.x, wave = tid >> 6, lane = tid & 63;
  const int q = lane >> 4, ll = lane & 15;
  const int colBase = blockIdx.y * 128 + wave * 32;
  gemm_swap<2, 8>(smc, WT, colBase, acc);

  const int cb = colBase + q * 8;
  u16x8 bs8 = *(const u16x8*)(bias + cb);
#pragma unroll
  for (int nt = 0; nt < 8; ++nt) {
    long nn = tileBase + nt * 16 + ll;
    if (nn >= N_NODES) continue;
    u16x8 o0;
#pragma unroll
    for (int mt = 0; mt < 2; ++mt)
#pragma unroll
      for (int r = 0; r < 4; ++r) {
        int i = mt * 4 + r;
        o0[i] = f2bf(acc[mt][nt][r] + bf2f(bs8[i]));
      }
    *(u16x8*)(out + nn * out_pitch + cb) = o0;
  }
}

// ---------------------------------------------------------------------------
// Edge-tiled agg: block = 64 consecutive CSR rows, loads batched 8-wide,
// one atomicAdd per dst-run. Sits at its 164MB e-read HBM floor (~33us).
// ---------------------------------------------------------------------------
template <bool FIRST>
__global__ void k_agg(const int* __restrict__ csrc, const int* __restrict__ cdst,
                      const unsigned short* __restrict__ e,
                      const unsigned short* __restrict__ eaC,
                      const unsigned short* __restrict__ arena,
                      const unsigned short* __restrict__ XW, int xw_pitch, int x2_off,
                      float* __restrict__ agg) {
  __shared__ int s_src[64];
  __shared__ int s_dst[64];
  const long base = (long)blockIdx.x * 64;
  const int c = threadIdx.x;
  if (c < 64) {
    long r = base + c;
    int s = csrc[r]; if ((unsigned)s >= N_NODES) s = 0;
    int d = cdst[r]; if ((unsigned)d >= N_NODES) d = 0;
    s_src[c] = s;
    s_dst[c] = d;
  }
  __syncthreads();
  float wac = 0.f, bac = 0.f;
  if (FIRST) { wac = bf2f(arena[A_WA + c]); bac = bf2f(arena[A_BA + c]); }
  float a = 0.f;
  int run = s_dst[0];
  for (int b8 = 0; b8 < 64; b8 += 8) {
    float evv[8], x2v[8];
#pragma unroll
    for (int j = 0; j < 8; ++j) {
      int row = b8 + j;
      if (FIRST) evv[j] = fmaf(bf2f(eaC[base + row]), wac, bac);
      else evv[j] = bf2f(__builtin_nontemporal_load(e + ((base + row) << 8) + c));
      x2v[j] = bf2f(XW[(long)s_src[row] * xw_pitch + x2_off + c]);
    }
#pragma unroll
    for (int j = 0; j < 8; ++j) {
      int d = s_dst[b8 + j];
      if (d != run) {  // uniform across the block (dst-sorted)
        atomicAdd(&agg[((long)run << 8) + c], a);
        a = 0.f;
        run = d;
      }
      float gate = 1.f / (1.f + __expf(-evv[j]));
      a = fmaf(gate, x2v[j], a);
    }
  }
  atomicAdd(&agg[((long)run << 8) + c], a);
}

// x += relu(xW1+b1 + agg); refresh bf16 copy; zero agg for the next layer.
__global__ void k_node_update(float* __restrict__ xf, unsigned short* __restrict__ xbf,
                              const unsigned short* __restrict__ XW,
                              float* __restrict__ agg) {
  int n = blockIdx.x, c = threadIdx.x;
  long idx = ((long)n << 8) + c;
  float av = agg[idx];
  agg[idx] = 0.f;
  float t = bf2f(XW[((long)n << 10) + c]) + av;
  float nx = xf[idx] + fmaxf(t, 0.f);
  xf[idx] = nx;
  xbf[idx] = f2bf(nx);
}

// ---------------------------------------------------------------------------
extern "C" void kernel_launch(void* const* d_in, const int* in_sizes, int n_in,
                              void* d_out, int out_size, void* d_ws, size_t ws_size,
                              hipStream_t stream) {
  const int* eidx = (const int*)d_in[2];
  const int* srcA = eidx;
  const int* dstA = eidx + N_EDGES;
  (void)in_sizes; (void)n_in; (void)out_size;

  char* ws = (char*)d_ws;
  size_t off = 0;
  auto alloc = [&](size_t bytes) -> char* {
    char* p = ws + off;
    off = (off + bytes + 255) & ~(size_t)255;
    return p;
  };
  unsigned short* e_buf   = (unsigned short*)alloc((size_t)N_EDGES * 256 * 2);  // 164 MB
  float*          xf      = (float*)alloc((size_t)N_NODES * 256 * 4);
  unsigned short* xbf     = (unsigned short*)alloc((size_t)N_NODES * 256 * 2);
  unsigned short* XWa     = (unsigned short*)alloc((size_t)N_NODES * 1024 * 2);
  unsigned short* XWb     = (unsigned short*)alloc((size_t)N_NODES * 1024 * 2);
  unsigned short* XW3     = (unsigned short*)alloc((size_t)N_NODES * 512 * 2);
  float*          agg     = (float*)alloc((size_t)N_NODES * 256 * 4);
  unsigned short* nodeBT  = (unsigned short*)alloc((size_t)917504 * 2);
  unsigned short* WeT     = (unsigned short*)alloc((size_t)4 * 65536 * 2);
  unsigned short* Wm1T    = (unsigned short*)alloc((size_t)32768 * 2);
  unsigned short* biascat = (unsigned short*)alloc((size_t)3584 * 2);
  unsigned short* arena   = (unsigned short*)alloc((size_t)ARENA_TOT * 2);
  int* deg    = (int*)alloc((size_t)N_NODES * 4);
  int* rowptr = (int*)alloc((size_t)(N_NODES + 1) * 4);
  int* cursor = (int*)alloc((size_t)N_NODES * 4);
  int* eid    = (int*)alloc((size_t)N_EDGES * 4);
  int* csrc   = (int*)alloc((size_t)N_EDGES * 4);
  int* cdst   = (int*)alloc((size_t)N_EDGES * 4);
  unsigned short* eaC = (unsigned short*)alloc((size_t)N_EDGES * 2);
  int* flag   = (int*)alloc(4);
  if (ws_size < off) return;  // distinctive signature: out stays all-zero

  Ptrs ptrs;
  {
    int map[19] = {0, 1, 3, 4, 5, 6, 7, 8, 9, 10, 11, 12, 13, 14, 15, 16, 17, 18, 19};
    for (int j = 0; j < 19; ++j) ptrs.p[j] = d_in[map[j]];
  }

  dim3 blk(256);
  k_detect<<<dim3(40), blk, 0, stream>>>((const unsigned short*)d_in[3], flag, deg);
  k_cast<<<dim3((ARENA_USED + 255) / 256), blk, 0, stream>>>(ptrs, flag, arena);
  k_prep<<<dim3(256, 1, 20), blk, 0, stream>>>(arena, nodeBT, WeT, Wm1T, biascat);
  k_init_x<<<dim3(N_NODES), blk, 0, stream>>>(arena, xf, xbf, agg);
  k_hist<<<dim3(N_EDGES / 256), blk, 0, stream>>>(dstA, deg);
  k_scan<<<dim3(1), blk, 0, stream>>>(deg, rowptr, cursor);
  k_fill<<<dim3(N_EDGES / 256), blk, 0, stream>>>(dstA, srcA, arena, cursor, eid, csrc,
                                                  cdst, eaC);

  // layer 0
  k_node_gemm<<<dim3(79, 8), blk, 0, stream>>>(xbf, nodeBT, biascat, XWa, 1024);
  k_agg<true><<<dim3(N_EDGES / 64), blk, 0, stream>>>(csrc, cdst, e_buf, eaC, arena,
                                                      XWa, 1024, 256, agg);
  k_node_update<<<dim3(N_NODES), blk, 0, stream>>>(xf, xbf, XWa, agg);   // x1
  k_fat<0><<<dim3(EDGE_BLOCKS + 632), blk, 0, stream>>>(
      e_buf, WeT, XWa, arena + A_BE, arena, eaC, csrc, cdst,
      xbf, nodeBT + 262144, biascat + 1024, XWb);                        // e1 + XWb
  // layer 1
  k_agg<false><<<dim3(N_EDGES / 64), blk, 0, stream>>>(csrc, cdst, e_buf, eaC, arena,
                                                       XWb, 1024, 256, agg);
  k_node_update<<<dim3(N_NODES), blk, 0, stream>>>(xf, xbf, XWb, agg);   // x2
  k_fat<1><<<dim3(EDGE_BLOCKS + 632), blk, 0, stream>>>(
      e_buf, WeT + 65536, XWb, arena + A_BE + 256, arena, eaC, csrc, cdst,
      xbf, nodeBT + 2 * 262144, biascat + 2048, XWa);                    // e2 + XWa
  // layer 2 (agg only; edge deferred into last2)
  k_agg<false><<<dim3(N_EDGES / 64), blk, 0, stream>>>(csrc, cdst, e_buf, eaC, arena,
                                                       XWa, 1024, 256, agg);
  k_node_update<<<dim3(N_NODES), blk, 0, stream>>>(xf, xbf, XWa, agg);   // x3
  k_node_gemm<<<dim3(79, 4), blk, 0, stream>>>(xbf, nodeBT + 786432, biascat + 3072, XW3, 512);
  k_edge_last2<<<dim3(EDGE_BLOCKS), blk, 0, stream>>>(
      e_buf, WeT + 2 * 65536, WeT + 3 * 65536, XWa, XW3, arena, eaC,
      csrc, cdst, Wm1T, eid, flag, d_out);
}